// Round 1
// baseline (6168.296 us; speedup 1.0000x reference)
//
#include <hip/hip_runtime.h>
#include <math.h>

#define D_ 3072
#define H_ 2048
#define N_ 16
#define BS_ 512

// ---------------- generic NN GEMM with epilogues ----------------
// v = sum_k A[m][k]*B[k][n] + bias[n]
// EP 0: C = tanh(v)
// EP 1: C = X - v
// EP 2: rowsum[m] += sum_n (v - X[m][n])^2
template<int EP>
__global__ __launch_bounds__(256) void gemm_nn(const float* __restrict__ A,
    const float* __restrict__ B, const float* __restrict__ bias,
    const float* __restrict__ X, float* __restrict__ C, float* __restrict__ rowsum,
    int M, int N, int K)
{
    __shared__ __align__(16) float As[64][17];
    __shared__ __align__(16) float Bs[16][64];
    const int tid = threadIdx.x;
    const int tx = tid & 15, ty = tid >> 4;
    const int m0 = blockIdx.y * 64, n0 = blockIdx.x * 64;
    float acc[4][4] = {};
    for (int k0 = 0; k0 < K; k0 += 16) {
        #pragma unroll
        for (int l = tid; l < 1024; l += 256) {
            int row = l >> 4, kk = l & 15;
            As[row][kk] = A[(size_t)(m0 + row) * K + k0 + kk];
        }
        #pragma unroll
        for (int l = tid; l < 1024; l += 256) {
            int kk = l >> 6, col = l & 63;
            Bs[kk][col] = B[(size_t)(k0 + kk) * N + n0 + col];
        }
        __syncthreads();
        #pragma unroll
        for (int kk = 0; kk < 16; ++kk) {
            float4 b4 = *(const float4*)&Bs[kk][tx * 4];
            #pragma unroll
            for (int j = 0; j < 4; ++j) {
                float a = As[ty * 4 + j][kk];
                acc[j][0] += a * b4.x;
                acc[j][1] += a * b4.y;
                acc[j][2] += a * b4.z;
                acc[j][3] += a * b4.w;
            }
        }
        __syncthreads();
    }
    #pragma unroll
    for (int j = 0; j < 4; ++j) {
        int m = m0 + ty * 4 + j;
        if (EP == 2) {
            float s = 0.f;
            #pragma unroll
            for (int q = 0; q < 4; ++q) {
                int n = n0 + tx * 4 + q;
                float v = acc[j][q] + bias[n];
                float dv = v - X[(size_t)m * N + n];
                s += dv * dv;
            }
            #pragma unroll
            for (int off = 8; off; off >>= 1) s += __shfl_down(s, off, 16);
            if (tx == 0) atomicAdd(&rowsum[m], s);
        } else {
            #pragma unroll
            for (int q = 0; q < 4; ++q) {
                int n = n0 + tx * 4 + q;
                float v = acc[j][q] + bias[n];
                if (EP == 0) C[(size_t)m * N + n] = tanhf(v);
                else         C[(size_t)m * N + n] = X[(size_t)m * N + n] - v;
            }
        }
    }
}

// ---------------- NT GEMM: C[m][n] = sum_k A[m][k] * Bt[n][k] ----------------
__global__ __launch_bounds__(256) void gemm_nt(const float* __restrict__ A,
    const float* __restrict__ Bt, float* __restrict__ C, int M, int N, int K)
{
    __shared__ float As[64][33];
    __shared__ float Bs[64][33];
    const int tid = threadIdx.x;
    const int tx = tid & 15, ty = tid >> 4;
    const int m0 = blockIdx.y * 64, n0 = blockIdx.x * 64;
    float acc[4][4] = {};
    for (int k0 = 0; k0 < K; k0 += 32) {
        #pragma unroll
        for (int l = tid; l < 2048; l += 256) {
            int row = l >> 5, kk = l & 31;
            As[row][kk] = A[(size_t)(m0 + row) * K + k0 + kk];
        }
        #pragma unroll
        for (int l = tid; l < 2048; l += 256) {
            int row = l >> 5, kk = l & 31;
            Bs[row][kk] = Bt[(size_t)(n0 + row) * K + k0 + kk];
        }
        __syncthreads();
        #pragma unroll
        for (int kk = 0; kk < 32; ++kk) {
            float a[4], bb[4];
            #pragma unroll
            for (int j = 0; j < 4; ++j) { a[j] = As[ty*4+j][kk]; bb[j] = Bs[tx*4+j][kk]; }
            #pragma unroll
            for (int j = 0; j < 4; ++j)
                #pragma unroll
                for (int q = 0; q < 4; ++q) acc[j][q] += a[j] * bb[q];
        }
        __syncthreads();
    }
    #pragma unroll
    for (int j = 0; j < 4; ++j)
        #pragma unroll
        for (int q = 0; q < 4; ++q)
            C[(size_t)(m0 + ty*4 + j) * N + n0 + tx*4 + q] = acc[j][q];
}

// ---------------- z_star / log-sigma / sigma ----------------
__global__ __launch_bounds__(256) void zsig_kernel(const float* __restrict__ h,
    const float* __restrict__ Wmu, const float* __restrict__ bmu,
    const float* __restrict__ Wls, const float* __restrict__ bls,
    float* __restrict__ z_star, float* __restrict__ lsig, float* __restrict__ sigma)
{
    const int b = blockIdx.x, tid = threadIdx.x;
    float acc[17];
    #pragma unroll
    for (int i = 0; i < 17; ++i) acc[i] = 0.f;
    for (int hh = tid; hh < H_; hh += 256) {
        float hv = h[(size_t)b * H_ + hh];
        const float* wr = &Wmu[(size_t)hh * 16];
        #pragma unroll
        for (int i = 0; i < 16; ++i) acc[i] += hv * wr[i];
        acc[16] += hv * Wls[hh];
    }
    __shared__ float red[17][4];
    const int wid = tid >> 6, lane = tid & 63;
    #pragma unroll
    for (int i = 0; i < 17; ++i) {
        float v = acc[i];
        #pragma unroll
        for (int off = 32; off; off >>= 1) v += __shfl_xor(v, off);
        if (lane == 0) red[i][wid] = v;
    }
    __syncthreads();
    if (tid < 17) {
        float v = red[tid][0] + red[tid][1] + red[tid][2] + red[tid][3];
        if (tid < 16) z_star[(size_t)b * 16 + tid] = v + bmu[tid];
        else { float ls = v + bls[0]; lsig[b] = ls; sigma[b] = expf(ls); }
    }
}

// ---------------- J^T J accumulation (fused, no J materialization) ----------------
// S[b][i][j] += sum_{d in tile} J[d,i]*J[d,j],  J[d,i] = sum_h W2[h,d]*u_b[h]*W1d[i,h]
__global__ __launch_bounds__(256) void jtj_kernel(const float* __restrict__ t,
    const float* __restrict__ W2, const float* __restrict__ W1d, float* __restrict__ S)
{
    __shared__ float W2s[32][65];
    __shared__ __align__(16) float W1s[16][36];
    __shared__ __align__(16) float us[8][36];
    const int tid = threadIdx.x;
    const int d = tid & 63;     // lane within wave
    const int bq = tid >> 6;    // wave id 0..3
    const int d0 = blockIdx.x * 64;
    const int b0 = blockIdx.y * 8;
    float acc0[16], acc1[16];
    #pragma unroll
    for (int i = 0; i < 16; ++i) { acc0[i] = 0.f; acc1[i] = 0.f; }

    for (int h0 = 0; h0 < H_; h0 += 32) {
        #pragma unroll
        for (int l = tid; l < 2048; l += 256) {
            int kk = l >> 6, dd = l & 63;
            W2s[kk][dd] = W2[(size_t)(h0 + kk) * D_ + d0 + dd];
        }
        #pragma unroll
        for (int l = tid; l < 512; l += 256) {
            int i = l >> 5, kk = l & 31;
            W1s[i][kk] = W1d[(size_t)i * H_ + h0 + kk];
        }
        {
            int bb = tid >> 5, kk = tid & 31;
            float tv = t[(size_t)(b0 + bb) * H_ + h0 + kk];
            us[bb][kk] = 1.0f - tv * tv;
        }
        __syncthreads();
        #pragma unroll
        for (int k4 = 0; k4 < 8; ++k4) {
            float w0 = W2s[k4*4+0][d], w1 = W2s[k4*4+1][d];
            float w2 = W2s[k4*4+2][d], w3 = W2s[k4*4+3][d];
            float4 u0 = *(const float4*)&us[bq][k4*4];
            float4 u1 = *(const float4*)&us[bq+4][k4*4];
            float p00 = w0*u0.x, p01 = w1*u0.y, p02 = w2*u0.z, p03 = w3*u0.w;
            float p10 = w0*u1.x, p11 = w1*u1.y, p12 = w2*u1.z, p13 = w3*u1.w;
            #pragma unroll
            for (int i = 0; i < 16; ++i) {
                float4 w1v = *(const float4*)&W1s[i][k4*4];
                acc0[i] += p00*w1v.x + p01*w1v.y + p02*w1v.z + p03*w1v.w;
                acc1[i] += p10*w1v.x + p11*w1v.y + p12*w1v.z + p13*w1v.w;
            }
        }
        __syncthreads();
    }
    // wave-level reduction over d; each wave owns batches b0+bq and b0+bq+4
    #pragma unroll
    for (int i = 0; i < 16; ++i) {
        #pragma unroll
        for (int j = i; j < 16; ++j) {
            float v0 = acc0[i] * acc0[j];
            float v1 = acc1[i] * acc1[j];
            #pragma unroll
            for (int off = 32; off; off >>= 1) {
                v0 += __shfl_xor(v0, off);
                v1 += __shfl_xor(v1, off);
            }
            if ((tid & 63) == 0) {
                int b1 = b0 + bq, b2 = b0 + bq + 4;
                atomicAdd(&S[(size_t)b1*256 + i*16 + j], v0);
                if (i != j) atomicAdd(&S[(size_t)b1*256 + j*16 + i], v0);
                atomicAdd(&S[(size_t)b2*256 + i*16 + j], v1);
                if (i != j) atomicAdd(&S[(size_t)b2*256 + j*16 + i], v1);
            }
        }
    }
}

// ---------------- Hessian core: S[b][m][n] += 2*sum_h g*t*u*W1[m,h]*W1[n,h] ----------------
__global__ __launch_bounds__(256) void hess_kernel(const float* __restrict__ t,
    const float* __restrict__ g, const float* __restrict__ W1d, float* __restrict__ S)
{
    __shared__ float ws[H_];
    __shared__ float W1c[16][129];
    const int b = blockIdx.x, tid = threadIdx.x;
    for (int hh = tid; hh < H_; hh += 256) {
        float tv = t[(size_t)b * H_ + hh];
        ws[hh] = 2.0f * g[(size_t)b * H_ + hh] * tv * (1.0f - tv * tv);
    }
    const int m = tid >> 4, n = tid & 15;
    float acc = 0.f;
    for (int h0 = 0; h0 < H_; h0 += 128) {
        __syncthreads();
        for (int l = tid; l < 2048; l += 256) {
            int i = l >> 7, kk = l & 127;
            W1c[i][kk] = W1d[(size_t)i * H_ + h0 + kk];
        }
        __syncthreads();
        #pragma unroll 8
        for (int kk = 0; kk < 128; ++kk)
            acc += ws[h0 + kk] * W1c[m][kk] * W1c[n][kk];
    }
    atomicAdd(&S[(size_t)b * 256 + tid], acc);
}

// ---------------- per-batch: lambda_min (bisection), Cholesky, solves, scalars ----------------
__global__ __launch_bounds__(256) void solve_kernel(const float* __restrict__ S,
    const float* __restrict__ sigma, const float* __restrict__ z_star,
    const float* __restrict__ eps, float* __restrict__ z_sample, float* __restrict__ d_out)
{
    __shared__ float Ash[4][16][17];
    __shared__ float Csh[4][16][17];
    __shared__ float Wsh[4][16][17];
    const int tid = threadIdx.x;
    const int wid = tid >> 6, lane = tid & 63;
    const int b = blockIdx.x * 4 + wid;
    float (*A)[17]  = Ash[wid];
    float (*Cm)[17] = Csh[wid];
    float (*W)[17]  = Wsh[wid];
    const float sg = sigma[b];
    const float inv_s2 = 1.0f / (sg * sg);

    for (int l = lane; l < 256; l += 64) {
        int i = l >> 4, j = l & 15;
        A[i][j] = S[(size_t)b * 256 + l] * inv_s2 + (i == j ? 1.0f : 0.f);
    }
    __syncthreads();

    float lo = 1e30f, hi = 1e30f;
    if (lane < 16) {
        float diag = A[lane][lane];
        float r = 0.f;
        #pragma unroll
        for (int j = 0; j < 16; ++j) r += (j == lane) ? 0.f : fabsf(A[lane][j]);
        lo = diag - r;
        hi = diag;
    }
    #pragma unroll
    for (int off = 8; off; off >>= 1) {
        lo = fminf(lo, __shfl_xor(lo, off));
        hi = fminf(hi, __shfl_xor(hi, off));
    }
    lo = __shfl(lo, 0) - 1e-3f;
    hi = __shfl(hi, 0) + 1e-3f;

    const int r4 = lane >> 4;
    const int c  = lane & 15;

    for (int iter = 0; iter < 32; ++iter) {
        float s = 0.5f * (lo + hi);
        for (int l = lane; l < 256; l += 64) {
            int i = l >> 4, j = l & 15;
            Cm[i][j] = A[i][j] - (i == j ? s : 0.f);
        }
        __syncthreads();
        int cnt = 0;
        for (int j = 0; j < 16; ++j) {
            float dpv = Cm[j][j];
            if (fabsf(dpv) < 1e-30f) dpv = -1e-30f;
            cnt += (dpv < 0.f) ? 1 : 0;
            if (j < 15) {
                for (int ib = j + 1 + r4; ib < 16; ib += 4) {
                    if (c > j) {
                        float f = Cm[ib][j] / dpv;
                        Cm[ib][c] -= f * Cm[j][c];
                    }
                }
            }
            __syncthreads();
        }
        if (cnt >= 1) hi = s; else lo = s;
    }

    const float lam_min = 0.5f * (lo + hi);
    const float delta = 10.0f - lam_min;

    // Cholesky of A + delta*I (lower L in Cm)
    for (int l = lane; l < 256; l += 64) {
        int i = l >> 4, j = l & 15;
        Cm[i][j] = A[i][j] + (i == j ? delta : 0.f);
    }
    __syncthreads();
    for (int j = 0; j < 16; ++j) {
        float dj = sqrtf(Cm[j][j]);
        __syncthreads();
        if (lane < 16) {
            if (lane == j) Cm[j][j] = dj;
            else if (lane > j) Cm[lane][j] = Cm[lane][j] / dj;
        }
        __syncthreads();
        if (j < 15) {
            for (int ib = j + 1 + r4; ib < 16; ib += 4) {
                if (c > j && c <= ib) Cm[ib][c] -= Cm[ib][j] * Cm[c][j];
            }
        }
        __syncthreads();
    }

    // W = L^{-1} (column per lane)
    if (lane < 16) {
        int cc = lane;
        W[cc][cc] = 1.0f / Cm[cc][cc];
        for (int i = cc + 1; i < 16; ++i) {
            float sm = 0.f;
            for (int k = cc; k < i; ++k) sm += Cm[i][k] * W[k][cc];
            W[i][cc] = -sm / Cm[i][i];
        }
    }
    __syncthreads();

    float tr = 0.f, zsq = 0.f, ldv = 0.f;
    if (lane < 16) {
        for (int i = lane; i < 16; ++i) tr += W[i][lane] * W[i][lane];
        float zv = z_star[(size_t)b * 16 + lane];
        zsq = zv * zv;
        ldv = logf(Cm[lane][lane]);
        float a = 0.f;
        for (int jj = lane; jj < 16; ++jj) a += W[jj][lane] * eps[(size_t)b * 16 + jj];
        z_sample[(size_t)b * 16 + lane] = zv + a;
    }
    #pragma unroll
    for (int off = 8; off; off >>= 1) {
        tr  += __shfl_xor(tr, off);
        zsq += __shfl_xor(zsq, off);
        ldv += __shfl_xor(ldv, off);
    }
    if (lane == 0) {
        d_out[2 * 512 + b] = 0.5f * zsq + 0.5f * tr;  // latent_energy
        d_out[3 * 512 + b] = ldv;                     // logdet_loss
        d_out[4 * 512 + b] = sg;                      // sigma
    }
}

__global__ void finalize_kernel(const float* __restrict__ rlsum, const float* __restrict__ sigma,
    const float* __restrict__ lsig, float* __restrict__ d_out)
{
    int b = blockIdx.x * 256 + threadIdx.x;
    if (b < BS_) {
        float sg = sigma[b];
        float rl = rlsum[b] / (2.0f * sg * sg);
        float le = d_out[2 * 512 + b];
        float ld = d_out[3 * 512 + b];
        d_out[b] = (rl + le + ld) / 3072.0f + lsig[b];  // neg_log_prob
        d_out[512 + b] = rl;                            // recon_loss
    }
}

extern "C" void kernel_launch(void* const* d_in, const int* in_sizes, int n_in,
                              void* d_out, int out_size, void* d_ws, size_t ws_size,
                              hipStream_t stream)
{
    const float* x       = (const float*)d_in[0];
    const float* eps     = (const float*)d_in[1];
    const float* enc_W1  = (const float*)d_in[2];
    const float* enc_b1  = (const float*)d_in[3];
    const float* enc_Wmu = (const float*)d_in[4];
    const float* enc_bmu = (const float*)d_in[5];
    const float* enc_Wls = (const float*)d_in[6];
    const float* enc_bls = (const float*)d_in[7];
    const float* dec_W1  = (const float*)d_in[8];
    const float* dec_b1  = (const float*)d_in[9];
    const float* dec_W2  = (const float*)d_in[10];
    const float* dec_b2  = (const float*)d_in[11];
    float* out = (float*)d_out;

    float* ws = (float*)d_ws;
    size_t off = 0;
    float* h    = ws + off; off += (size_t)BS_ * H_;
    float* t    = ws + off; off += (size_t)BS_ * H_;
    float* e    = ws + off; off += (size_t)BS_ * D_;
    float* g    = ws + off; off += (size_t)BS_ * H_;
    float* S    = ws + off; off += (size_t)BS_ * 256;
    float* z_st = ws + off; off += (size_t)BS_ * 16;
    float* lsig = ws + off; off += BS_;
    float* sigm = ws + off; off += BS_;
    float* z_sm = ws + off; off += (size_t)BS_ * 16;
    float* rls  = ws + off; off += BS_;
    if (ws_size < off * sizeof(float)) return;

    hipMemsetAsync(S, 0, (size_t)BS_ * 256 * sizeof(float), stream);
    hipMemsetAsync(rls, 0, BS_ * sizeof(float), stream);

    // h = tanh(x @ enc_W1 + b1)
    gemm_nn<0><<<dim3(H_/64, BS_/64), 256, 0, stream>>>(x, enc_W1, enc_b1, nullptr, h, nullptr, BS_, H_, D_);
    // z_star, log sigma, sigma
    zsig_kernel<<<dim3(BS_), 256, 0, stream>>>(h, enc_Wmu, enc_bmu, enc_Wls, enc_bls, z_st, lsig, sigm);
    // t = tanh(z_star @ dec_W1 + b1)
    gemm_nn<0><<<dim3(H_/64, BS_/64), 256, 0, stream>>>(z_st, dec_W1, dec_b1, nullptr, t, nullptr, BS_, H_, N_);
    // e = x - (t @ dec_W2 + b2)
    gemm_nn<1><<<dim3(D_/64, BS_/64), 256, 0, stream>>>(t, dec_W2, dec_b2, x, e, nullptr, BS_, D_, H_);
    // g = e @ W2^T
    gemm_nt<<<dim3(H_/64, BS_/64), 256, 0, stream>>>(e, dec_W2, g, BS_, H_, D_);
    // S += J^T J
    jtj_kernel<<<dim3(D_/64, BS_/8), 256, 0, stream>>>(t, dec_W2, dec_W1, S);
    // S += 2 * hess core
    hess_kernel<<<dim3(BS_), 256, 0, stream>>>(t, g, dec_W1, S);
    // eig-min / Cholesky / triangular solves / scalars
    solve_kernel<<<dim3(BS_/4), 256, 0, stream>>>(S, sigm, z_st, eps, z_sm, out);
    // t2 = tanh(z_sample @ dec_W1 + b1) (reuse h)
    gemm_nn<0><<<dim3(H_/64, BS_/64), 256, 0, stream>>>(z_sm, dec_W1, dec_b1, nullptr, h, nullptr, BS_, H_, N_);
    // rowsum of (recon - x)^2
    gemm_nn<2><<<dim3(D_/64, BS_/64), 256, 0, stream>>>(h, dec_W2, dec_b2, x, nullptr, rls, BS_, D_, H_);
    // combine
    finalize_kernel<<<dim3(2), 256, 0, stream>>>(rls, sigm, lsig, out);
}

// Round 2
// 694.547 us; speedup vs baseline: 8.8810x; 8.8810x over previous
//
#include <hip/hip_runtime.h>
#include <hip/hip_bf16.h>
#include <math.h>

#define D_ 3072
#define H_ 2048
#define N_ 16
#define BS_ 512

typedef short s16x8 __attribute__((ext_vector_type(8)));
typedef float f32x4v __attribute__((ext_vector_type(4)));
typedef __hip_bfloat16 bf16;

__device__ __forceinline__ void gload_lds16(const void* g, void* l) {
    __builtin_amdgcn_global_load_lds((const __attribute__((address_space(1))) void*)g,
                                     (__attribute__((address_space(3))) void*)l, 16, 0, 0);
}

__device__ __forceinline__ float bf2f(unsigned short u) {
    unsigned v = (unsigned)u << 16; float f; __builtin_memcpy(&f, &v, 4); return f;
}

enum { EP_TANH_F32 = 0, EP_E_BF = 1, EP_F32 = 2, EP_BF = 3, EP_RECON = 4 };

// C[M,N] = A(M,K) * Bt(N,K)^T, all K-contiguous bf16, fp32 accum. 128x128 tile, BK=32.
template<int EP>
__global__ __launch_bounds__(256) void mfma_nt(
    const bf16* __restrict__ A, const bf16* __restrict__ Bt,
    const float* __restrict__ bias, const float* __restrict__ X,
    float* __restrict__ Cf, bf16* __restrict__ Cb, float* __restrict__ rowsum,
    int M, int N, int K)
{
    __shared__ __align__(16) bf16 As[128 * 32];
    __shared__ __align__(16) bf16 Bs[128 * 32];
    const int tid = threadIdx.x;
    const int w = tid >> 6, l = tid & 63;
    const int wr = w >> 1, wc = w & 1;
    const int m0 = blockIdx.y * 128, n0 = blockIdx.x * 128;

    f32x4v acc[4][4];
    #pragma unroll
    for (int a = 0; a < 4; ++a)
        #pragma unroll
        for (int b = 0; b < 4; ++b) acc[a][b] = (f32x4v){0.f, 0.f, 0.f, 0.f};

    const int srow = l >> 2;        // 0..15
    const int scol = (l & 3) * 8;   // bf16 elements (16B per lane)

    for (int k0 = 0; k0 < K; k0 += 32) {
        #pragma unroll
        for (int q = 0; q < 2; ++q) {
            int r0 = w * 32 + q * 16;
            gload_lds16(&A[(size_t)(m0 + r0 + srow) * K + k0 + scol], &As[r0 * 32]);
            gload_lds16(&Bt[(size_t)(n0 + r0 + srow) * K + k0 + scol], &Bs[r0 * 32]);
        }
        __syncthreads();
        s16x8 af[4], bfr[4];
        #pragma unroll
        for (int mf = 0; mf < 4; ++mf)
            af[mf] = *(const s16x8*)&As[(wr * 64 + mf * 16 + (l & 15)) * 32 + (l >> 4) * 8];
        #pragma unroll
        for (int nf = 0; nf < 4; ++nf)
            bfr[nf] = *(const s16x8*)&Bs[(wc * 64 + nf * 16 + (l & 15)) * 32 + (l >> 4) * 8];
        #pragma unroll
        for (int mf = 0; mf < 4; ++mf)
            #pragma unroll
            for (int nf = 0; nf < 4; ++nf)
                acc[mf][nf] = __builtin_amdgcn_mfma_f32_16x16x32_bf16(af[mf], bfr[nf], acc[mf][nf], 0, 0, 0);
        __syncthreads();
    }

    #pragma unroll
    for (int mf = 0; mf < 4; ++mf) {
        if (EP == EP_RECON) {
            #pragma unroll
            for (int r = 0; r < 4; ++r) {
                int m = m0 + wr * 64 + mf * 16 + (l >> 4) * 4 + r;
                float p = 0.f;
                #pragma unroll
                for (int nf = 0; nf < 4; ++nf) {
                    int n = n0 + wc * 64 + nf * 16 + (l & 15);
                    float v = acc[mf][nf][r] + bias[n] - X[(size_t)m * N + n];
                    p += v * v;
                }
                #pragma unroll
                for (int off = 1; off < 16; off <<= 1) p += __shfl_xor(p, off);
                if ((l & 15) == 0) atomicAdd(&rowsum[m], p);
            }
        } else {
            #pragma unroll
            for (int nf = 0; nf < 4; ++nf) {
                int n = n0 + wc * 64 + nf * 16 + (l & 15);
                #pragma unroll
                for (int r = 0; r < 4; ++r) {
                    int m = m0 + wr * 64 + mf * 16 + (l >> 4) * 4 + r;
                    float v = acc[mf][nf][r];
                    if (EP == EP_TANH_F32)
                        Cf[(size_t)m * N + n] = tanhf(v + bias[n]);
                    else if (EP == EP_E_BF)
                        Cb[(size_t)m * N + n] = __float2bfloat16(X[(size_t)m * N + n] - (v + bias[n]));
                    else if (EP == EP_F32)
                        Cf[(size_t)m * N + n] = v;
                    else
                        Cb[(size_t)m * N + n] = __float2bfloat16(v);
                }
            }
        }
    }
}

// plain fp32 -> bf16 cast, 8 elements/thread
__global__ __launch_bounds__(256) void cast_bf(const float* __restrict__ in, bf16* __restrict__ out, int n8)
{
    int i = blockIdx.x * 256 + threadIdx.x;
    if (i < n8) {
        const float4* p = (const float4*)in + (size_t)i * 2;
        float4 a = p[0], b = p[1];
        union { s16x8 v; bf16 e[8]; } u;
        u.e[0] = __float2bfloat16(a.x); u.e[1] = __float2bfloat16(a.y);
        u.e[2] = __float2bfloat16(a.z); u.e[3] = __float2bfloat16(a.w);
        u.e[4] = __float2bfloat16(b.x); u.e[5] = __float2bfloat16(b.y);
        u.e[6] = __float2bfloat16(b.z); u.e[7] = __float2bfloat16(b.w);
        *(s16x8*)&out[(size_t)i * 8] = u.v;
    }
}

// out[c*R + r] = bf16(in[r*C + c]);  in is R x C
__global__ __launch_bounds__(256) void castT(const float* __restrict__ in, bf16* __restrict__ out, int R, int C)
{
    __shared__ float tile[64][65];
    int r0 = blockIdx.x * 64, c0 = blockIdx.y * 64;
    int tx = threadIdx.x & 63, ty = threadIdx.x >> 6;
    #pragma unroll
    for (int k = 0; k < 16; ++k) {
        int rr = ty * 16 + k;
        tile[rr][tx] = in[(size_t)(r0 + rr) * C + c0 + tx];
    }
    __syncthreads();
    #pragma unroll
    for (int k = 0; k < 16; ++k) {
        int cc = ty * 16 + k;
        out[(size_t)(c0 + cc) * R + r0 + tx] = __float2bfloat16(tile[tx][cc]);
    }
}

// ---------------- z_star / log-sigma / sigma ----------------
__global__ __launch_bounds__(256) void zsig_kernel(const float* __restrict__ h,
    const float* __restrict__ Wmu, const float* __restrict__ bmu,
    const float* __restrict__ Wls, const float* __restrict__ bls,
    float* __restrict__ z_star, float* __restrict__ lsig, float* __restrict__ sigma)
{
    const int b = blockIdx.x, tid = threadIdx.x;
    float acc[17];
    #pragma unroll
    for (int i = 0; i < 17; ++i) acc[i] = 0.f;
    for (int hh = tid; hh < H_; hh += 256) {
        float hv = h[(size_t)b * H_ + hh];
        const float* wr = &Wmu[(size_t)hh * 16];
        #pragma unroll
        for (int i = 0; i < 16; ++i) acc[i] += hv * wr[i];
        acc[16] += hv * Wls[hh];
    }
    __shared__ float red[17][4];
    const int wid = tid >> 6, lane = tid & 63;
    #pragma unroll
    for (int i = 0; i < 17; ++i) {
        float v = acc[i];
        #pragma unroll
        for (int off = 32; off; off >>= 1) v += __shfl_xor(v, off);
        if (lane == 0) red[i][wid] = v;
    }
    __syncthreads();
    if (tid < 17) {
        float v = red[tid][0] + red[tid][1] + red[tid][2] + red[tid][3];
        if (tid < 16) z_star[(size_t)b * 16 + tid] = v + bmu[tid];
        else { float ls = v + bls[0]; lsig[b] = ls; sigma[b] = expf(ls); }
    }
}

// t = tanh(z @ W1 + b1); optional fp32 out + bf16 out. K=16.
__global__ __launch_bounds__(256) void build_t(const float* __restrict__ z,
    const float* __restrict__ W1, const float* __restrict__ b1,
    float* __restrict__ tf, bf16* __restrict__ tb)
{
    __shared__ float zs[16];
    int b = blockIdx.x, tid = threadIdx.x;
    if (tid < 16) zs[tid] = z[(size_t)b * 16 + tid];
    __syncthreads();
    for (int hh = tid; hh < H_; hh += 256) {
        float a = b1[hh];
        #pragma unroll
        for (int i = 0; i < 16; ++i) a += zs[i] * W1[(size_t)i * H_ + hh];
        float tv = tanhf(a);
        if (tf) tf[(size_t)b * H_ + hh] = tv;
        tb[(size_t)b * H_ + hh] = __float2bfloat16(tv);
    }
}

// Vt[(b_local*16+i), h] = (1-t^2) * W1[i,h]  (bf16)
__global__ __launch_bounds__(256) void build_vt(const float* __restrict__ t,
    const float* __restrict__ W1, bf16* __restrict__ Vt, int b0)
{
    int bl = blockIdx.x, b = b0 + bl, tid = threadIdx.x;
    __shared__ float u[H_];
    for (int hh = tid; hh < H_; hh += 256) {
        float tv = t[(size_t)b * H_ + hh];
        u[hh] = 1.f - tv * tv;
    }
    __syncthreads();
    size_t base = (size_t)bl * 16 * H_;
    int hh = tid * 8;
    for (int i = 0; i < 16; ++i) {
        union { s16x8 v; bf16 e[8]; } pk;
        #pragma unroll
        for (int k = 0; k < 8; ++k)
            pk.e[k] = __float2bfloat16(u[hh + k] * W1[(size_t)i * H_ + hh + k]);
        *(s16x8*)&Vt[base + (size_t)i * H_ + hh] = pk.v;
    }
}

// S[b][i][j] = sum_d J[bi,d]*J[bj,d] + sum_h w_h W1[i,h] W1[j,h],  w = 2*g*t*(1-t^2)
__global__ __launch_bounds__(256) void assemble_S(const bf16* __restrict__ J,
    const float* __restrict__ t, const float* __restrict__ g,
    const float* __restrict__ W1, float* __restrict__ S, int b0)
{
    int bl = blockIdx.x, b = b0 + bl, tid = threadIdx.x;
    int i = tid >> 4, j = tid & 15;
    __shared__ __align__(16) bf16 Js[16][520];
    __shared__ __align__(16) float wsh[512];
    __shared__ __align__(16) float W1s[16][516];

    float acc = 0.f;
    for (int d0 = 0; d0 < D_; d0 += 512) {
        __syncthreads();
        for (int q = tid; q < 1024; q += 256) {
            int row = q >> 6, c8 = (q & 63) * 8;
            *(int4*)&Js[row][c8] = *(const int4*)&J[((size_t)bl * 16 + row) * D_ + d0 + c8];
        }
        __syncthreads();
        for (int d = 0; d < 512; d += 8) {
            s16x8 vi = *(const s16x8*)&Js[i][d];
            s16x8 vj = *(const s16x8*)&Js[j][d];
            #pragma unroll
            for (int e = 0; e < 8; ++e)
                acc += bf2f((unsigned short)vi[e]) * bf2f((unsigned short)vj[e]);
        }
    }

    float acc2 = 0.f;
    for (int h0 = 0; h0 < H_; h0 += 512) {
        __syncthreads();
        for (int hh = tid; hh < 512; hh += 256) {
            float tv = t[(size_t)b * H_ + h0 + hh];
            wsh[hh] = 2.f * g[(size_t)b * H_ + h0 + hh] * tv * (1.f - tv * tv);
        }
        for (int q = tid; q < 2048; q += 256) {
            int row = q >> 7, c4 = (q & 127) * 4;
            *(float4*)&W1s[row][c4] = *(const float4*)&W1[(size_t)row * H_ + h0 + c4];
        }
        __syncthreads();
        for (int hh = 0; hh < 512; hh += 4) {
            float4 wv = *(const float4*)&wsh[hh];
            float4 ai = *(const float4*)&W1s[i][hh];
            float4 aj = *(const float4*)&W1s[j][hh];
            acc2 += wv.x * ai.x * aj.x + wv.y * ai.y * aj.y + wv.z * ai.z * aj.z + wv.w * ai.w * aj.w;
        }
    }
    S[(size_t)b * 256 + tid] = acc + acc2;
}

// ---------------- per-batch: lambda_min (bisection), Cholesky, solves, scalars ----------------
__global__ __launch_bounds__(256) void solve_kernel(const float* __restrict__ S,
    const float* __restrict__ sigma, const float* __restrict__ z_star,
    const float* __restrict__ eps, float* __restrict__ z_sample, float* __restrict__ d_out)
{
    __shared__ float Ash[4][16][17];
    __shared__ float Csh[4][16][17];
    __shared__ float Wsh[4][16][17];
    const int tid = threadIdx.x;
    const int wid = tid >> 6, lane = tid & 63;
    const int b = blockIdx.x * 4 + wid;
    float (*A)[17]  = Ash[wid];
    float (*Cm)[17] = Csh[wid];
    float (*W)[17]  = Wsh[wid];
    const float sg = sigma[b];
    const float inv_s2 = 1.0f / (sg * sg);

    for (int l = lane; l < 256; l += 64) {
        int i = l >> 4, j = l & 15;
        A[i][j] = S[(size_t)b * 256 + l] * inv_s2 + (i == j ? 1.0f : 0.f);
    }
    __syncthreads();

    float lo = 1e30f, hi = 1e30f;
    if (lane < 16) {
        float diag = A[lane][lane];
        float r = 0.f;
        #pragma unroll
        for (int j = 0; j < 16; ++j) r += (j == lane) ? 0.f : fabsf(A[lane][j]);
        lo = diag - r;
        hi = diag;
    }
    #pragma unroll
    for (int off = 8; off; off >>= 1) {
        lo = fminf(lo, __shfl_xor(lo, off));
        hi = fminf(hi, __shfl_xor(hi, off));
    }
    lo = __shfl(lo, 0) - 1e-3f;
    hi = __shfl(hi, 0) + 1e-3f;

    const int r4 = lane >> 4;
    const int c  = lane & 15;

    for (int iter = 0; iter < 32; ++iter) {
        float s = 0.5f * (lo + hi);
        for (int l = lane; l < 256; l += 64) {
            int i = l >> 4, j = l & 15;
            Cm[i][j] = A[i][j] - (i == j ? s : 0.f);
        }
        __syncthreads();
        int cnt = 0;
        for (int j = 0; j < 16; ++j) {
            float dpv = Cm[j][j];
            if (fabsf(dpv) < 1e-30f) dpv = -1e-30f;
            cnt += (dpv < 0.f) ? 1 : 0;
            if (j < 15) {
                for (int ib = j + 1 + r4; ib < 16; ib += 4) {
                    if (c > j) {
                        float f = Cm[ib][j] / dpv;
                        Cm[ib][c] -= f * Cm[j][c];
                    }
                }
            }
            __syncthreads();
        }
        if (cnt >= 1) hi = s; else lo = s;
    }

    const float lam_min = 0.5f * (lo + hi);
    const float delta = 10.0f - lam_min;

    for (int l = lane; l < 256; l += 64) {
        int i = l >> 4, j = l & 15;
        Cm[i][j] = A[i][j] + (i == j ? delta : 0.f);
    }
    __syncthreads();
    for (int j = 0; j < 16; ++j) {
        float dj = sqrtf(Cm[j][j]);
        __syncthreads();
        if (lane < 16) {
            if (lane == j) Cm[j][j] = dj;
            else if (lane > j) Cm[lane][j] = Cm[lane][j] / dj;
        }
        __syncthreads();
        if (j < 15) {
            for (int ib = j + 1 + r4; ib < 16; ib += 4) {
                if (c > j && c <= ib) Cm[ib][c] -= Cm[ib][j] * Cm[c][j];
            }
        }
        __syncthreads();
    }

    if (lane < 16) {
        int cc = lane;
        W[cc][cc] = 1.0f / Cm[cc][cc];
        for (int i = cc + 1; i < 16; ++i) {
            float sm = 0.f;
            for (int k = cc; k < i; ++k) sm += Cm[i][k] * W[k][cc];
            W[i][cc] = -sm / Cm[i][i];
        }
    }
    __syncthreads();

    float tr = 0.f, zsq = 0.f, ldv = 0.f;
    if (lane < 16) {
        for (int i = lane; i < 16; ++i) tr += W[i][lane] * W[i][lane];
        float zv = z_star[(size_t)b * 16 + lane];
        zsq = zv * zv;
        ldv = logf(Cm[lane][lane]);
        float a = 0.f;
        for (int jj = lane; jj < 16; ++jj) a += W[jj][lane] * eps[(size_t)b * 16 + jj];
        z_sample[(size_t)b * 16 + lane] = zv + a;
    }
    #pragma unroll
    for (int off = 8; off; off >>= 1) {
        tr  += __shfl_xor(tr, off);
        zsq += __shfl_xor(zsq, off);
        ldv += __shfl_xor(ldv, off);
    }
    if (lane == 0) {
        d_out[2 * 512 + b] = 0.5f * zsq + 0.5f * tr;
        d_out[3 * 512 + b] = ldv;
        d_out[4 * 512 + b] = sg;
    }
}

__global__ void finalize_kernel(const float* __restrict__ rlsum, const float* __restrict__ sigma,
    const float* __restrict__ lsig, float* __restrict__ d_out)
{
    int b = blockIdx.x * 256 + threadIdx.x;
    if (b < BS_) {
        float sg = sigma[b];
        float rl = rlsum[b] / (2.0f * sg * sg);
        float le = d_out[2 * 512 + b];
        float ld = d_out[3 * 512 + b];
        d_out[b] = (rl + le + ld) / 3072.0f + lsig[b];
        d_out[512 + b] = rl;
    }
}

extern "C" void kernel_launch(void* const* d_in, const int* in_sizes, int n_in,
                              void* d_out, int out_size, void* d_ws, size_t ws_size,
                              hipStream_t stream)
{
    const float* x       = (const float*)d_in[0];
    const float* eps     = (const float*)d_in[1];
    const float* enc_W1  = (const float*)d_in[2];
    const float* enc_b1  = (const float*)d_in[3];
    const float* enc_Wmu = (const float*)d_in[4];
    const float* enc_bmu = (const float*)d_in[5];
    const float* enc_Wls = (const float*)d_in[6];
    const float* enc_bls = (const float*)d_in[7];
    const float* dec_W1  = (const float*)d_in[8];
    const float* dec_b1  = (const float*)d_in[9];
    const float* dec_W2  = (const float*)d_in[10];
    const float* dec_b2  = (const float*)d_in[11];
    float* out = (float*)d_out;

    char* wsb = (char*)d_ws;
    size_t off = 0;
    auto alloc = [&](size_t bytes) -> void* {
        off = (off + 255) & ~(size_t)255;
        void* p = wsb + off;
        off += bytes;
        return p;
    };

    float* h    = (float*)alloc((size_t)BS_ * H_ * 4);
    float* t    = (float*)alloc((size_t)BS_ * H_ * 4);
    float* g    = (float*)alloc((size_t)BS_ * H_ * 4);
    float* z_st = (float*)alloc((size_t)BS_ * 16 * 4);
    float* lsig = (float*)alloc(BS_ * 4);
    float* sigm = (float*)alloc(BS_ * 4);
    float* z_sm = (float*)alloc((size_t)BS_ * 16 * 4);
    float* rls  = (float*)alloc(BS_ * 4);
    float* S    = (float*)alloc((size_t)BS_ * 256 * 4);
    bf16* x_bf  = (bf16*)alloc((size_t)BS_ * D_ * 2);
    bf16* eW1t  = (bf16*)alloc((size_t)H_ * D_ * 2);
    bf16* W2b   = (bf16*)alloc((size_t)H_ * D_ * 2);
    bf16* W2t   = (bf16*)alloc((size_t)D_ * H_ * 2);
    bf16* t_bf  = (bf16*)alloc((size_t)BS_ * H_ * 2);
    bf16* e_bf  = (bf16*)alloc((size_t)BS_ * D_ * 2);
    bf16* t2b   = (bf16*)alloc((size_t)BS_ * H_ * 2);

    // pick J-chunk size that fits the workspace
    int nb = 0;
    size_t base_off = off;
    const int cand[3] = {512, 128, 32};
    bf16* Vt = nullptr; bf16* Jb = nullptr;
    for (int ci = 0; ci < 3; ++ci) {
        off = base_off;
        int n = cand[ci];
        bf16* vt = (bf16*)alloc((size_t)n * 16 * H_ * 2);
        bf16* jb = (bf16*)alloc((size_t)n * 16 * D_ * 2);
        if (off <= ws_size) { nb = n; Vt = vt; Jb = jb; break; }
    }
    if (nb == 0) return;

    // casts
    cast_bf<<<dim3((BS_ * D_ / 8 + 255) / 256), 256, 0, stream>>>(x, x_bf, BS_ * D_ / 8);
    castT<<<dim3(D_ / 64, H_ / 64), 256, 0, stream>>>(enc_W1, eW1t, D_, H_);
    cast_bf<<<dim3((H_ * D_ / 8 + 255) / 256), 256, 0, stream>>>(dec_W2, W2b, H_ * D_ / 8);
    castT<<<dim3(H_ / 64, D_ / 64), 256, 0, stream>>>(dec_W2, W2t, H_, D_);

    // h = tanh(x @ enc_W1 + b1)
    mfma_nt<EP_TANH_F32><<<dim3(H_ / 128, BS_ / 128), 256, 0, stream>>>(
        x_bf, eW1t, enc_b1, nullptr, h, nullptr, nullptr, BS_, H_, D_);
    // z_star, sigma
    zsig_kernel<<<dim3(BS_), 256, 0, stream>>>(h, enc_Wmu, enc_bmu, enc_Wls, enc_bls, z_st, lsig, sigm);
    // t = tanh(z_star @ dec_W1 + b1)
    build_t<<<dim3(BS_), 256, 0, stream>>>(z_st, dec_W1, dec_b1, t, t_bf);
    // e = x - (t @ W2 + b2)   (bf16 out)
    mfma_nt<EP_E_BF><<<dim3(D_ / 128, BS_ / 128), 256, 0, stream>>>(
        t_bf, W2t, dec_b2, x, nullptr, e_bf, nullptr, BS_, D_, H_);
    // g = e @ W2^T
    mfma_nt<EP_F32><<<dim3(H_ / 128, BS_ / 128), 256, 0, stream>>>(
        e_bf, W2b, nullptr, nullptr, g, nullptr, nullptr, BS_, H_, D_);

    // J = Vt @ W2t^T, then S = J^T J + hess (chunked over batches)
    for (int b0 = 0; b0 < BS_; b0 += nb) {
        build_vt<<<dim3(nb), 256, 0, stream>>>(t, dec_W1, Vt, b0);
        mfma_nt<EP_BF><<<dim3(D_ / 128, nb * 16 / 128), 256, 0, stream>>>(
            Vt, W2t, nullptr, nullptr, nullptr, Jb, nullptr, nb * 16, D_, H_);
        assemble_S<<<dim3(nb), 256, 0, stream>>>(Jb, t, g, dec_W1, S, b0);
    }

    // eig-min / Cholesky / solves / scalars
    solve_kernel<<<dim3(BS_ / 4), 256, 0, stream>>>(S, sigm, z_st, eps, z_sm, out);
    // t2 = tanh(z_sample @ dec_W1 + b1)  (bf16 only)
    build_t<<<dim3(BS_), 256, 0, stream>>>(z_sm, dec_W1, dec_b1, nullptr, t2b);
    hipMemsetAsync(rls, 0, BS_ * 4, stream);
    // rowsum of (recon - x)^2
    mfma_nt<EP_RECON><<<dim3(D_ / 128, BS_ / 128), 256, 0, stream>>>(
        t2b, W2t, dec_b2, x, nullptr, nullptr, rls, BS_, D_, H_);
    finalize_kernel<<<dim3(2), 256, 0, stream>>>(rls, sigm, lsig, out);
}

// Round 3
// 525.630 us; speedup vs baseline: 11.7350x; 1.3214x over previous
//
#include <hip/hip_runtime.h>
#include <hip/hip_bf16.h>
#include <math.h>

#define D_ 3072
#define H_ 2048
#define N_ 16
#define BS_ 512

typedef short s16x8 __attribute__((ext_vector_type(8)));
typedef float f32x4v __attribute__((ext_vector_type(4)));
typedef __hip_bfloat16 bf16;

__device__ __forceinline__ void gload_lds16(const void* g, void* l) {
    __builtin_amdgcn_global_load_lds((const __attribute__((address_space(1))) void*)g,
                                     (__attribute__((address_space(3))) void*)l, 16, 0, 0);
}

__device__ __forceinline__ float bf2f(unsigned short u) {
    unsigned v = (unsigned)u << 16; float f; __builtin_memcpy(&f, &v, 4); return f;
}

enum { EP_TANH_F32 = 0, EP_E_BF = 1, EP_F32 = 2, EP_BF = 3, EP_RECON = 4 };

// C[M,N] = A(M,K) * Bt(N,K)^T, all K-contiguous bf16, fp32 accum. 128x128 tile, BK=32.
template<int EP>
__global__ __launch_bounds__(256) void mfma_nt(
    const bf16* __restrict__ A, const bf16* __restrict__ Bt,
    const float* __restrict__ bias, const float* __restrict__ X,
    float* __restrict__ Cf, bf16* __restrict__ Cb, float* __restrict__ rowsum,
    int M, int N, int K)
{
    __shared__ __align__(16) bf16 As[128 * 32];
    __shared__ __align__(16) bf16 Bs[128 * 32];
    const int tid = threadIdx.x;
    const int w = tid >> 6, l = tid & 63;
    const int wr = w >> 1, wc = w & 1;
    const int m0 = blockIdx.y * 128, n0 = blockIdx.x * 128;

    f32x4v acc[4][4];
    #pragma unroll
    for (int a = 0; a < 4; ++a)
        #pragma unroll
        for (int b = 0; b < 4; ++b) acc[a][b] = (f32x4v){0.f, 0.f, 0.f, 0.f};

    const int srow = l >> 2;        // 0..15
    const int scol = (l & 3) * 8;   // bf16 elements (16B per lane)

    for (int k0 = 0; k0 < K; k0 += 32) {
        #pragma unroll
        for (int q = 0; q < 2; ++q) {
            int r0 = w * 32 + q * 16;
            gload_lds16(&A[(size_t)(m0 + r0 + srow) * K + k0 + scol], &As[r0 * 32]);
            gload_lds16(&Bt[(size_t)(n0 + r0 + srow) * K + k0 + scol], &Bs[r0 * 32]);
        }
        __syncthreads();
        s16x8 af[4], bfr[4];
        #pragma unroll
        for (int mf = 0; mf < 4; ++mf)
            af[mf] = *(const s16x8*)&As[(wr * 64 + mf * 16 + (l & 15)) * 32 + (l >> 4) * 8];
        #pragma unroll
        for (int nf = 0; nf < 4; ++nf)
            bfr[nf] = *(const s16x8*)&Bs[(wc * 64 + nf * 16 + (l & 15)) * 32 + (l >> 4) * 8];
        #pragma unroll
        for (int mf = 0; mf < 4; ++mf)
            #pragma unroll
            for (int nf = 0; nf < 4; ++nf)
                acc[mf][nf] = __builtin_amdgcn_mfma_f32_16x16x32_bf16(af[mf], bfr[nf], acc[mf][nf], 0, 0, 0);
        __syncthreads();
    }

    #pragma unroll
    for (int mf = 0; mf < 4; ++mf) {
        if (EP == EP_RECON) {
            #pragma unroll
            for (int r = 0; r < 4; ++r) {
                int m = m0 + wr * 64 + mf * 16 + (l >> 4) * 4 + r;
                float p = 0.f;
                #pragma unroll
                for (int nf = 0; nf < 4; ++nf) {
                    int n = n0 + wc * 64 + nf * 16 + (l & 15);
                    float v = acc[mf][nf][r] + bias[n] - X[(size_t)m * N + n];
                    p += v * v;
                }
                #pragma unroll
                for (int off = 1; off < 16; off <<= 1) p += __shfl_xor(p, off);
                if ((l & 15) == 0) atomicAdd(&rowsum[m], p);
            }
        } else {
            #pragma unroll
            for (int nf = 0; nf < 4; ++nf) {
                int n = n0 + wc * 64 + nf * 16 + (l & 15);
                #pragma unroll
                for (int r = 0; r < 4; ++r) {
                    int m = m0 + wr * 64 + mf * 16 + (l >> 4) * 4 + r;
                    float v = acc[mf][nf][r];
                    if (EP == EP_TANH_F32)
                        Cf[(size_t)m * N + n] = tanhf(v + bias[n]);
                    else if (EP == EP_E_BF)
                        Cb[(size_t)m * N + n] = __float2bfloat16(X[(size_t)m * N + n] - (v + bias[n]));
                    else if (EP == EP_F32)
                        Cf[(size_t)m * N + n] = v;
                    else
                        Cb[(size_t)m * N + n] = __float2bfloat16(v);
                }
            }
        }
    }
}

// plain fp32 -> bf16 cast, 8 elements/thread
__global__ __launch_bounds__(256) void cast_bf(const float* __restrict__ in, bf16* __restrict__ out, int n8)
{
    int i = blockIdx.x * 256 + threadIdx.x;
    if (i < n8) {
        const float4* p = (const float4*)in + (size_t)i * 2;
        float4 a = p[0], b = p[1];
        union { s16x8 v; bf16 e[8]; } u;
        u.e[0] = __float2bfloat16(a.x); u.e[1] = __float2bfloat16(a.y);
        u.e[2] = __float2bfloat16(a.z); u.e[3] = __float2bfloat16(a.w);
        u.e[4] = __float2bfloat16(b.x); u.e[5] = __float2bfloat16(b.y);
        u.e[6] = __float2bfloat16(b.z); u.e[7] = __float2bfloat16(b.w);
        *(s16x8*)&out[(size_t)i * 8] = u.v;
    }
}

// out[c*R + r] = bf16(in[r*C + c]);  in is R x C
__global__ __launch_bounds__(256) void castT(const float* __restrict__ in, bf16* __restrict__ out, int R, int C)
{
    __shared__ float tile[64][65];
    int r0 = blockIdx.x * 64, c0 = blockIdx.y * 64;
    int tx = threadIdx.x & 63, ty = threadIdx.x >> 6;
    #pragma unroll
    for (int k = 0; k < 16; ++k) {
        int rr = ty * 16 + k;
        tile[rr][tx] = in[(size_t)(r0 + rr) * C + c0 + tx];
    }
    __syncthreads();
    #pragma unroll
    for (int k = 0; k < 16; ++k) {
        int cc = ty * 16 + k;
        out[(size_t)(c0 + cc) * R + r0 + tx] = __float2bfloat16(tile[tx][cc]);
    }
}

// ---------------- z_star / log-sigma / sigma ----------------
__global__ __launch_bounds__(256) void zsig_kernel(const float* __restrict__ h,
    const float* __restrict__ Wmu, const float* __restrict__ bmu,
    const float* __restrict__ Wls, const float* __restrict__ bls,
    float* __restrict__ z_star, float* __restrict__ lsig, float* __restrict__ sigma)
{
    const int b = blockIdx.x, tid = threadIdx.x;
    float acc[17];
    #pragma unroll
    for (int i = 0; i < 17; ++i) acc[i] = 0.f;
    for (int hh = tid; hh < H_; hh += 256) {
        float hv = h[(size_t)b * H_ + hh];
        const float* wr = &Wmu[(size_t)hh * 16];
        #pragma unroll
        for (int i = 0; i < 16; ++i) acc[i] += hv * wr[i];
        acc[16] += hv * Wls[hh];
    }
    __shared__ float red[17][4];
    const int wid = tid >> 6, lane = tid & 63;
    #pragma unroll
    for (int i = 0; i < 17; ++i) {
        float v = acc[i];
        #pragma unroll
        for (int off = 32; off; off >>= 1) v += __shfl_xor(v, off);
        if (lane == 0) red[i][wid] = v;
    }
    __syncthreads();
    if (tid < 17) {
        float v = red[tid][0] + red[tid][1] + red[tid][2] + red[tid][3];
        if (tid < 16) z_star[(size_t)b * 16 + tid] = v + bmu[tid];
        else { float ls = v + bls[0]; lsig[b] = ls; sigma[b] = expf(ls); }
    }
}

// t = tanh(z @ W1 + b1); optional fp32 out + bf16 out. K=16.
__global__ __launch_bounds__(256) void build_t(const float* __restrict__ z,
    const float* __restrict__ W1, const float* __restrict__ b1,
    float* __restrict__ tf, bf16* __restrict__ tb)
{
    __shared__ float zs[16];
    int b = blockIdx.x, tid = threadIdx.x;
    if (tid < 16) zs[tid] = z[(size_t)b * 16 + tid];
    __syncthreads();
    for (int hh = tid; hh < H_; hh += 256) {
        float a = b1[hh];
        #pragma unroll
        for (int i = 0; i < 16; ++i) a += zs[i] * W1[(size_t)i * H_ + hh];
        float tv = tanhf(a);
        if (tf) tf[(size_t)b * H_ + hh] = tv;
        tb[(size_t)b * H_ + hh] = __float2bfloat16(tv);
    }
}

// Vt[(b_local*16+i), h] = (1-t^2) * W1[i,h]  (bf16)
__global__ __launch_bounds__(256) void build_vt(const float* __restrict__ t,
    const float* __restrict__ W1, bf16* __restrict__ Vt, int b0)
{
    int bl = blockIdx.x, b = b0 + bl, tid = threadIdx.x;
    __shared__ float u[H_];
    for (int hh = tid; hh < H_; hh += 256) {
        float tv = t[(size_t)b * H_ + hh];
        u[hh] = 1.f - tv * tv;
    }
    __syncthreads();
    size_t base = (size_t)bl * 16 * H_;
    int hh = tid * 8;
    for (int i = 0; i < 16; ++i) {
        union { s16x8 v; bf16 e[8]; } pk;
        #pragma unroll
        for (int k = 0; k < 8; ++k)
            pk.e[k] = __float2bfloat16(u[hh + k] * W1[(size_t)i * H_ + hh + k]);
        *(s16x8*)&Vt[base + (size_t)i * H_ + hh] = pk.v;
    }
}

// S[b][i][j] = sum_d J[bi,d]*J[bj,d] + sum_h w_h W1[i,h] W1[j,h],  w = 2*g*t*(1-t^2)
__global__ __launch_bounds__(256) void assemble_S(const bf16* __restrict__ J,
    const float* __restrict__ t, const float* __restrict__ g,
    const float* __restrict__ W1, float* __restrict__ S, int b0)
{
    int bl = blockIdx.x, b = b0 + bl, tid = threadIdx.x;
    int i = tid >> 4, j = tid & 15;
    __shared__ __align__(16) bf16 Js[16][520];
    __shared__ __align__(16) float wsh[512];
    __shared__ __align__(16) float W1s[16][516];

    float acc = 0.f;
    for (int d0 = 0; d0 < D_; d0 += 512) {
        __syncthreads();
        for (int q = tid; q < 1024; q += 256) {
            int row = q >> 6, c8 = (q & 63) * 8;
            *(int4*)&Js[row][c8] = *(const int4*)&J[((size_t)bl * 16 + row) * D_ + d0 + c8];
        }
        __syncthreads();
        for (int d = 0; d < 512; d += 8) {
            s16x8 vi = *(const s16x8*)&Js[i][d];
            s16x8 vj = *(const s16x8*)&Js[j][d];
            #pragma unroll
            for (int e = 0; e < 8; ++e)
                acc += bf2f((unsigned short)vi[e]) * bf2f((unsigned short)vj[e]);
        }
    }

    float acc2 = 0.f;
    for (int h0 = 0; h0 < H_; h0 += 512) {
        __syncthreads();
        for (int hh = tid; hh < 512; hh += 256) {
            float tv = t[(size_t)b * H_ + h0 + hh];
            wsh[hh] = 2.f * g[(size_t)b * H_ + h0 + hh] * tv * (1.f - tv * tv);
        }
        for (int q = tid; q < 2048; q += 256) {
            int row = q >> 7, c4 = (q & 127) * 4;
            *(float4*)&W1s[row][c4] = *(const float4*)&W1[(size_t)row * H_ + h0 + c4];
        }
        __syncthreads();
        for (int hh = 0; hh < 512; hh += 4) {
            float4 wv = *(const float4*)&wsh[hh];
            float4 ai = *(const float4*)&W1s[i][hh];
            float4 aj = *(const float4*)&W1s[j][hh];
            acc2 += wv.x * ai.x * aj.x + wv.y * ai.y * aj.y + wv.z * ai.z * aj.z + wv.w * ai.w * aj.w;
        }
    }
    S[(size_t)b * 256 + tid] = acc + acc2;
}

// ---------------- per-batch 16x16: barrier-free register solve ----------------
// One wave = 4 matrices (16-lane groups, column-per-lane). No LDS, no barriers.
__global__ __launch_bounds__(64) void solve_kernel(const float* __restrict__ S,
    const float* __restrict__ sigma, const float* __restrict__ z_star,
    const float* __restrict__ eps, float* __restrict__ z_sample, float* __restrict__ d_out)
{
    const int lane = threadIdx.x;
    const int q = lane >> 4;       // matrix within wave
    const int j = lane & 15;       // column owned by this lane
    const int b = blockIdx.x * 4 + q;

    const float sg = sigma[b];
    const float inv_s2 = 1.0f / (sg * sg);

    // a0 = original A (column j), a = working copy for tridiagonalization
    float a0[16], a[16];
    #pragma unroll
    for (int r = 0; r < 16; ++r) {
        a0[r] = S[(size_t)b * 256 + r * 16 + j] * inv_s2 + ((r == j) ? 1.0f : 0.0f);
        a[r] = a0[r];
    }

    // ---- Householder tridiagonalization (14 reflections) ----
    #pragma unroll
    for (int k = 0; k < 14; ++k) {
        // column k of current matrix, via symmetry: x[r] = A[r][k] = lane r's a[k]
        float x[16];
        #pragma unroll
        for (int r = 0; r < 16; ++r) x[r] = __shfl(a[k], r, 16);
        float sig2 = 0.f;
        #pragma unroll
        for (int r = 0; r < 16; ++r) if (r > k + 1) sig2 += x[r] * x[r];
        float x0 = x[k + 1];
        float normx = sqrtf(sig2 + x0 * x0);
        float alpha = (x0 >= 0.f) ? -normx : normx;
        float v[16];
        #pragma unroll
        for (int r = 0; r < 16; ++r)
            v[r] = (r <= k) ? 0.f : ((r == k + 1) ? x0 - alpha : x[r]);
        float vtv = 0.f;
        #pragma unroll
        for (int r = 0; r < 16; ++r) vtv += v[r] * v[r];
        float beta = (vtv > 1e-28f) ? 2.0f / vtv : 0.f;
        // s_j = (A v)[j]  (dot of own column with v, valid by symmetry)
        float sj = 0.f;
        #pragma unroll
        for (int r = 0; r < 16; ++r) sj += a[r] * v[r];
        float av[16];
        #pragma unroll
        for (int r = 0; r < 16; ++r) av[r] = __shfl(sj, r, 16);
        float vtav = 0.f;
        #pragma unroll
        for (int r = 0; r < 16; ++r) vtav += v[r] * av[r];
        float c = 0.5f * beta * vtav;
        float wv[16];
        #pragma unroll
        for (int r = 0; r < 16; ++r) wv[r] = beta * (av[r] - c * v[r]);
        // per-lane v_j, w_j without runtime indexing (A[j][k] == a[k] by symmetry)
        float vj = (j <= k) ? 0.f : ((j == k + 1) ? a[k] - alpha : a[k]);
        float wj = beta * (sj - c * vj);
        #pragma unroll
        for (int r = 0; r < 16; ++r) a[r] -= v[r] * wj + wv[r] * vj;
    }

    // extract tridiagonal (all lanes get full d[], e[])
    float dg[16], eo[15];
    #pragma unroll
    for (int r = 0; r < 16; ++r) dg[r] = __shfl(a[r], r, 16);
    #pragma unroll
    for (int r = 0; r < 15; ++r) eo[r] = __shfl(a[r + 1], r, 16);

    // Gershgorin bracket for lambda_min
    float lo = 1e30f, hi = 1e30f;
    #pragma unroll
    for (int r = 0; r < 16; ++r) {
        float rad = ((r > 0) ? fabsf(eo[r - 1]) : 0.f) + ((r < 15) ? fabsf(eo[r]) : 0.f);
        lo = fminf(lo, dg[r] - rad);
        hi = fminf(hi, dg[r]);
    }
    lo -= 1e-4f; hi += 1e-4f;

    // ---- multisection: 16 lanes evaluate 16 shifts per pass ----
    #pragma unroll
    for (int pass = 0; pass < 5; ++pass) {
        float step = (hi - lo) * (1.0f / 17.0f);
        float s = lo + step * (float)(j + 1);
        float qq = dg[0] - s;
        int cnt = (qq < 0.f) ? 1 : 0;
        #pragma unroll
        for (int i = 1; i < 16; ++i) {
            float denom = (fabsf(qq) < 1e-30f) ? -1e-30f : qq;
            qq = dg[i] - s - eo[i - 1] * eo[i - 1] / denom;
            cnt += (qq < 0.f) ? 1 : 0;
        }
        unsigned long long bal = __ballot(cnt >= 1);
        unsigned grp = (unsigned)((bal >> (q * 16)) & 0xffffull);
        int f = grp ? (__ffs(grp) - 1) : 16;
        float nlo = lo + step * (float)f;
        float nhi = (f < 16) ? (lo + step * (float)(f + 1)) : hi;
        lo = nlo; hi = nhi;
    }
    const float lam_min = 0.5f * (lo + hi);
    const float delta = 10.0f - lam_min;

    // ---- Cholesky of B = A + delta*I (column-per-lane) ----
    float bm[16];
    #pragma unroll
    for (int r = 0; r < 16; ++r) bm[r] = a0[r] + ((r == j) ? delta : 0.f);

    float ldsum = 0.f;
    #pragma unroll
    for (int kk = 0; kk < 16; ++kk) {
        float ck[16];
        #pragma unroll
        for (int r = 0; r < 16; ++r) ck[r] = __shfl(bm[kk], r, 16);  // row kk == col kk (symmetric)
        float dkk = sqrtf(fmaxf(ck[kk], 1e-30f));
        float inv = 1.0f / dkk;
        ldsum += logf(dkk);
        float lfull[16];
        #pragma unroll
        for (int r = 0; r < 16; ++r) lfull[r] = ck[r] * inv;
        float lj = bm[kk] * inv;   // L[j][kk] via symmetry (valid for j >= kk)
        if (j == kk) {
            #pragma unroll
            for (int r = 0; r < 16; ++r) bm[r] = (r >= kk) ? lfull[r] : 0.f;
        } else if (j > kk) {
            #pragma unroll
            for (int r = 0; r < 16; ++r)
                if (r > kk) bm[r] -= lfull[r] * lj;
        }
    }

    // ---- W = L^{-1}, lane j computes column j ----
    float w[16];
    #pragma unroll
    for (int r = 0; r < 16; ++r) w[r] = 0.f;
    #pragma unroll
    for (int i = 0; i < 16; ++i) {
        float row[16];
        #pragma unroll
        for (int kx = 0; kx < 16; ++kx) row[kx] = __shfl(bm[i], kx, 16);  // L[i][kx]
        float sacc = 0.f;
        #pragma unroll
        for (int kx = 0; kx < 16; ++kx) if (kx < i) sacc += row[kx] * w[kx];
        float invd = 1.0f / row[i];
        float val = (i == j) ? invd : (-sacc * invd);
        w[i] = (i >= j) ? val : 0.f;
    }

    // trace(Prec^{-1}) = ||W||_F^2 ; z_off = W^T eps ; scalars
    float tsum = 0.f;
    #pragma unroll
    for (int r = 0; r < 16; ++r) tsum += w[r] * w[r];
    float zv = z_star[(size_t)b * 16 + j];
    float ep = eps[(size_t)b * 16 + j];
    float epsv[16];
    #pragma unroll
    for (int r = 0; r < 16; ++r) epsv[r] = __shfl(ep, r, 16);
    float zoff = 0.f;
    #pragma unroll
    for (int r = 0; r < 16; ++r) zoff += w[r] * epsv[r];
    z_sample[(size_t)b * 16 + j] = zv + zoff;

    float zsq = zv * zv;
    #pragma unroll
    for (int off = 1; off < 16; off <<= 1) {
        tsum += __shfl_xor(tsum, off);
        zsq  += __shfl_xor(zsq, off);
    }
    if (j == 0) {
        d_out[2 * 512 + b] = 0.5f * zsq + 0.5f * tsum;  // latent_energy
        d_out[3 * 512 + b] = ldsum;                     // logdet_loss
        d_out[4 * 512 + b] = sg;                        // sigma
    }
}

__global__ void finalize_kernel(const float* __restrict__ rlsum, const float* __restrict__ sigma,
    const float* __restrict__ lsig, float* __restrict__ d_out)
{
    int b = blockIdx.x * 256 + threadIdx.x;
    if (b < BS_) {
        float sg = sigma[b];
        float rl = rlsum[b] / (2.0f * sg * sg);
        float le = d_out[2 * 512 + b];
        float ld = d_out[3 * 512 + b];
        d_out[b] = (rl + le + ld) / 3072.0f + lsig[b];
        d_out[512 + b] = rl;
    }
}

extern "C" void kernel_launch(void* const* d_in, const int* in_sizes, int n_in,
                              void* d_out, int out_size, void* d_ws, size_t ws_size,
                              hipStream_t stream)
{
    const float* x       = (const float*)d_in[0];
    const float* eps     = (const float*)d_in[1];
    const float* enc_W1  = (const float*)d_in[2];
    const float* enc_b1  = (const float*)d_in[3];
    const float* enc_Wmu = (const float*)d_in[4];
    const float* enc_bmu = (const float*)d_in[5];
    const float* enc_Wls = (const float*)d_in[6];
    const float* enc_bls = (const float*)d_in[7];
    const float* dec_W1  = (const float*)d_in[8];
    const float* dec_b1  = (const float*)d_in[9];
    const float* dec_W2  = (const float*)d_in[10];
    const float* dec_b2  = (const float*)d_in[11];
    float* out = (float*)d_out;

    char* wsb = (char*)d_ws;
    size_t off = 0;
    auto alloc = [&](size_t bytes) -> void* {
        off = (off + 255) & ~(size_t)255;
        void* p = wsb + off;
        off += bytes;
        return p;
    };

    float* h    = (float*)alloc((size_t)BS_ * H_ * 4);
    float* t    = (float*)alloc((size_t)BS_ * H_ * 4);
    float* g    = (float*)alloc((size_t)BS_ * H_ * 4);
    float* z_st = (float*)alloc((size_t)BS_ * 16 * 4);
    float* lsig = (float*)alloc(BS_ * 4);
    float* sigm = (float*)alloc(BS_ * 4);
    float* z_sm = (float*)alloc((size_t)BS_ * 16 * 4);
    float* rls  = (float*)alloc(BS_ * 4);
    float* S    = (float*)alloc((size_t)BS_ * 256 * 4);
    bf16* x_bf  = (bf16*)alloc((size_t)BS_ * D_ * 2);
    bf16* eW1t  = (bf16*)alloc((size_t)H_ * D_ * 2);
    bf16* W2b   = (bf16*)alloc((size_t)H_ * D_ * 2);
    bf16* W2t   = (bf16*)alloc((size_t)D_ * H_ * 2);
    bf16* t_bf  = (bf16*)alloc((size_t)BS_ * H_ * 2);
    bf16* e_bf  = (bf16*)alloc((size_t)BS_ * D_ * 2);
    bf16* t2b   = (bf16*)alloc((size_t)BS_ * H_ * 2);

    // pick J-chunk size that fits the workspace
    int nb = 0;
    size_t base_off = off;
    const int cand[3] = {512, 128, 32};
    bf16* Vt = nullptr; bf16* Jb = nullptr;
    for (int ci = 0; ci < 3; ++ci) {
        off = base_off;
        int n = cand[ci];
        bf16* vt = (bf16*)alloc((size_t)n * 16 * H_ * 2);
        bf16* jb = (bf16*)alloc((size_t)n * 16 * D_ * 2);
        if (off <= ws_size) { nb = n; Vt = vt; Jb = jb; break; }
    }
    if (nb == 0) return;

    // casts
    cast_bf<<<dim3((BS_ * D_ / 8 + 255) / 256), 256, 0, stream>>>(x, x_bf, BS_ * D_ / 8);
    castT<<<dim3(D_ / 64, H_ / 64), 256, 0, stream>>>(enc_W1, eW1t, D_, H_);
    cast_bf<<<dim3((H_ * D_ / 8 + 255) / 256), 256, 0, stream>>>(dec_W2, W2b, H_ * D_ / 8);
    castT<<<dim3(H_ / 64, D_ / 64), 256, 0, stream>>>(dec_W2, W2t, H_, D_);

    // h = tanh(x @ enc_W1 + b1)
    mfma_nt<EP_TANH_F32><<<dim3(H_ / 128, BS_ / 128), 256, 0, stream>>>(
        x_bf, eW1t, enc_b1, nullptr, h, nullptr, nullptr, BS_, H_, D_);
    // z_star, sigma
    zsig_kernel<<<dim3(BS_), 256, 0, stream>>>(h, enc_Wmu, enc_bmu, enc_Wls, enc_bls, z_st, lsig, sigm);
    // t = tanh(z_star @ dec_W1 + b1)
    build_t<<<dim3(BS_), 256, 0, stream>>>(z_st, dec_W1, dec_b1, t, t_bf);
    // e = x - (t @ W2 + b2)   (bf16 out)
    mfma_nt<EP_E_BF><<<dim3(D_ / 128, BS_ / 128), 256, 0, stream>>>(
        t_bf, W2t, dec_b2, x, nullptr, e_bf, nullptr, BS_, D_, H_);
    // g = e @ W2^T
    mfma_nt<EP_F32><<<dim3(H_ / 128, BS_ / 128), 256, 0, stream>>>(
        e_bf, W2b, nullptr, nullptr, g, nullptr, nullptr, BS_, H_, D_);

    // J = Vt @ W2t^T, then S = J^T J + hess (chunked over batches)
    for (int b0 = 0; b0 < BS_; b0 += nb) {
        build_vt<<<dim3(nb), 256, 0, stream>>>(t, dec_W1, Vt, b0);
        mfma_nt<EP_BF><<<dim3(D_ / 128, nb * 16 / 128), 256, 0, stream>>>(
            Vt, W2t, nullptr, nullptr, nullptr, Jb, nullptr, nb * 16, D_, H_);
        assemble_S<<<dim3(nb), 256, 0, stream>>>(Jb, t, g, dec_W1, S, b0);
    }

    // eig-min / Cholesky / solves / scalars (barrier-free register solve)
    solve_kernel<<<dim3(BS_ / 4), 64, 0, stream>>>(S, sigm, z_st, eps, z_sm, out);
    // t2 = tanh(z_sample @ dec_W1 + b1)  (bf16 only)
    build_t<<<dim3(BS_), 256, 0, stream>>>(z_sm, dec_W1, dec_b1, nullptr, t2b);
    hipMemsetAsync(rls, 0, BS_ * 4, stream);
    // rowsum of (recon - x)^2
    mfma_nt<EP_RECON><<<dim3(D_ / 128, BS_ / 128), 256, 0, stream>>>(
        t2b, W2t, dec_b2, x, nullptr, nullptr, rls, BS_, D_, H_);
    finalize_kernel<<<dim3(2), 256, 0, stream>>>(rls, sigm, lsig, out);
}

// Round 4
// 464.461 us; speedup vs baseline: 13.2806x; 1.1317x over previous
//
#include <hip/hip_runtime.h>
#include <hip/hip_bf16.h>
#include <math.h>

#define D_ 3072
#define H_ 2048
#define N_ 16
#define BS_ 512

typedef short s16x8 __attribute__((ext_vector_type(8)));
typedef float f32x4v __attribute__((ext_vector_type(4)));
typedef __hip_bfloat16 bf16;

__device__ __forceinline__ void gload_lds16(const void* g, void* l) {
    __builtin_amdgcn_global_load_lds((const __attribute__((address_space(1))) void*)g,
                                     (__attribute__((address_space(3))) void*)l, 16, 0, 0);
}

enum { EP_TANH_F32 = 0, EP_E_BF = 1, EP_F32 = 2, EP_RECON = 4 };

// C[M,N] = A(M,K) * Bt(N,K)^T, all K-contiguous bf16, fp32 accum. 128x128 tile, BK=32.
template<int EP>
__global__ __launch_bounds__(256) void mfma_nt(
    const bf16* __restrict__ A, const bf16* __restrict__ Bt,
    const float* __restrict__ bias, const float* __restrict__ X,
    float* __restrict__ Cf, bf16* __restrict__ Cb, float* __restrict__ rowsum,
    int M, int N, int K)
{
    __shared__ __align__(16) bf16 As[128 * 32];
    __shared__ __align__(16) bf16 Bs[128 * 32];
    const int tid = threadIdx.x;
    const int w = tid >> 6, l = tid & 63;
    const int wr = w >> 1, wc = w & 1;
    const int m0 = blockIdx.y * 128, n0 = blockIdx.x * 128;

    f32x4v acc[4][4];
    #pragma unroll
    for (int a = 0; a < 4; ++a)
        #pragma unroll
        for (int b = 0; b < 4; ++b) acc[a][b] = (f32x4v){0.f, 0.f, 0.f, 0.f};

    const int srow = l >> 2;        // 0..15
    const int scol = (l & 3) * 8;   // bf16 elements (16B per lane)

    for (int k0 = 0; k0 < K; k0 += 32) {
        #pragma unroll
        for (int q = 0; q < 2; ++q) {
            int r0 = w * 32 + q * 16;
            gload_lds16(&A[(size_t)(m0 + r0 + srow) * K + k0 + scol], &As[r0 * 32]);
            gload_lds16(&Bt[(size_t)(n0 + r0 + srow) * K + k0 + scol], &Bs[r0 * 32]);
        }
        __syncthreads();
        s16x8 af[4], bfr[4];
        #pragma unroll
        for (int mf = 0; mf < 4; ++mf)
            af[mf] = *(const s16x8*)&As[(wr * 64 + mf * 16 + (l & 15)) * 32 + (l >> 4) * 8];
        #pragma unroll
        for (int nf = 0; nf < 4; ++nf)
            bfr[nf] = *(const s16x8*)&Bs[(wc * 64 + nf * 16 + (l & 15)) * 32 + (l >> 4) * 8];
        #pragma unroll
        for (int mf = 0; mf < 4; ++mf)
            #pragma unroll
            for (int nf = 0; nf < 4; ++nf)
                acc[mf][nf] = __builtin_amdgcn_mfma_f32_16x16x32_bf16(af[mf], bfr[nf], acc[mf][nf], 0, 0, 0);
        __syncthreads();
    }

    #pragma unroll
    for (int mf = 0; mf < 4; ++mf) {
        if (EP == EP_RECON) {
            #pragma unroll
            for (int r = 0; r < 4; ++r) {
                int m = m0 + wr * 64 + mf * 16 + (l >> 4) * 4 + r;
                float p = 0.f;
                #pragma unroll
                for (int nf = 0; nf < 4; ++nf) {
                    int n = n0 + wc * 64 + nf * 16 + (l & 15);
                    float v = acc[mf][nf][r] + bias[n] - X[(size_t)m * N + n];
                    p += v * v;
                }
                #pragma unroll
                for (int off = 1; off < 16; off <<= 1) p += __shfl_xor(p, off);
                if ((l & 15) == 0) atomicAdd(&rowsum[m], p);
            }
        } else {
            #pragma unroll
            for (int nf = 0; nf < 4; ++nf) {
                int n = n0 + wc * 64 + nf * 16 + (l & 15);
                #pragma unroll
                for (int r = 0; r < 4; ++r) {
                    int m = m0 + wr * 64 + mf * 16 + (l >> 4) * 4 + r;
                    float v = acc[mf][nf][r];
                    if (EP == EP_TANH_F32)
                        Cf[(size_t)m * N + n] = tanhf(v + bias[n]);
                    else if (EP == EP_E_BF)
                        Cb[(size_t)m * N + n] = __float2bfloat16(X[(size_t)m * N + n] - (v + bias[n]));
                    else if (EP == EP_F32)
                        Cf[(size_t)m * N + n] = v;
                }
            }
        }
    }
}

// ---------------- fused J-GEMM + J^T J: S[b] += (Vt_b @ W2)(Vt_b @ W2)^T ----------------
// A = Vt (Mx2048), Bt = W2t (3072x2048). No J materialization: the 128x128 J-tile
// goes to LDS (bf16) and each 16x128 batch strip is self-multiplied via MFMA (af==bf).
__global__ __launch_bounds__(256) void jtj_fused(
    const bf16* __restrict__ Vt, const bf16* __restrict__ W2t,
    float* __restrict__ S, int Mb, int b0)
{
    __shared__ union {
        struct { __align__(16) bf16 As[128 * 32]; __align__(16) bf16 Bs[128 * 32]; } s;
        __align__(16) bf16 J[128 * 136];
    } u;
    const int tid = threadIdx.x;
    const int w = tid >> 6, l = tid & 63;
    const int wr = w >> 1, wc = w & 1;

    // XCD-aware swizzle: per-XCD m-chunking (A-panel L2 locality)
    int mb, nb;
    if ((Mb & 7) == 0) {
        int lin = blockIdx.y * 24 + blockIdx.x;
        int xcd = lin & 7, idx = lin >> 3;
        int mchunk = Mb >> 3;
        mb = xcd * mchunk + idx / 24;
        nb = idx % 24;
    } else { mb = blockIdx.y; nb = blockIdx.x; }
    const int m0 = mb * 128, n0 = nb * 128;

    f32x4v acc[4][4];
    #pragma unroll
    for (int a = 0; a < 4; ++a)
        #pragma unroll
        for (int b = 0; b < 4; ++b) acc[a][b] = (f32x4v){0.f, 0.f, 0.f, 0.f};

    const int srow = l >> 2;
    const int scol = (l & 3) * 8;

    for (int k0 = 0; k0 < H_; k0 += 32) {
        #pragma unroll
        for (int q = 0; q < 2; ++q) {
            int r0 = w * 32 + q * 16;
            gload_lds16(&Vt[(size_t)(m0 + r0 + srow) * H_ + k0 + scol], &u.s.As[r0 * 32]);
            gload_lds16(&W2t[(size_t)(n0 + r0 + srow) * H_ + k0 + scol], &u.s.Bs[r0 * 32]);
        }
        __syncthreads();
        s16x8 af[4], bfr[4];
        #pragma unroll
        for (int mf = 0; mf < 4; ++mf)
            af[mf] = *(const s16x8*)&u.s.As[(wr * 64 + mf * 16 + (l & 15)) * 32 + (l >> 4) * 8];
        #pragma unroll
        for (int nf = 0; nf < 4; ++nf)
            bfr[nf] = *(const s16x8*)&u.s.Bs[(wc * 64 + nf * 16 + (l & 15)) * 32 + (l >> 4) * 8];
        #pragma unroll
        for (int mf = 0; mf < 4; ++mf)
            #pragma unroll
            for (int nf = 0; nf < 4; ++nf)
                acc[mf][nf] = __builtin_amdgcn_mfma_f32_16x16x32_bf16(af[mf], bfr[nf], acc[mf][nf], 0, 0, 0);
        __syncthreads();
    }

    // ---- epilogue: J-tile (bf16) -> LDS, then per-batch strip self-product ----
    __syncthreads();
    #pragma unroll
    for (int mf = 0; mf < 4; ++mf) {
        int rbase = wr * 64 + mf * 16 + (l >> 4) * 4;
        #pragma unroll
        for (int nf = 0; nf < 4; ++nf) {
            int col = wc * 64 + nf * 16 + (l & 15);
            #pragma unroll
            for (int r = 0; r < 4; ++r)
                u.J[(rbase + r) * 136 + col] = __float2bfloat16(acc[mf][nf][r]);
        }
    }
    __syncthreads();

    #pragma unroll
    for (int t2 = 0; t2 < 2; ++t2) {
        int bl = w * 2 + t2;                 // batch strip 0..7 within tile
        f32x4v sp = (f32x4v){0.f, 0.f, 0.f, 0.f};
        #pragma unroll
        for (int kq = 0; kq < 4; ++kq) {
            s16x8 fr = *(const s16x8*)&u.J[(bl * 16 + (l & 15)) * 136 + kq * 32 + (l >> 4) * 8];
            sp = __builtin_amdgcn_mfma_f32_16x16x32_bf16(fr, fr, sp, 0, 0, 0);
        }
        int bglob = b0 + mb * 8 + bl;
        #pragma unroll
        for (int r = 0; r < 4; ++r)
            atomicAdd(&S[(size_t)bglob * 256 + ((l >> 4) * 4 + r) * 16 + (l & 15)], sp[r]);
    }
}

// plain fp32 -> bf16 cast, 8 elements/thread
__global__ __launch_bounds__(256) void cast_bf(const float* __restrict__ in, bf16* __restrict__ out, int n8)
{
    int i = blockIdx.x * 256 + threadIdx.x;
    if (i < n8) {
        const float4* p = (const float4*)in + (size_t)i * 2;
        float4 a = p[0], b = p[1];
        union { s16x8 v; bf16 e[8]; } u;
        u.e[0] = __float2bfloat16(a.x); u.e[1] = __float2bfloat16(a.y);
        u.e[2] = __float2bfloat16(a.z); u.e[3] = __float2bfloat16(a.w);
        u.e[4] = __float2bfloat16(b.x); u.e[5] = __float2bfloat16(b.y);
        u.e[6] = __float2bfloat16(b.z); u.e[7] = __float2bfloat16(b.w);
        *(s16x8*)&out[(size_t)i * 8] = u.v;
    }
}

// out[c*R + r] = bf16(in[r*C + c]);  in is R x C
__global__ __launch_bounds__(256) void castT(const float* __restrict__ in, bf16* __restrict__ out, int R, int C)
{
    __shared__ float tile[64][65];
    int r0 = blockIdx.x * 64, c0 = blockIdx.y * 64;
    int tx = threadIdx.x & 63, ty = threadIdx.x >> 6;
    #pragma unroll
    for (int k = 0; k < 16; ++k) {
        int rr = ty * 16 + k;
        tile[rr][tx] = in[(size_t)(r0 + rr) * C + c0 + tx];
    }
    __syncthreads();
    #pragma unroll
    for (int k = 0; k < 16; ++k) {
        int cc = ty * 16 + k;
        out[(size_t)(c0 + cc) * R + r0 + tx] = __float2bfloat16(tile[tx][cc]);
    }
}

// ---------------- z_star / log-sigma / sigma ----------------
__global__ __launch_bounds__(256) void zsig_kernel(const float* __restrict__ h,
    const float* __restrict__ Wmu, const float* __restrict__ bmu,
    const float* __restrict__ Wls, const float* __restrict__ bls,
    float* __restrict__ z_star, float* __restrict__ lsig, float* __restrict__ sigma)
{
    const int b = blockIdx.x, tid = threadIdx.x;
    float acc[17];
    #pragma unroll
    for (int i = 0; i < 17; ++i) acc[i] = 0.f;
    for (int hh = tid; hh < H_; hh += 256) {
        float hv = h[(size_t)b * H_ + hh];
        const float* wr = &Wmu[(size_t)hh * 16];
        #pragma unroll
        for (int i = 0; i < 16; ++i) acc[i] += hv * wr[i];
        acc[16] += hv * Wls[hh];
    }
    __shared__ float red[17][4];
    const int wid = tid >> 6, lane = tid & 63;
    #pragma unroll
    for (int i = 0; i < 17; ++i) {
        float v = acc[i];
        #pragma unroll
        for (int off = 32; off; off >>= 1) v += __shfl_xor(v, off);
        if (lane == 0) red[i][wid] = v;
    }
    __syncthreads();
    if (tid < 17) {
        float v = red[tid][0] + red[tid][1] + red[tid][2] + red[tid][3];
        if (tid < 16) z_star[(size_t)b * 16 + tid] = v + bmu[tid];
        else { float ls = v + bls[0]; lsig[b] = ls; sigma[b] = expf(ls); }
    }
}

// t = tanh(z @ W1 + b1); optional fp32 out + bf16 out. K=16.
__global__ __launch_bounds__(256) void build_t(const float* __restrict__ z,
    const float* __restrict__ W1, const float* __restrict__ b1,
    float* __restrict__ tf, bf16* __restrict__ tb)
{
    __shared__ float zs[16];
    int b = blockIdx.x, tid = threadIdx.x;
    if (tid < 16) zs[tid] = z[(size_t)b * 16 + tid];
    __syncthreads();
    for (int hh = tid; hh < H_; hh += 256) {
        float a = b1[hh];
        #pragma unroll
        for (int i = 0; i < 16; ++i) a += zs[i] * W1[(size_t)i * H_ + hh];
        float tv = tanhf(a);
        if (tf) tf[(size_t)b * H_ + hh] = tv;
        tb[(size_t)b * H_ + hh] = __float2bfloat16(tv);
    }
}

// Vt[(b_local*16+i), h] = (1-t^2) * W1[i,h]  (bf16)
__global__ __launch_bounds__(256) void build_vt(const float* __restrict__ t,
    const float* __restrict__ W1, bf16* __restrict__ Vt, int b0)
{
    int bl = blockIdx.x, b = b0 + bl, tid = threadIdx.x;
    __shared__ float u[H_];
    for (int hh = tid; hh < H_; hh += 256) {
        float tv = t[(size_t)b * H_ + hh];
        u[hh] = 1.f - tv * tv;
    }
    __syncthreads();
    size_t base = (size_t)bl * 16 * H_;
    int hh = tid * 8;
    for (int i = 0; i < 16; ++i) {
        union { s16x8 v; bf16 e[8]; } pk;
        #pragma unroll
        for (int k = 0; k < 8; ++k)
            pk.e[k] = __float2bfloat16(u[hh + k] * W1[(size_t)i * H_ + hh + k]);
        *(s16x8*)&Vt[base + (size_t)i * H_ + hh] = pk.v;
    }
}

// S[b][i][j] += sum_h w_h W1[i,h] W1[j,h],  w = 2*g*t*(1-t^2)
__global__ __launch_bounds__(256) void hess_kernel(const float* __restrict__ t,
    const float* __restrict__ g, const float* __restrict__ W1, float* __restrict__ S)
{
    int b = blockIdx.x, tid = threadIdx.x;
    int i = tid >> 4, j = tid & 15;
    __shared__ __align__(16) float wsh[512];
    __shared__ __align__(16) float W1s[16][516];

    float acc2 = 0.f;
    for (int h0 = 0; h0 < H_; h0 += 512) {
        __syncthreads();
        for (int hh = tid; hh < 512; hh += 256) {
            float tv = t[(size_t)b * H_ + h0 + hh];
            wsh[hh] = 2.f * g[(size_t)b * H_ + h0 + hh] * tv * (1.f - tv * tv);
        }
        for (int q = tid; q < 2048; q += 256) {
            int row = q >> 7, c4 = (q & 127) * 4;
            *(float4*)&W1s[row][c4] = *(const float4*)&W1[(size_t)row * H_ + h0 + c4];
        }
        __syncthreads();
        for (int hh = 0; hh < 512; hh += 4) {
            float4 wv = *(const float4*)&wsh[hh];
            float4 ai = *(const float4*)&W1s[i][hh];
            float4 aj = *(const float4*)&W1s[j][hh];
            acc2 += wv.x * ai.x * aj.x + wv.y * ai.y * aj.y + wv.z * ai.z * aj.z + wv.w * ai.w * aj.w;
        }
    }
    S[(size_t)b * 256 + tid] += acc2;
}

// ---------------- per-batch 16x16: barrier-free register solve ----------------
__global__ __launch_bounds__(64) void solve_kernel(const float* __restrict__ S,
    const float* __restrict__ sigma, const float* __restrict__ z_star,
    const float* __restrict__ eps, float* __restrict__ z_sample, float* __restrict__ d_out)
{
    const int lane = threadIdx.x;
    const int q = lane >> 4;
    const int j = lane & 15;
    const int b = blockIdx.x * 4 + q;

    const float sg = sigma[b];
    const float inv_s2 = 1.0f / (sg * sg);

    float a0[16], a[16];
    #pragma unroll
    for (int r = 0; r < 16; ++r) {
        a0[r] = S[(size_t)b * 256 + r * 16 + j] * inv_s2 + ((r == j) ? 1.0f : 0.0f);
        a[r] = a0[r];
    }

    #pragma unroll
    for (int k = 0; k < 14; ++k) {
        float x[16];
        #pragma unroll
        for (int r = 0; r < 16; ++r) x[r] = __shfl(a[k], r, 16);
        float sig2 = 0.f;
        #pragma unroll
        for (int r = 0; r < 16; ++r) if (r > k + 1) sig2 += x[r] * x[r];
        float x0 = x[k + 1];
        float normx = sqrtf(sig2 + x0 * x0);
        float alpha = (x0 >= 0.f) ? -normx : normx;
        float v[16];
        #pragma unroll
        for (int r = 0; r < 16; ++r)
            v[r] = (r <= k) ? 0.f : ((r == k + 1) ? x0 - alpha : x[r]);
        float vtv = 0.f;
        #pragma unroll
        for (int r = 0; r < 16; ++r) vtv += v[r] * v[r];
        float beta = (vtv > 1e-28f) ? 2.0f / vtv : 0.f;
        float sj = 0.f;
        #pragma unroll
        for (int r = 0; r < 16; ++r) sj += a[r] * v[r];
        float av[16];
        #pragma unroll
        for (int r = 0; r < 16; ++r) av[r] = __shfl(sj, r, 16);
        float vtav = 0.f;
        #pragma unroll
        for (int r = 0; r < 16; ++r) vtav += v[r] * av[r];
        float c = 0.5f * beta * vtav;
        float wv[16];
        #pragma unroll
        for (int r = 0; r < 16; ++r) wv[r] = beta * (av[r] - c * v[r]);
        float vj = (j <= k) ? 0.f : ((j == k + 1) ? a[k] - alpha : a[k]);
        float wj = beta * (sj - c * vj);
        #pragma unroll
        for (int r = 0; r < 16; ++r) a[r] -= v[r] * wj + wv[r] * vj;
    }

    float dg[16], eo[15];
    #pragma unroll
    for (int r = 0; r < 16; ++r) dg[r] = __shfl(a[r], r, 16);
    #pragma unroll
    for (int r = 0; r < 15; ++r) eo[r] = __shfl(a[r + 1], r, 16);

    float lo = 1e30f, hi = 1e30f;
    #pragma unroll
    for (int r = 0; r < 16; ++r) {
        float rad = ((r > 0) ? fabsf(eo[r - 1]) : 0.f) + ((r < 15) ? fabsf(eo[r]) : 0.f);
        lo = fminf(lo, dg[r] - rad);
        hi = fminf(hi, dg[r]);
    }
    lo -= 1e-4f; hi += 1e-4f;

    #pragma unroll
    for (int pass = 0; pass < 5; ++pass) {
        float step = (hi - lo) * (1.0f / 17.0f);
        float s = lo + step * (float)(j + 1);
        float qq = dg[0] - s;
        int cnt = (qq < 0.f) ? 1 : 0;
        #pragma unroll
        for (int i = 1; i < 16; ++i) {
            float denom = (fabsf(qq) < 1e-30f) ? -1e-30f : qq;
            qq = dg[i] - s - eo[i - 1] * eo[i - 1] / denom;
            cnt += (qq < 0.f) ? 1 : 0;
        }
        unsigned long long bal = __ballot(cnt >= 1);
        unsigned grp = (unsigned)((bal >> (q * 16)) & 0xffffull);
        int f = grp ? (__ffs(grp) - 1) : 16;
        float nlo = lo + step * (float)f;
        float nhi = (f < 16) ? (lo + step * (float)(f + 1)) : hi;
        lo = nlo; hi = nhi;
    }
    const float lam_min = 0.5f * (lo + hi);
    const float delta = 10.0f - lam_min;

    float bm[16];
    #pragma unroll
    for (int r = 0; r < 16; ++r) bm[r] = a0[r] + ((r == j) ? delta : 0.f);

    float ldsum = 0.f;
    #pragma unroll
    for (int kk = 0; kk < 16; ++kk) {
        float ck[16];
        #pragma unroll
        for (int r = 0; r < 16; ++r) ck[r] = __shfl(bm[kk], r, 16);
        float dkk = sqrtf(fmaxf(ck[kk], 1e-30f));
        float inv = 1.0f / dkk;
        ldsum += logf(dkk);
        float lfull[16];
        #pragma unroll
        for (int r = 0; r < 16; ++r) lfull[r] = ck[r] * inv;
        float lj = bm[kk] * inv;
        if (j == kk) {
            #pragma unroll
            for (int r = 0; r < 16; ++r) bm[r] = (r >= kk) ? lfull[r] : 0.f;
        } else if (j > kk) {
            #pragma unroll
            for (int r = 0; r < 16; ++r)
                if (r > kk) bm[r] -= lfull[r] * lj;
        }
    }

    float w[16];
    #pragma unroll
    for (int r = 0; r < 16; ++r) w[r] = 0.f;
    #pragma unroll
    for (int i = 0; i < 16; ++i) {
        float row[16];
        #pragma unroll
        for (int kx = 0; kx < 16; ++kx) row[kx] = __shfl(bm[i], kx, 16);
        float sacc = 0.f;
        #pragma unroll
        for (int kx = 0; kx < 16; ++kx) if (kx < i) sacc += row[kx] * w[kx];
        float invd = 1.0f / row[i];
        float val = (i == j) ? invd : (-sacc * invd);
        w[i] = (i >= j) ? val : 0.f;
    }

    float tsum = 0.f;
    #pragma unroll
    for (int r = 0; r < 16; ++r) tsum += w[r] * w[r];
    float zv = z_star[(size_t)b * 16 + j];
    float ep = eps[(size_t)b * 16 + j];
    float epsv[16];
    #pragma unroll
    for (int r = 0; r < 16; ++r) epsv[r] = __shfl(ep, r, 16);
    float zoff = 0.f;
    #pragma unroll
    for (int r = 0; r < 16; ++r) zoff += w[r] * epsv[r];
    z_sample[(size_t)b * 16 + j] = zv + zoff;

    float zsq = zv * zv;
    #pragma unroll
    for (int off = 1; off < 16; off <<= 1) {
        tsum += __shfl_xor(tsum, off);
        zsq  += __shfl_xor(zsq, off);
    }
    if (j == 0) {
        d_out[2 * 512 + b] = 0.5f * zsq + 0.5f * tsum;
        d_out[3 * 512 + b] = ldsum;
        d_out[4 * 512 + b] = sg;
    }
}

__global__ void finalize_kernel(const float* __restrict__ rlsum, const float* __restrict__ sigma,
    const float* __restrict__ lsig, float* __restrict__ d_out)
{
    int b = blockIdx.x * 256 + threadIdx.x;
    if (b < BS_) {
        float sg = sigma[b];
        float rl = rlsum[b] / (2.0f * sg * sg);
        float le = d_out[2 * 512 + b];
        float ld = d_out[3 * 512 + b];
        d_out[b] = (rl + le + ld) / 3072.0f + lsig[b];
        d_out[512 + b] = rl;
    }
}

extern "C" void kernel_launch(void* const* d_in, const int* in_sizes, int n_in,
                              void* d_out, int out_size, void* d_ws, size_t ws_size,
                              hipStream_t stream)
{
    const float* x       = (const float*)d_in[0];
    const float* eps     = (const float*)d_in[1];
    const float* enc_W1  = (const float*)d_in[2];
    const float* enc_b1  = (const float*)d_in[3];
    const float* enc_Wmu = (const float*)d_in[4];
    const float* enc_bmu = (const float*)d_in[5];
    const float* enc_Wls = (const float*)d_in[6];
    const float* enc_bls = (const float*)d_in[7];
    const float* dec_W1  = (const float*)d_in[8];
    const float* dec_b1  = (const float*)d_in[9];
    const float* dec_W2  = (const float*)d_in[10];
    const float* dec_b2  = (const float*)d_in[11];
    float* out = (float*)d_out;

    char* wsb = (char*)d_ws;
    size_t off = 0;
    auto alloc = [&](size_t bytes) -> void* {
        off = (off + 255) & ~(size_t)255;
        void* p = wsb + off;
        off += bytes;
        return p;
    };

    float* h    = (float*)alloc((size_t)BS_ * H_ * 4);
    float* t    = (float*)alloc((size_t)BS_ * H_ * 4);
    float* g    = (float*)alloc((size_t)BS_ * H_ * 4);
    float* z_st = (float*)alloc((size_t)BS_ * 16 * 4);
    float* lsig = (float*)alloc(BS_ * 4);
    float* sigm = (float*)alloc(BS_ * 4);
    float* z_sm = (float*)alloc((size_t)BS_ * 16 * 4);
    float* rls  = (float*)alloc(BS_ * 4);
    float* S    = (float*)alloc((size_t)BS_ * 256 * 4);
    bf16* x_bf  = (bf16*)alloc((size_t)BS_ * D_ * 2);
    bf16* eW1t  = (bf16*)alloc((size_t)H_ * D_ * 2);
    bf16* W2b   = (bf16*)alloc((size_t)H_ * D_ * 2);
    bf16* W2t   = (bf16*)alloc((size_t)D_ * H_ * 2);
    bf16* t_bf  = (bf16*)alloc((size_t)BS_ * H_ * 2);
    bf16* e_bf  = (bf16*)alloc((size_t)BS_ * D_ * 2);
    bf16* t2b   = (bf16*)alloc((size_t)BS_ * H_ * 2);

    // pick J-chunk size that fits the workspace (Vt only now)
    int nb = 0;
    size_t base_off = off;
    const int cand[3] = {512, 128, 32};
    bf16* Vt = nullptr;
    for (int ci = 0; ci < 3; ++ci) {
        off = base_off;
        int n = cand[ci];
        bf16* vt = (bf16*)alloc((size_t)n * 16 * H_ * 2);
        if (off <= ws_size) { nb = n; Vt = vt; break; }
    }
    if (nb == 0) return;

    // casts
    cast_bf<<<dim3((BS_ * D_ / 8 + 255) / 256), 256, 0, stream>>>(x, x_bf, BS_ * D_ / 8);
    castT<<<dim3(D_ / 64, H_ / 64), 256, 0, stream>>>(enc_W1, eW1t, D_, H_);
    cast_bf<<<dim3((H_ * D_ / 8 + 255) / 256), 256, 0, stream>>>(dec_W2, W2b, H_ * D_ / 8);
    castT<<<dim3(H_ / 64, D_ / 64), 256, 0, stream>>>(dec_W2, W2t, H_, D_);

    // h = tanh(x @ enc_W1 + b1)
    mfma_nt<EP_TANH_F32><<<dim3(H_ / 128, BS_ / 128), 256, 0, stream>>>(
        x_bf, eW1t, enc_b1, nullptr, h, nullptr, nullptr, BS_, H_, D_);
    // z_star, sigma
    zsig_kernel<<<dim3(BS_), 256, 0, stream>>>(h, enc_Wmu, enc_bmu, enc_Wls, enc_bls, z_st, lsig, sigm);
    // t = tanh(z_star @ dec_W1 + b1)
    build_t<<<dim3(BS_), 256, 0, stream>>>(z_st, dec_W1, dec_b1, t, t_bf);
    // e = x - (t @ W2 + b2)   (bf16 out)
    mfma_nt<EP_E_BF><<<dim3(D_ / 128, BS_ / 128), 256, 0, stream>>>(
        t_bf, W2t, dec_b2, x, nullptr, e_bf, nullptr, BS_, D_, H_);
    // g = e @ W2^T
    mfma_nt<EP_F32><<<dim3(H_ / 128, BS_ / 128), 256, 0, stream>>>(
        e_bf, W2b, nullptr, nullptr, g, nullptr, nullptr, BS_, H_, D_);

    // S = J^T J (fused, chunked over batches) + hess
    hipMemsetAsync(S, 0, (size_t)BS_ * 256 * 4, stream);
    for (int b0 = 0; b0 < BS_; b0 += nb) {
        build_vt<<<dim3(nb), 256, 0, stream>>>(t, dec_W1, Vt, b0);
        jtj_fused<<<dim3(D_ / 128, nb * 16 / 128), 256, 0, stream>>>(
            Vt, W2t, S, nb * 16 / 128, b0);
    }
    hess_kernel<<<dim3(BS_), 256, 0, stream>>>(t, g, dec_W1, S);

    // eig-min / Cholesky / solves / scalars (barrier-free register solve)
    solve_kernel<<<dim3(BS_ / 4), 64, 0, stream>>>(S, sigm, z_st, eps, z_sm, out);
    // t2 = tanh(z_sample @ dec_W1 + b1)  (bf16 only)
    build_t<<<dim3(BS_), 256, 0, stream>>>(z_sm, dec_W1, dec_b1, nullptr, t2b);
    hipMemsetAsync(rls, 0, BS_ * 4, stream);
    // rowsum of (recon - x)^2
    mfma_nt<EP_RECON><<<dim3(D_ / 128, BS_ / 128), 256, 0, stream>>>(
        t2b, W2t, dec_b2, x, nullptr, nullptr, rls, BS_, D_, H_);
    finalize_kernel<<<dim3(2), 256, 0, stream>>>(rls, sigm, lsig, out);
}

// Round 5
// 377.814 us; speedup vs baseline: 16.3263x; 1.2293x over previous
//
#include <hip/hip_runtime.h>
#include <hip/hip_bf16.h>
#include <math.h>

#define D_ 3072
#define H_ 2048
#define N_ 16
#define BS_ 512

typedef short s16x8 __attribute__((ext_vector_type(8)));
typedef float f32x4v __attribute__((ext_vector_type(4)));
typedef __hip_bfloat16 bf16;

__device__ __forceinline__ void gload_lds16(const void* g, void* l) {
    __builtin_amdgcn_global_load_lds((const __attribute__((address_space(1))) void*)g,
                                     (__attribute__((address_space(3))) void*)l, 16, 0, 0);
}

__device__ __forceinline__ float bf2f(unsigned short u) {
    unsigned v = (unsigned)u << 16; float f; __builtin_memcpy(&f, &v, 4); return f;
}

// ---------------- split-K NT GEMM: C(f32) += A(M,K)*Bt(N,K)^T over K-chunk ----------------
__global__ __launch_bounds__(256) void mfma_nt_sk(
    const bf16* __restrict__ A, const bf16* __restrict__ Bt,
    float* __restrict__ C, int M, int N, int K, int KC)
{
    __shared__ __align__(16) bf16 As[128 * 32];
    __shared__ __align__(16) bf16 Bs[128 * 32];
    const int tid = threadIdx.x;
    const int w = tid >> 6, l = tid & 63;
    const int wr = w >> 1, wc = w & 1;
    const int m0 = blockIdx.y * 128, n0 = blockIdx.x * 128;
    const int kbeg = blockIdx.z * KC;

    f32x4v acc[4][4];
    #pragma unroll
    for (int a = 0; a < 4; ++a)
        #pragma unroll
        for (int b = 0; b < 4; ++b) acc[a][b] = (f32x4v){0.f, 0.f, 0.f, 0.f};

    const int srow = l >> 2;
    const int scol = (l & 3) * 8;

    for (int k0 = kbeg; k0 < kbeg + KC; k0 += 32) {
        #pragma unroll
        for (int q = 0; q < 2; ++q) {
            int r0 = w * 32 + q * 16;
            gload_lds16(&A[(size_t)(m0 + r0 + srow) * K + k0 + scol], &As[r0 * 32]);
            gload_lds16(&Bt[(size_t)(n0 + r0 + srow) * K + k0 + scol], &Bs[r0 * 32]);
        }
        __syncthreads();
        s16x8 af[4], bfr[4];
        #pragma unroll
        for (int mf = 0; mf < 4; ++mf)
            af[mf] = *(const s16x8*)&As[(wr * 64 + mf * 16 + (l & 15)) * 32 + (l >> 4) * 8];
        #pragma unroll
        for (int nf = 0; nf < 4; ++nf)
            bfr[nf] = *(const s16x8*)&Bs[(wc * 64 + nf * 16 + (l & 15)) * 32 + (l >> 4) * 8];
        #pragma unroll
        for (int mf = 0; mf < 4; ++mf)
            #pragma unroll
            for (int nf = 0; nf < 4; ++nf)
                acc[mf][nf] = __builtin_amdgcn_mfma_f32_16x16x32_bf16(af[mf], bfr[nf], acc[mf][nf], 0, 0, 0);
        __syncthreads();
    }

    #pragma unroll
    for (int mf = 0; mf < 4; ++mf)
        #pragma unroll
        for (int nf = 0; nf < 4; ++nf) {
            int n = n0 + wc * 64 + nf * 16 + (l & 15);
            #pragma unroll
            for (int r = 0; r < 4; ++r) {
                int m = m0 + wr * 64 + mf * 16 + (l >> 4) * 4 + r;
                atomicAdd(&C[(size_t)m * N + n], acc[mf][nf][r]);
            }
        }
}

// ---------------- epilogues for split-K GEMMs ----------------
__global__ __launch_bounds__(256) void ep_tanh(const float* __restrict__ C,
    const float* __restrict__ bias, float* __restrict__ Hout, int MN, int N)
{
    int base = (blockIdx.x * 256 + threadIdx.x) * 4;
    if (base < MN) {
        float4 c = *(const float4*)&C[base];
        int n = base % N;
        float4 bb = *(const float4*)&bias[n];
        float4 o;
        o.x = tanhf(c.x + bb.x); o.y = tanhf(c.y + bb.y);
        o.z = tanhf(c.z + bb.z); o.w = tanhf(c.w + bb.w);
        *(float4*)&Hout[base] = o;
    }
}

__global__ __launch_bounds__(256) void ep_ebf(const float* __restrict__ C,
    const float* __restrict__ bias, const float* __restrict__ X,
    bf16* __restrict__ Eout, int MN, int N)
{
    int base = (blockIdx.x * 256 + threadIdx.x) * 8;
    if (base < MN) {
        float4 c0 = *(const float4*)&C[base];
        float4 c1 = *(const float4*)&C[base + 4];
        float4 x0 = *(const float4*)&X[base];
        float4 x1 = *(const float4*)&X[base + 4];
        int n = base % N;
        float4 b0 = *(const float4*)&bias[n];
        float4 b1 = *(const float4*)&bias[n + 4];
        union { s16x8 v; bf16 e[8]; } u;
        u.e[0] = __float2bfloat16(x0.x - (c0.x + b0.x));
        u.e[1] = __float2bfloat16(x0.y - (c0.y + b0.y));
        u.e[2] = __float2bfloat16(x0.z - (c0.z + b0.z));
        u.e[3] = __float2bfloat16(x0.w - (c0.w + b0.w));
        u.e[4] = __float2bfloat16(x1.x - (c1.x + b1.x));
        u.e[5] = __float2bfloat16(x1.y - (c1.y + b1.y));
        u.e[6] = __float2bfloat16(x1.z - (c1.z + b1.z));
        u.e[7] = __float2bfloat16(x1.w - (c1.w + b1.w));
        *(s16x8*)&Eout[base] = u.v;
    }
}

// rls[m] = sum_n (C[m,n]+bias[n]-X[m,n])^2   (full block reduce, no memset needed)
__global__ __launch_bounds__(256) void ep_recon(const float* __restrict__ C,
    const float* __restrict__ bias, const float* __restrict__ X, float* __restrict__ rls)
{
    int m = blockIdx.x;
    float s = 0.f;
    for (int n = threadIdx.x * 4; n < D_; n += 1024) {
        float4 c = *(const float4*)&C[(size_t)m * D_ + n];
        float4 bb = *(const float4*)&bias[n];
        float4 xx = *(const float4*)&X[(size_t)m * D_ + n];
        float v0 = c.x + bb.x - xx.x, v1 = c.y + bb.y - xx.y;
        float v2 = c.z + bb.z - xx.z, v3 = c.w + bb.w - xx.w;
        s += v0 * v0 + v1 * v1 + v2 * v2 + v3 * v3;
    }
    __shared__ float red[4];
    int wid = threadIdx.x >> 6, lane = threadIdx.x & 63;
    #pragma unroll
    for (int off = 32; off; off >>= 1) s += __shfl_xor(s, off);
    if (lane == 0) red[wid] = s;
    __syncthreads();
    if (threadIdx.x == 0) rls[m] = red[0] + red[1] + red[2] + red[3];
}

// ---------------- fused J-GEMM + J^T J (unchanged from round 4) ----------------
__global__ __launch_bounds__(256) void jtj_fused(
    const bf16* __restrict__ Vt, const bf16* __restrict__ W2t,
    float* __restrict__ S, int Mb, int b0)
{
    __shared__ union {
        struct { __align__(16) bf16 As[128 * 32]; __align__(16) bf16 Bs[128 * 32]; } s;
        __align__(16) bf16 J[128 * 136];
    } u;
    const int tid = threadIdx.x;
    const int w = tid >> 6, l = tid & 63;
    const int wr = w >> 1, wc = w & 1;

    int mb, nb;
    if ((Mb & 7) == 0) {
        int lin = blockIdx.y * 24 + blockIdx.x;
        int xcd = lin & 7, idx = lin >> 3;
        int mchunk = Mb >> 3;
        mb = xcd * mchunk + idx / 24;
        nb = idx % 24;
    } else { mb = blockIdx.y; nb = blockIdx.x; }
    const int m0 = mb * 128, n0 = nb * 128;

    f32x4v acc[4][4];
    #pragma unroll
    for (int a = 0; a < 4; ++a)
        #pragma unroll
        for (int b = 0; b < 4; ++b) acc[a][b] = (f32x4v){0.f, 0.f, 0.f, 0.f};

    const int srow = l >> 2;
    const int scol = (l & 3) * 8;

    for (int k0 = 0; k0 < H_; k0 += 32) {
        #pragma unroll
        for (int q = 0; q < 2; ++q) {
            int r0 = w * 32 + q * 16;
            gload_lds16(&Vt[(size_t)(m0 + r0 + srow) * H_ + k0 + scol], &u.s.As[r0 * 32]);
            gload_lds16(&W2t[(size_t)(n0 + r0 + srow) * H_ + k0 + scol], &u.s.Bs[r0 * 32]);
        }
        __syncthreads();
        s16x8 af[4], bfr[4];
        #pragma unroll
        for (int mf = 0; mf < 4; ++mf)
            af[mf] = *(const s16x8*)&u.s.As[(wr * 64 + mf * 16 + (l & 15)) * 32 + (l >> 4) * 8];
        #pragma unroll
        for (int nf = 0; nf < 4; ++nf)
            bfr[nf] = *(const s16x8*)&u.s.Bs[(wc * 64 + nf * 16 + (l & 15)) * 32 + (l >> 4) * 8];
        #pragma unroll
        for (int mf = 0; mf < 4; ++mf)
            #pragma unroll
            for (int nf = 0; nf < 4; ++nf)
                acc[mf][nf] = __builtin_amdgcn_mfma_f32_16x16x32_bf16(af[mf], bfr[nf], acc[mf][nf], 0, 0, 0);
        __syncthreads();
    }

    __syncthreads();
    #pragma unroll
    for (int mf = 0; mf < 4; ++mf) {
        int rbase = wr * 64 + mf * 16 + (l >> 4) * 4;
        #pragma unroll
        for (int nf = 0; nf < 4; ++nf) {
            int col = wc * 64 + nf * 16 + (l & 15);
            #pragma unroll
            for (int r = 0; r < 4; ++r)
                u.J[(rbase + r) * 136 + col] = __float2bfloat16(acc[mf][nf][r]);
        }
    }
    __syncthreads();

    #pragma unroll
    for (int t2 = 0; t2 < 2; ++t2) {
        int bl = w * 2 + t2;
        f32x4v sp = (f32x4v){0.f, 0.f, 0.f, 0.f};
        #pragma unroll
        for (int kq = 0; kq < 4; ++kq) {
            s16x8 fr = *(const s16x8*)&u.J[(bl * 16 + (l & 15)) * 136 + kq * 32 + (l >> 4) * 8];
            sp = __builtin_amdgcn_mfma_f32_16x16x32_bf16(fr, fr, sp, 0, 0, 0);
        }
        int bglob = b0 + mb * 8 + bl;
        #pragma unroll
        for (int r = 0; r < 4; ++r)
            atomicAdd(&S[(size_t)bglob * 256 + ((l >> 4) * 4 + r) * 16 + (l & 15)], sp[r]);
    }
}

// ---------------- hessian via MFMA: S[b] += (w . W1) @ W1^T, w = 2*g*t*(1-t^2) ----------------
__global__ __launch_bounds__(256) void hess_mfma(const float* __restrict__ t,
    const float* __restrict__ g, const bf16* __restrict__ W1b, float* __restrict__ S)
{
    const int w = threadIdx.x >> 6, l = threadIdx.x & 63;
    const int b = blockIdx.x * 4 + w;
    const int row = l & 15, kq = (l >> 4) * 8;

    f32x4v sp = (f32x4v){0.f, 0.f, 0.f, 0.f};
    for (int k0 = 0; k0 < H_; k0 += 32) {
        int kk = k0 + kq;
        s16x8 wf = *(const s16x8*)&W1b[(size_t)row * H_ + kk];
        float4 t0 = *(const float4*)&t[(size_t)b * H_ + kk];
        float4 t1 = *(const float4*)&t[(size_t)b * H_ + kk + 4];
        float4 g0 = *(const float4*)&g[(size_t)b * H_ + kk];
        float4 g1 = *(const float4*)&g[(size_t)b * H_ + kk + 4];
        float wv[8];
        wv[0] = 2.f * g0.x * t0.x * (1.f - t0.x * t0.x);
        wv[1] = 2.f * g0.y * t0.y * (1.f - t0.y * t0.y);
        wv[2] = 2.f * g0.z * t0.z * (1.f - t0.z * t0.z);
        wv[3] = 2.f * g0.w * t0.w * (1.f - t0.w * t0.w);
        wv[4] = 2.f * g1.x * t1.x * (1.f - t1.x * t1.x);
        wv[5] = 2.f * g1.y * t1.y * (1.f - t1.y * t1.y);
        wv[6] = 2.f * g1.z * t1.z * (1.f - t1.z * t1.z);
        wv[7] = 2.f * g1.w * t1.w * (1.f - t1.w * t1.w);
        union { s16x8 v; bf16 e[8]; } af;
        #pragma unroll
        for (int e = 0; e < 8; ++e)
            af.e[e] = __float2bfloat16(wv[e] * bf2f((unsigned short)wf[e]));
        sp = __builtin_amdgcn_mfma_f32_16x16x32_bf16(af.v, wf, sp, 0, 0, 0);
    }
    #pragma unroll
    for (int r = 0; r < 4; ++r)
        S[(size_t)b * 256 + ((l >> 4) * 4 + r) * 16 + (l & 15)] += sp[r];
}

// plain fp32 -> bf16 cast, 8 elements/thread
__global__ __launch_bounds__(256) void cast_bf(const float* __restrict__ in, bf16* __restrict__ out, int n8)
{
    int i = blockIdx.x * 256 + threadIdx.x;
    if (i < n8) {
        const float4* p = (const float4*)in + (size_t)i * 2;
        float4 a = p[0], b = p[1];
        union { s16x8 v; bf16 e[8]; } u;
        u.e[0] = __float2bfloat16(a.x); u.e[1] = __float2bfloat16(a.y);
        u.e[2] = __float2bfloat16(a.z); u.e[3] = __float2bfloat16(a.w);
        u.e[4] = __float2bfloat16(b.x); u.e[5] = __float2bfloat16(b.y);
        u.e[6] = __float2bfloat16(b.z); u.e[7] = __float2bfloat16(b.w);
        *(s16x8*)&out[(size_t)i * 8] = u.v;
    }
}

// out[c*R + r] = bf16(in[r*C + c]);  in is R x C
__global__ __launch_bounds__(256) void castT(const float* __restrict__ in, bf16* __restrict__ out, int R, int C)
{
    __shared__ float tile[64][65];
    int r0 = blockIdx.x * 64, c0 = blockIdx.y * 64;
    int tx = threadIdx.x & 63, ty = threadIdx.x >> 6;
    #pragma unroll
    for (int k = 0; k < 16; ++k) {
        int rr = ty * 16 + k;
        tile[rr][tx] = in[(size_t)(r0 + rr) * C + c0 + tx];
    }
    __syncthreads();
    #pragma unroll
    for (int k = 0; k < 16; ++k) {
        int cc = ty * 16 + k;
        out[(size_t)(c0 + cc) * R + r0 + tx] = __float2bfloat16(tile[tx][cc]);
    }
}

// ---------------- z_star / log-sigma / sigma ----------------
__global__ __launch_bounds__(256) void zsig_kernel(const float* __restrict__ h,
    const float* __restrict__ Wmu, const float* __restrict__ bmu,
    const float* __restrict__ Wls, const float* __restrict__ bls,
    float* __restrict__ z_star, float* __restrict__ lsig, float* __restrict__ sigma)
{
    const int b = blockIdx.x, tid = threadIdx.x;
    float acc[17];
    #pragma unroll
    for (int i = 0; i < 17; ++i) acc[i] = 0.f;
    for (int hh = tid; hh < H_; hh += 256) {
        float hv = h[(size_t)b * H_ + hh];
        const float* wr = &Wmu[(size_t)hh * 16];
        #pragma unroll
        for (int i = 0; i < 16; ++i) acc[i] += hv * wr[i];
        acc[16] += hv * Wls[hh];
    }
    __shared__ float red[17][4];
    const int wid = tid >> 6, lane = tid & 63;
    #pragma unroll
    for (int i = 0; i < 17; ++i) {
        float v = acc[i];
        #pragma unroll
        for (int off = 32; off; off >>= 1) v += __shfl_xor(v, off);
        if (lane == 0) red[i][wid] = v;
    }
    __syncthreads();
    if (tid < 17) {
        float v = red[tid][0] + red[tid][1] + red[tid][2] + red[tid][3];
        if (tid < 16) z_star[(size_t)b * 16 + tid] = v + bmu[tid];
        else { float ls = v + bls[0]; lsig[b] = ls; sigma[b] = expf(ls); }
    }
}

// t = tanh(z @ W1 + b1); optional fp32 out + bf16 out. K=16.
__global__ __launch_bounds__(256) void build_t(const float* __restrict__ z,
    const float* __restrict__ W1, const float* __restrict__ b1,
    float* __restrict__ tf, bf16* __restrict__ tb)
{
    __shared__ float zs[16];
    int b = blockIdx.x, tid = threadIdx.x;
    if (tid < 16) zs[tid] = z[(size_t)b * 16 + tid];
    __syncthreads();
    for (int hh = tid; hh < H_; hh += 256) {
        float a = b1[hh];
        #pragma unroll
        for (int i = 0; i < 16; ++i) a += zs[i] * W1[(size_t)i * H_ + hh];
        float tv = tanhf(a);
        if (tf) tf[(size_t)b * H_ + hh] = tv;
        tb[(size_t)b * H_ + hh] = __float2bfloat16(tv);
    }
}

// Vt[(b_local*16+i), h] = (1-t^2) * W1[i,h]  (bf16)
__global__ __launch_bounds__(256) void build_vt(const float* __restrict__ t,
    const float* __restrict__ W1, bf16* __restrict__ Vt, int b0)
{
    int bl = blockIdx.x, b = b0 + bl, tid = threadIdx.x;
    __shared__ float u[H_];
    for (int hh = tid; hh < H_; hh += 256) {
        float tv = t[(size_t)b * H_ + hh];
        u[hh] = 1.f - tv * tv;
    }
    __syncthreads();
    size_t base = (size_t)bl * 16 * H_;
    int hh = tid * 8;
    for (int i = 0; i < 16; ++i) {
        union { s16x8 v; bf16 e[8]; } pk;
        #pragma unroll
        for (int k = 0; k < 8; ++k)
            pk.e[k] = __float2bfloat16(u[hh + k] * W1[(size_t)i * H_ + hh + k]);
        *(s16x8*)&Vt[base + (size_t)i * H_ + hh] = pk.v;
    }
}

// ---------------- per-batch 16x16: barrier-free register solve ----------------
__global__ __launch_bounds__(64) void solve_kernel(const float* __restrict__ S,
    const float* __restrict__ sigma, const float* __restrict__ z_star,
    const float* __restrict__ eps, float* __restrict__ z_sample, float* __restrict__ d_out)
{
    const int lane = threadIdx.x;
    const int q = lane >> 4;
    const int j = lane & 15;
    const int b = blockIdx.x * 4 + q;

    const float sg = sigma[b];
    const float inv_s2 = 1.0f / (sg * sg);

    float a0[16], a[16];
    #pragma unroll
    for (int r = 0; r < 16; ++r) {
        a0[r] = S[(size_t)b * 256 + r * 16 + j] * inv_s2 + ((r == j) ? 1.0f : 0.0f);
        a[r] = a0[r];
    }

    #pragma unroll
    for (int k = 0; k < 14; ++k) {
        float x[16];
        #pragma unroll
        for (int r = 0; r < 16; ++r) x[r] = __shfl(a[k], r, 16);
        float sig2 = 0.f;
        #pragma unroll
        for (int r = 0; r < 16; ++r) if (r > k + 1) sig2 += x[r] * x[r];
        float x0 = x[k + 1];
        float normx = sqrtf(sig2 + x0 * x0);
        float alpha = (x0 >= 0.f) ? -normx : normx;
        float v[16];
        #pragma unroll
        for (int r = 0; r < 16; ++r)
            v[r] = (r <= k) ? 0.f : ((r == k + 1) ? x0 - alpha : x[r]);
        float vtv = 0.f;
        #pragma unroll
        for (int r = 0; r < 16; ++r) vtv += v[r] * v[r];
        float beta = (vtv > 1e-28f) ? 2.0f / vtv : 0.f;
        float sj = 0.f;
        #pragma unroll
        for (int r = 0; r < 16; ++r) sj += a[r] * v[r];
        float av[16];
        #pragma unroll
        for (int r = 0; r < 16; ++r) av[r] = __shfl(sj, r, 16);
        float vtav = 0.f;
        #pragma unroll
        for (int r = 0; r < 16; ++r) vtav += v[r] * av[r];
        float c = 0.5f * beta * vtav;
        float wv[16];
        #pragma unroll
        for (int r = 0; r < 16; ++r) wv[r] = beta * (av[r] - c * v[r]);
        float vj = (j <= k) ? 0.f : ((j == k + 1) ? a[k] - alpha : a[k]);
        float wj = beta * (sj - c * vj);
        #pragma unroll
        for (int r = 0; r < 16; ++r) a[r] -= v[r] * wj + wv[r] * vj;
    }

    float dg[16], eo[15];
    #pragma unroll
    for (int r = 0; r < 16; ++r) dg[r] = __shfl(a[r], r, 16);
    #pragma unroll
    for (int r = 0; r < 15; ++r) eo[r] = __shfl(a[r + 1], r, 16);

    float lo = 1e30f, hi = 1e30f;
    #pragma unroll
    for (int r = 0; r < 16; ++r) {
        float rad = ((r > 0) ? fabsf(eo[r - 1]) : 0.f) + ((r < 15) ? fabsf(eo[r]) : 0.f);
        lo = fminf(lo, dg[r] - rad);
        hi = fminf(hi, dg[r]);
    }
    lo -= 1e-4f; hi += 1e-4f;

    #pragma unroll
    for (int pass = 0; pass < 5; ++pass) {
        float step = (hi - lo) * (1.0f / 17.0f);
        float s = lo + step * (float)(j + 1);
        float qq = dg[0] - s;
        int cnt = (qq < 0.f) ? 1 : 0;
        #pragma unroll
        for (int i = 1; i < 16; ++i) {
            float denom = (fabsf(qq) < 1e-30f) ? -1e-30f : qq;
            qq = dg[i] - s - eo[i - 1] * eo[i - 1] / denom;
            cnt += (qq < 0.f) ? 1 : 0;
        }
        unsigned long long bal = __ballot(cnt >= 1);
        unsigned grp = (unsigned)((bal >> (q * 16)) & 0xffffull);
        int f = grp ? (__ffs(grp) - 1) : 16;
        float nlo = lo + step * (float)f;
        float nhi = (f < 16) ? (lo + step * (float)(f + 1)) : hi;
        lo = nlo; hi = nhi;
    }
    const float lam_min = 0.5f * (lo + hi);
    const float delta = 10.0f - lam_min;

    float bm[16];
    #pragma unroll
    for (int r = 0; r < 16; ++r) bm[r] = a0[r] + ((r == j) ? delta : 0.f);

    float ldsum = 0.f;
    #pragma unroll
    for (int kk = 0; kk < 16; ++kk) {
        float ck[16];
        #pragma unroll
        for (int r = 0; r < 16; ++r) ck[r] = __shfl(bm[kk], r, 16);
        float dkk = sqrtf(fmaxf(ck[kk], 1e-30f));
        float inv = 1.0f / dkk;
        ldsum += logf(dkk);
        float lfull[16];
        #pragma unroll
        for (int r = 0; r < 16; ++r) lfull[r] = ck[r] * inv;
        float lj = bm[kk] * inv;
        if (j == kk) {
            #pragma unroll
            for (int r = 0; r < 16; ++r) bm[r] = (r >= kk) ? lfull[r] : 0.f;
        } else if (j > kk) {
            #pragma unroll
            for (int r = 0; r < 16; ++r)
                if (r > kk) bm[r] -= lfull[r] * lj;
        }
    }

    float w[16];
    #pragma unroll
    for (int r = 0; r < 16; ++r) w[r] = 0.f;
    #pragma unroll
    for (int i = 0; i < 16; ++i) {
        float row[16];
        #pragma unroll
        for (int kx = 0; kx < 16; ++kx) row[kx] = __shfl(bm[i], kx, 16);
        float sacc = 0.f;
        #pragma unroll
        for (int kx = 0; kx < 16; ++kx) if (kx < i) sacc += row[kx] * w[kx];
        float invd = 1.0f / row[i];
        float val = (i == j) ? invd : (-sacc * invd);
        w[i] = (i >= j) ? val : 0.f;
    }

    float tsum = 0.f;
    #pragma unroll
    for (int r = 0; r < 16; ++r) tsum += w[r] * w[r];
    float zv = z_star[(size_t)b * 16 + j];
    float ep = eps[(size_t)b * 16 + j];
    float epsv[16];
    #pragma unroll
    for (int r = 0; r < 16; ++r) epsv[r] = __shfl(ep, r, 16);
    float zoff = 0.f;
    #pragma unroll
    for (int r = 0; r < 16; ++r) zoff += w[r] * epsv[r];
    z_sample[(size_t)b * 16 + j] = zv + zoff;

    float zsq = zv * zv;
    #pragma unroll
    for (int off = 1; off < 16; off <<= 1) {
        tsum += __shfl_xor(tsum, off);
        zsq  += __shfl_xor(zsq, off);
    }
    if (j == 0) {
        d_out[2 * 512 + b] = 0.5f * zsq + 0.5f * tsum;
        d_out[3 * 512 + b] = ldsum;
        d_out[4 * 512 + b] = sg;
    }
}

__global__ void finalize_kernel(const float* __restrict__ rlsum, const float* __restrict__ sigma,
    const float* __restrict__ lsig, float* __restrict__ d_out)
{
    int b = blockIdx.x * 256 + threadIdx.x;
    if (b < BS_) {
        float sg = sigma[b];
        float rl = rlsum[b] / (2.0f * sg * sg);
        float le = d_out[2 * 512 + b];
        float ld = d_out[3 * 512 + b];
        d_out[b] = (rl + le + ld) / 3072.0f + lsig[b];
        d_out[512 + b] = rl;
    }
}

extern "C" void kernel_launch(void* const* d_in, const int* in_sizes, int n_in,
                              void* d_out, int out_size, void* d_ws, size_t ws_size,
                              hipStream_t stream)
{
    const float* x       = (const float*)d_in[0];
    const float* eps     = (const float*)d_in[1];
    const float* enc_W1  = (const float*)d_in[2];
    const float* enc_b1  = (const float*)d_in[3];
    const float* enc_Wmu = (const float*)d_in[4];
    const float* enc_bmu = (const float*)d_in[5];
    const float* enc_Wls = (const float*)d_in[6];
    const float* enc_bls = (const float*)d_in[7];
    const float* dec_W1  = (const float*)d_in[8];
    const float* dec_b1  = (const float*)d_in[9];
    const float* dec_W2  = (const float*)d_in[10];
    const float* dec_b2  = (const float*)d_in[11];
    float* out = (float*)d_out;

    char* wsb = (char*)d_ws;
    size_t off = 0;
    auto alloc = [&](size_t bytes) -> void* {
        off = (off + 255) & ~(size_t)255;
        void* p = wsb + off;
        off += bytes;
        return p;
    };

    float* h    = (float*)alloc((size_t)BS_ * H_ * 4);
    float* t    = (float*)alloc((size_t)BS_ * H_ * 4);
    float* g    = (float*)alloc((size_t)BS_ * H_ * 4);
    float* z_st = (float*)alloc((size_t)BS_ * 16 * 4);
    float* lsig = (float*)alloc(BS_ * 4);
    float* sigm = (float*)alloc(BS_ * 4);
    float* z_sm = (float*)alloc((size_t)BS_ * 16 * 4);
    float* rls  = (float*)alloc(BS_ * 4);
    float* S    = (float*)alloc((size_t)BS_ * 256 * 4);
    float* Ch   = (float*)alloc((size_t)BS_ * H_ * 4);   // split-K scratch (M x 2048)
    float* Cd   = (float*)alloc((size_t)BS_ * D_ * 4);   // split-K scratch (M x 3072)
    bf16* x_bf  = (bf16*)alloc((size_t)BS_ * D_ * 2);
    bf16* eW1t  = (bf16*)alloc((size_t)H_ * D_ * 2);
    bf16* W2b   = (bf16*)alloc((size_t)H_ * D_ * 2);
    bf16* W2t   = (bf16*)alloc((size_t)D_ * H_ * 2);
    bf16* W1b   = (bf16*)alloc((size_t)N_ * H_ * 2);
    bf16* t_bf  = (bf16*)alloc((size_t)BS_ * H_ * 2);
    bf16* e_bf  = (bf16*)alloc((size_t)BS_ * D_ * 2);
    bf16* t2b   = (bf16*)alloc((size_t)BS_ * H_ * 2);

    // pick J-chunk size that fits the workspace (Vt only)
    int nb = 0;
    size_t base_off = off;
    const int cand[3] = {512, 128, 32};
    bf16* Vt = nullptr;
    for (int ci = 0; ci < 3; ++ci) {
        off = base_off;
        int n = cand[ci];
        bf16* vt = (bf16*)alloc((size_t)n * 16 * H_ * 2);
        if (off <= ws_size) { nb = n; Vt = vt; break; }
    }
    if (nb == 0) return;

    // casts
    cast_bf<<<dim3((BS_ * D_ / 8 + 255) / 256), 256, 0, stream>>>(x, x_bf, BS_ * D_ / 8);
    castT<<<dim3(D_ / 64, H_ / 64), 256, 0, stream>>>(enc_W1, eW1t, D_, H_);
    cast_bf<<<dim3((H_ * D_ / 8 + 255) / 256), 256, 0, stream>>>(dec_W2, W2b, H_ * D_ / 8);
    castT<<<dim3(H_ / 64, D_ / 64), 256, 0, stream>>>(dec_W2, W2t, H_, D_);
    cast_bf<<<dim3((N_ * H_ / 8 + 255) / 256), 256, 0, stream>>>(dec_W1, W1b, N_ * H_ / 8);

    hipMemsetAsync(Ch, 0, (size_t)BS_ * H_ * 4, stream);
    hipMemsetAsync(Cd, 0, (size_t)BS_ * D_ * 4, stream);
    hipMemsetAsync(g,  0, (size_t)BS_ * H_ * 4, stream);
    hipMemsetAsync(S,  0, (size_t)BS_ * 256 * 4, stream);

    // h = tanh(x @ enc_W1 + b1)  [split-K 4]
    mfma_nt_sk<<<dim3(H_ / 128, BS_ / 128, 4), 256, 0, stream>>>(
        x_bf, eW1t, Ch, BS_, H_, D_, D_ / 4);
    ep_tanh<<<dim3(BS_ * H_ / 4 / 256), 256, 0, stream>>>(Ch, enc_b1, h, BS_ * H_, H_);
    // z_star, sigma
    zsig_kernel<<<dim3(BS_), 256, 0, stream>>>(h, enc_Wmu, enc_bmu, enc_Wls, enc_bls, z_st, lsig, sigm);
    // t = tanh(z_star @ dec_W1 + b1)
    build_t<<<dim3(BS_), 256, 0, stream>>>(z_st, dec_W1, dec_b1, t, t_bf);
    // e = x - (t @ W2 + b2)  [split-K 4]
    mfma_nt_sk<<<dim3(D_ / 128, BS_ / 128, 4), 256, 0, stream>>>(
        t_bf, W2t, Cd, BS_, D_, H_, H_ / 4);
    ep_ebf<<<dim3(BS_ * D_ / 8 / 256), 256, 0, stream>>>(Cd, dec_b2, x, e_bf, BS_ * D_, D_);
    // g = e @ W2^T  [split-K 4, direct accumulate]
    mfma_nt_sk<<<dim3(H_ / 128, BS_ / 128, 4), 256, 0, stream>>>(
        e_bf, W2b, g, BS_, H_, D_, D_ / 4);

    // S = J^T J (fused, chunked over batches)
    for (int b0 = 0; b0 < BS_; b0 += nb) {
        build_vt<<<dim3(nb), 256, 0, stream>>>(t, dec_W1, Vt, b0);
        jtj_fused<<<dim3(D_ / 128, nb * 16 / 128), 256, 0, stream>>>(
            Vt, W2t, S, nb * 16 / 128, b0);
    }
    // S += hessian core (MFMA, one wave per batch)
    hess_mfma<<<dim3(BS_ / 4), 256, 0, stream>>>(t, g, W1b, S);

    // eig-min / Cholesky / solves / scalars
    solve_kernel<<<dim3(BS_ / 4), 64, 0, stream>>>(S, sigm, z_st, eps, z_sm, out);
    // t2 = tanh(z_sample @ dec_W1 + b1)
    build_t<<<dim3(BS_), 256, 0, stream>>>(z_sm, dec_W1, dec_b1, nullptr, t2b);
    // recon GEMM [split-K 4] + row-sum epilogue
    hipMemsetAsync(Cd, 0, (size_t)BS_ * D_ * 4, stream);
    mfma_nt_sk<<<dim3(D_ / 128, BS_ / 128, 4), 256, 0, stream>>>(
        t2b, W2t, Cd, BS_, D_, H_, H_ / 4);
    ep_recon<<<dim3(BS_), 256, 0, stream>>>(Cd, dec_b2, x, rls);
    finalize_kernel<<<dim3(2), 256, 0, stream>>>(rls, sigm, lsig, out);
}

// Round 6
// 376.766 us; speedup vs baseline: 16.3717x; 1.0028x over previous
//
#include <hip/hip_runtime.h>
#include <hip/hip_bf16.h>
#include <math.h>

#define D_ 3072
#define H_ 2048
#define N_ 16
#define BS_ 512

typedef short s16x8 __attribute__((ext_vector_type(8)));
typedef float f32x4v __attribute__((ext_vector_type(4)));
typedef __hip_bfloat16 bf16;

__device__ __forceinline__ void gload_lds16(const void* g, void* l) {
    __builtin_amdgcn_global_load_lds((const __attribute__((address_space(1))) void*)g,
                                     (__attribute__((address_space(3))) void*)l, 16, 0, 0);
}

__device__ __forceinline__ float bf2f(unsigned short u) {
    unsigned v = (unsigned)u << 16; float f; __builtin_memcpy(&f, &v, 4); return f;
}

// ---------------- split-K NT GEMM: C(f32) += A(M,K)*Bt(N,K)^T over K-chunk ----------------
__global__ __launch_bounds__(256) void mfma_nt_sk(
    const bf16* __restrict__ A, const bf16* __restrict__ Bt,
    float* __restrict__ C, int M, int N, int K, int KC)
{
    __shared__ __align__(16) bf16 As[128 * 32];
    __shared__ __align__(16) bf16 Bs[128 * 32];
    const int tid = threadIdx.x;
    const int w = tid >> 6, l = tid & 63;
    const int wr = w >> 1, wc = w & 1;
    const int m0 = blockIdx.y * 128, n0 = blockIdx.x * 128;
    const int kbeg = blockIdx.z * KC;

    f32x4v acc[4][4];
    #pragma unroll
    for (int a = 0; a < 4; ++a)
        #pragma unroll
        for (int b = 0; b < 4; ++b) acc[a][b] = (f32x4v){0.f, 0.f, 0.f, 0.f};

    const int srow = l >> 2;
    const int scol = (l & 3) * 8;

    for (int k0 = kbeg; k0 < kbeg + KC; k0 += 32) {
        #pragma unroll
        for (int q = 0; q < 2; ++q) {
            int r0 = w * 32 + q * 16;
            gload_lds16(&A[(size_t)(m0 + r0 + srow) * K + k0 + scol], &As[r0 * 32]);
            gload_lds16(&Bt[(size_t)(n0 + r0 + srow) * K + k0 + scol], &Bs[r0 * 32]);
        }
        __syncthreads();
        s16x8 af[4], bfr[4];
        #pragma unroll
        for (int mf = 0; mf < 4; ++mf)
            af[mf] = *(const s16x8*)&As[(wr * 64 + mf * 16 + (l & 15)) * 32 + (l >> 4) * 8];
        #pragma unroll
        for (int nf = 0; nf < 4; ++nf)
            bfr[nf] = *(const s16x8*)&Bs[(wc * 64 + nf * 16 + (l & 15)) * 32 + (l >> 4) * 8];
        #pragma unroll
        for (int mf = 0; mf < 4; ++mf)
            #pragma unroll
            for (int nf = 0; nf < 4; ++nf)
                acc[mf][nf] = __builtin_amdgcn_mfma_f32_16x16x32_bf16(af[mf], bfr[nf], acc[mf][nf], 0, 0, 0);
        __syncthreads();
    }

    #pragma unroll
    for (int mf = 0; mf < 4; ++mf)
        #pragma unroll
        for (int nf = 0; nf < 4; ++nf) {
            int n = n0 + wc * 64 + nf * 16 + (l & 15);
            #pragma unroll
            for (int r = 0; r < 4; ++r) {
                int m = m0 + wr * 64 + mf * 16 + (l >> 4) * 4 + r;
                atomicAdd(&C[(size_t)m * N + n], acc[mf][nf][r]);
            }
        }
}

// ---------------- epilogues ----------------
__global__ __launch_bounds__(256) void ep_ebf(const float* __restrict__ C,
    const float* __restrict__ bias, const float* __restrict__ X,
    bf16* __restrict__ Eout, int MN, int N)
{
    int base = (blockIdx.x * 256 + threadIdx.x) * 8;
    if (base < MN) {
        float4 c0 = *(const float4*)&C[base];
        float4 c1 = *(const float4*)&C[base + 4];
        float4 x0 = *(const float4*)&X[base];
        float4 x1 = *(const float4*)&X[base + 4];
        int n = base % N;
        float4 b0 = *(const float4*)&bias[n];
        float4 b1 = *(const float4*)&bias[n + 4];
        union { s16x8 v; bf16 e[8]; } u;
        u.e[0] = __float2bfloat16(x0.x - (c0.x + b0.x));
        u.e[1] = __float2bfloat16(x0.y - (c0.y + b0.y));
        u.e[2] = __float2bfloat16(x0.z - (c0.z + b0.z));
        u.e[3] = __float2bfloat16(x0.w - (c0.w + b0.w));
        u.e[4] = __float2bfloat16(x1.x - (c1.x + b1.x));
        u.e[5] = __float2bfloat16(x1.y - (c1.y + b1.y));
        u.e[6] = __float2bfloat16(x1.z - (c1.z + b1.z));
        u.e[7] = __float2bfloat16(x1.w - (c1.w + b1.w));
        *(s16x8*)&Eout[base] = u.v;
    }
}

__global__ __launch_bounds__(256) void ep_recon(const float* __restrict__ C,
    const float* __restrict__ bias, const float* __restrict__ X, float* __restrict__ rls)
{
    int m = blockIdx.x;
    float s = 0.f;
    for (int n = threadIdx.x * 4; n < D_; n += 1024) {
        float4 c = *(const float4*)&C[(size_t)m * D_ + n];
        float4 bb = *(const float4*)&bias[n];
        float4 xx = *(const float4*)&X[(size_t)m * D_ + n];
        float v0 = c.x + bb.x - xx.x, v1 = c.y + bb.y - xx.y;
        float v2 = c.z + bb.z - xx.z, v3 = c.w + bb.w - xx.w;
        s += v0 * v0 + v1 * v1 + v2 * v2 + v3 * v3;
    }
    __shared__ float red[4];
    int wid = threadIdx.x >> 6, lane = threadIdx.x & 63;
    #pragma unroll
    for (int off = 32; off; off >>= 1) s += __shfl_xor(s, off);
    if (lane == 0) red[wid] = s;
    __syncthreads();
    if (threadIdx.x == 0) rls[m] = red[0] + red[1] + red[2] + red[3];
}

// ---------------- fused J-GEMM + J^T J: BK=64, T2 XOR-swizzled LDS ----------------
// Swizzle involution on byte-offset within a 128-B row: col ^= ((row&7)<<4).
// Stage: linear LDS dest (gload_lds contract), pre-swizzled GLOBAL source.
// Read: swizzled ds_read address. Both sides use the same involution (rule #21).
__global__ __launch_bounds__(256) void jtj_fused(
    const bf16* __restrict__ Vt, const bf16* __restrict__ W2t,
    float* __restrict__ S, int Mb, int b0)
{
    __shared__ union {
        struct { __align__(16) bf16 As[128 * 64]; __align__(16) bf16 Bs[128 * 64]; } s;  // 32 KB
        __align__(16) bf16 J[128 * 136];                                                  // 34.8 KB
    } u;
    const int tid = threadIdx.x;
    const int w = tid >> 6, l = tid & 63;
    const int wr = w >> 1, wc = w & 1;

    int mb, nb;
    if ((Mb & 7) == 0) {
        int lin = blockIdx.y * 24 + blockIdx.x;
        int xcd = lin & 7, idx = lin >> 3;
        int mchunk = Mb >> 3;
        mb = xcd * mchunk + idx / 24;
        nb = idx % 24;
    } else { mb = blockIdx.y; nb = blockIdx.x; }
    const int m0 = mb * 128, n0 = nb * 128;

    f32x4v acc[4][4];
    #pragma unroll
    for (int a = 0; a < 4; ++a)
        #pragma unroll
        for (int b = 0; b < 4; ++b) acc[a][b] = (f32x4v){0.f, 0.f, 0.f, 0.f};

    // staging: dest byte = rnd*4096 + w*1024 + l*16 (HW adds l*16 to uniform base)
    // -> dest row = rnd*32 + w*8 + (l>>3), dest col-byte = (l&7)*16
    // -> source col-byte = destcol ^ ((row&7)<<4), row&7 = l>>3
    const int drow = (w << 3) + (l >> 3);
    const int scb = (((l & 7) ^ (l >> 3)) << 4);

    for (int k0 = 0; k0 < H_; k0 += 64) {
        #pragma unroll
        for (int rnd = 0; rnd < 4; ++rnd) {
            int row = rnd * 32 + drow;
            gload_lds16((const char*)Vt  + ((size_t)(m0 + row) * H_ + k0) * 2 + scb,
                        (char*)u.s.As + rnd * 4096 + w * 1024);
            gload_lds16((const char*)W2t + ((size_t)(n0 + row) * H_ + k0) * 2 + scb,
                        (char*)u.s.Bs + rnd * 4096 + w * 1024);
        }
        __syncthreads();
        #pragma unroll
        for (int ks = 0; ks < 2; ++ks) {
            const int cb = (ks * 64 + ((l >> 4) * 16)) ^ ((l & 7) << 4);
            s16x8 af[4], bfr[4];
            #pragma unroll
            for (int mf = 0; mf < 4; ++mf) {
                int row = wr * 64 + mf * 16 + (l & 15);
                af[mf] = *(const s16x8*)((const char*)u.s.As + row * 128 + cb);
            }
            #pragma unroll
            for (int nf = 0; nf < 4; ++nf) {
                int row = wc * 64 + nf * 16 + (l & 15);
                bfr[nf] = *(const s16x8*)((const char*)u.s.Bs + row * 128 + cb);
            }
            #pragma unroll
            for (int mf = 0; mf < 4; ++mf)
                #pragma unroll
                for (int nf = 0; nf < 4; ++nf)
                    acc[mf][nf] = __builtin_amdgcn_mfma_f32_16x16x32_bf16(af[mf], bfr[nf], acc[mf][nf], 0, 0, 0);
        }
        __syncthreads();
    }

    // ---- epilogue: J-tile (bf16) -> LDS, per-batch strip self-product ----
    __syncthreads();
    #pragma unroll
    for (int mf = 0; mf < 4; ++mf) {
        int rbase = wr * 64 + mf * 16 + (l >> 4) * 4;
        #pragma unroll
        for (int nf = 0; nf < 4; ++nf) {
            int col = wc * 64 + nf * 16 + (l & 15);
            #pragma unroll
            for (int r = 0; r < 4; ++r)
                u.J[(rbase + r) * 136 + col] = __float2bfloat16(acc[mf][nf][r]);
        }
    }
    __syncthreads();

    #pragma unroll
    for (int t2 = 0; t2 < 2; ++t2) {
        int bl = w * 2 + t2;
        f32x4v sp = (f32x4v){0.f, 0.f, 0.f, 0.f};
        #pragma unroll
        for (int kq = 0; kq < 4; ++kq) {
            s16x8 fr = *(const s16x8*)&u.J[(bl * 16 + (l & 15)) * 136 + kq * 32 + (l >> 4) * 8];
            sp = __builtin_amdgcn_mfma_f32_16x16x32_bf16(fr, fr, sp, 0, 0, 0);
        }
        int bglob = b0 + mb * 8 + bl;
        #pragma unroll
        for (int r = 0; r < 4; ++r)
            atomicAdd(&S[(size_t)bglob * 256 + ((l >> 4) * 4 + r) * 16 + (l & 15)], sp[r]);
    }
}

// ---------------- hessian via MFMA ----------------
__global__ __launch_bounds__(256) void hess_mfma(const float* __restrict__ t,
    const float* __restrict__ g, const bf16* __restrict__ W1b, float* __restrict__ S)
{
    const int w = threadIdx.x >> 6, l = threadIdx.x & 63;
    const int b = blockIdx.x * 4 + w;
    const int row = l & 15, kq = (l >> 4) * 8;

    f32x4v sp = (f32x4v){0.f, 0.f, 0.f, 0.f};
    for (int k0 = 0; k0 < H_; k0 += 32) {
        int kk = k0 + kq;
        s16x8 wf = *(const s16x8*)&W1b[(size_t)row * H_ + kk];
        float4 t0 = *(const float4*)&t[(size_t)b * H_ + kk];
        float4 t1 = *(const float4*)&t[(size_t)b * H_ + kk + 4];
        float4 g0 = *(const float4*)&g[(size_t)b * H_ + kk];
        float4 g1 = *(const float4*)&g[(size_t)b * H_ + kk + 4];
        float wv[8];
        wv[0] = 2.f * g0.x * t0.x * (1.f - t0.x * t0.x);
        wv[1] = 2.f * g0.y * t0.y * (1.f - t0.y * t0.y);
        wv[2] = 2.f * g0.z * t0.z * (1.f - t0.z * t0.z);
        wv[3] = 2.f * g0.w * t0.w * (1.f - t0.w * t0.w);
        wv[4] = 2.f * g1.x * t1.x * (1.f - t1.x * t1.x);
        wv[5] = 2.f * g1.y * t1.y * (1.f - t1.y * t1.y);
        wv[6] = 2.f * g1.z * t1.z * (1.f - t1.z * t1.z);
        wv[7] = 2.f * g1.w * t1.w * (1.f - t1.w * t1.w);
        union { s16x8 v; bf16 e[8]; } af;
        #pragma unroll
        for (int e = 0; e < 8; ++e)
            af.e[e] = __float2bfloat16(wv[e] * bf2f((unsigned short)wf[e]));
        sp = __builtin_amdgcn_mfma_f32_16x16x32_bf16(af.v, wf, sp, 0, 0, 0);
    }
    #pragma unroll
    for (int r = 0; r < 4; ++r)
        S[(size_t)b * 256 + ((l >> 4) * 4 + r) * 16 + (l & 15)] += sp[r];
}

// ---------------- casts ----------------
__global__ __launch_bounds__(256) void cast_bf(const float* __restrict__ in, bf16* __restrict__ out, int n8)
{
    int i = blockIdx.x * 256 + threadIdx.x;
    if (i < n8) {
        const float4* p = (const float4*)in + (size_t)i * 2;
        float4 a = p[0], b = p[1];
        union { s16x8 v; bf16 e[8]; } u;
        u.e[0] = __float2bfloat16(a.x); u.e[1] = __float2bfloat16(a.y);
        u.e[2] = __float2bfloat16(a.z); u.e[3] = __float2bfloat16(a.w);
        u.e[4] = __float2bfloat16(b.x); u.e[5] = __float2bfloat16(b.y);
        u.e[6] = __float2bfloat16(b.z); u.e[7] = __float2bfloat16(b.w);
        *(s16x8*)&out[(size_t)i * 8] = u.v;
    }
}

// outT[c*R + r] = bf16(in[r*C + c]); if outN, also outN[r*C + c] = bf16(in[r*C + c])
__global__ __launch_bounds__(256) void castT(const float* __restrict__ in, bf16* __restrict__ outT,
    bf16* __restrict__ outN, int R, int C)
{
    __shared__ float tile[64][65];
    int r0 = blockIdx.x * 64, c0 = blockIdx.y * 64;
    int tx = threadIdx.x & 63, ty = threadIdx.x >> 6;
    #pragma unroll
    for (int k = 0; k < 16; ++k) {
        int rr = ty * 16 + k;
        float v = in[(size_t)(r0 + rr) * C + c0 + tx];
        tile[rr][tx] = v;
        if (outN) outN[(size_t)(r0 + rr) * C + c0 + tx] = __float2bfloat16(v);
    }
    __syncthreads();
    #pragma unroll
    for (int k = 0; k < 16; ++k) {
        int cc = ty * 16 + k;
        outT[(size_t)(c0 + cc) * R + r0 + tx] = __float2bfloat16(tile[tx][cc]);
    }
}

// ---------------- z_star / log-sigma / sigma (tanh fused, reads split-K accumulator) ----------------
__global__ __launch_bounds__(256) void zsig_kernel(const float* __restrict__ Ch,
    const float* __restrict__ b1, const float* __restrict__ Wmu, const float* __restrict__ bmu,
    const float* __restrict__ Wls, const float* __restrict__ bls,
    float* __restrict__ z_star, float* __restrict__ lsig, float* __restrict__ sigma)
{
    const int b = blockIdx.x, tid = threadIdx.x;
    float acc[17];
    #pragma unroll
    for (int i = 0; i < 17; ++i) acc[i] = 0.f;
    for (int hh = tid; hh < H_; hh += 256) {
        float hv = tanhf(Ch[(size_t)b * H_ + hh] + b1[hh]);
        const float* wr = &Wmu[(size_t)hh * 16];
        #pragma unroll
        for (int i = 0; i < 16; ++i) acc[i] += hv * wr[i];
        acc[16] += hv * Wls[hh];
    }
    __shared__ float red[17][4];
    const int wid = tid >> 6, lane = tid & 63;
    #pragma unroll
    for (int i = 0; i < 17; ++i) {
        float v = acc[i];
        #pragma unroll
        for (int off = 32; off; off >>= 1) v += __shfl_xor(v, off);
        if (lane == 0) red[i][wid] = v;
    }
    __syncthreads();
    if (tid < 17) {
        float v = red[tid][0] + red[tid][1] + red[tid][2] + red[tid][3];
        if (tid < 16) z_star[(size_t)b * 16 + tid] = v + bmu[tid];
        else { float ls = v + bls[0]; lsig[b] = ls; sigma[b] = expf(ls); }
    }
}

// t = tanh(z @ W1 + b1); optional fp32 out + bf16 out. K=16.
__global__ __launch_bounds__(256) void build_t(const float* __restrict__ z,
    const float* __restrict__ W1, const float* __restrict__ b1,
    float* __restrict__ tf, bf16* __restrict__ tb)
{
    __shared__ float zs[16];
    int b = blockIdx.x, tid = threadIdx.x;
    if (tid < 16) zs[tid] = z[(size_t)b * 16 + tid];
    __syncthreads();
    for (int hh = tid; hh < H_; hh += 256) {
        float a = b1[hh];
        #pragma unroll
        for (int i = 0; i < 16; ++i) a += zs[i] * W1[(size_t)i * H_ + hh];
        float tv = tanhf(a);
        if (tf) tf[(size_t)b * H_ + hh] = tv;
        tb[(size_t)b * H_ + hh] = __float2bfloat16(tv);
    }
}

// Vt[(b_local*16+i), h] = (1-t^2) * W1[i,h]  (bf16)
__global__ __launch_bounds__(256) void build_vt(const float* __restrict__ t,
    const float* __restrict__ W1, bf16* __restrict__ Vt, int b0)
{
    int bl = blockIdx.x, b = b0 + bl, tid = threadIdx.x;
    __shared__ float u[H_];
    for (int hh = tid; hh < H_; hh += 256) {
        float tv = t[(size_t)b * H_ + hh];
        u[hh] = 1.f - tv * tv;
    }
    __syncthreads();
    size_t base = (size_t)bl * 16 * H_;
    int hh = tid * 8;
    for (int i = 0; i < 16; ++i) {
        union { s16x8 v; bf16 e[8]; } pk;
        #pragma unroll
        for (int k = 0; k < 8; ++k)
            pk.e[k] = __float2bfloat16(u[hh + k] * W1[(size_t)i * H_ + hh + k]);
        *(s16x8*)&Vt[base + (size_t)i * H_ + hh] = pk.v;
    }
}

// ---------------- per-batch 16x16: barrier-free register solve ----------------
__global__ __launch_bounds__(64) void solve_kernel(const float* __restrict__ S,
    const float* __restrict__ sigma, const float* __restrict__ z_star,
    const float* __restrict__ eps, float* __restrict__ z_sample, float* __restrict__ d_out)
{
    const int lane = threadIdx.x;
    const int q = lane >> 4;
    const int j = lane & 15;
    const int b = blockIdx.x * 4 + q;

    const float sg = sigma[b];
    const float inv_s2 = 1.0f / (sg * sg);

    float a0[16], a[16];
    #pragma unroll
    for (int r = 0; r < 16; ++r) {
        a0[r] = S[(size_t)b * 256 + r * 16 + j] * inv_s2 + ((r == j) ? 1.0f : 0.0f);
        a[r] = a0[r];
    }

    #pragma unroll
    for (int k = 0; k < 14; ++k) {
        float x[16];
        #pragma unroll
        for (int r = 0; r < 16; ++r) x[r] = __shfl(a[k], r, 16);
        float sig2 = 0.f;
        #pragma unroll
        for (int r = 0; r < 16; ++r) if (r > k + 1) sig2 += x[r] * x[r];
        float x0 = x[k + 1];
        float normx = sqrtf(sig2 + x0 * x0);
        float alpha = (x0 >= 0.f) ? -normx : normx;
        float v[16];
        #pragma unroll
        for (int r = 0; r < 16; ++r)
            v[r] = (r <= k) ? 0.f : ((r == k + 1) ? x0 - alpha : x[r]);
        float vtv = 0.f;
        #pragma unroll
        for (int r = 0; r < 16; ++r) vtv += v[r] * v[r];
        float beta = (vtv > 1e-28f) ? 2.0f / vtv : 0.f;
        float sj = 0.f;
        #pragma unroll
        for (int r = 0; r < 16; ++r) sj += a[r] * v[r];
        float av[16];
        #pragma unroll
        for (int r = 0; r < 16; ++r) av[r] = __shfl(sj, r, 16);
        float vtav = 0.f;
        #pragma unroll
        for (int r = 0; r < 16; ++r) vtav += v[r] * av[r];
        float c = 0.5f * beta * vtav;
        float wv[16];
        #pragma unroll
        for (int r = 0; r < 16; ++r) wv[r] = beta * (av[r] - c * v[r]);
        float vj = (j <= k) ? 0.f : ((j == k + 1) ? a[k] - alpha : a[k]);
        float wj = beta * (sj - c * vj);
        #pragma unroll
        for (int r = 0; r < 16; ++r) a[r] -= v[r] * wj + wv[r] * vj;
    }

    float dg[16], eo[15];
    #pragma unroll
    for (int r = 0; r < 16; ++r) dg[r] = __shfl(a[r], r, 16);
    #pragma unroll
    for (int r = 0; r < 15; ++r) eo[r] = __shfl(a[r + 1], r, 16);

    float lo = 1e30f, hi = 1e30f;
    #pragma unroll
    for (int r = 0; r < 16; ++r) {
        float rad = ((r > 0) ? fabsf(eo[r - 1]) : 0.f) + ((r < 15) ? fabsf(eo[r]) : 0.f);
        lo = fminf(lo, dg[r] - rad);
        hi = fminf(hi, dg[r]);
    }
    lo -= 1e-4f; hi += 1e-4f;

    #pragma unroll
    for (int pass = 0; pass < 5; ++pass) {
        float step = (hi - lo) * (1.0f / 17.0f);
        float s = lo + step * (float)(j + 1);
        float qq = dg[0] - s;
        int cnt = (qq < 0.f) ? 1 : 0;
        #pragma unroll
        for (int i = 1; i < 16; ++i) {
            float denom = (fabsf(qq) < 1e-30f) ? -1e-30f : qq;
            qq = dg[i] - s - eo[i - 1] * eo[i - 1] / denom;
            cnt += (qq < 0.f) ? 1 : 0;
        }
        unsigned long long bal = __ballot(cnt >= 1);
        unsigned grp = (unsigned)((bal >> (q * 16)) & 0xffffull);
        int f = grp ? (__ffs(grp) - 1) : 16;
        float nlo = lo + step * (float)f;
        float nhi = (f < 16) ? (lo + step * (float)(f + 1)) : hi;
        lo = nlo; hi = nhi;
    }
    const float lam_min = 0.5f * (lo + hi);
    const float delta = 10.0f - lam_min;

    float bm[16];
    #pragma unroll
    for (int r = 0; r < 16; ++r) bm[r] = a0[r] + ((r == j) ? delta : 0.f);

    float ldsum = 0.f;
    #pragma unroll
    for (int kk = 0; kk < 16; ++kk) {
        float ck[16];
        #pragma unroll
        for (int r = 0; r < 16; ++r) ck[r] = __shfl(bm[kk], r, 16);
        float dkk = sqrtf(fmaxf(ck[kk], 1e-30f));
        float inv = 1.0f / dkk;
        ldsum += logf(dkk);
        float lfull[16];
        #pragma unroll
        for (int r = 0; r < 16; ++r) lfull[r] = ck[r] * inv;
        float lj = bm[kk] * inv;
        if (j == kk) {
            #pragma unroll
            for (int r = 0; r < 16; ++r) bm[r] = (r >= kk) ? lfull[r] : 0.f;
        } else if (j > kk) {
            #pragma unroll
            for (int r = 0; r < 16; ++r)
                if (r > kk) bm[r] -= lfull[r] * lj;
        }
    }

    float w[16];
    #pragma unroll
    for (int r = 0; r < 16; ++r) w[r] = 0.f;
    #pragma unroll
    for (int i = 0; i < 16; ++i) {
        float row[16];
        #pragma unroll
        for (int kx = 0; kx < 16; ++kx) row[kx] = __shfl(bm[i], kx, 16);
        float sacc = 0.f;
        #pragma unroll
        for (int kx = 0; kx < 16; ++kx) if (kx < i) sacc += row[kx] * w[kx];
        float invd = 1.0f / row[i];
        float val = (i == j) ? invd : (-sacc * invd);
        w[i] = (i >= j) ? val : 0.f;
    }

    float tsum = 0.f;
    #pragma unroll
    for (int r = 0; r < 16; ++r) tsum += w[r] * w[r];
    float zv = z_star[(size_t)b * 16 + j];
    float ep = eps[(size_t)b * 16 + j];
    float epsv[16];
    #pragma unroll
    for (int r = 0; r < 16; ++r) epsv[r] = __shfl(ep, r, 16);
    float zoff = 0.f;
    #pragma unroll
    for (int r = 0; r < 16; ++r) zoff += w[r] * epsv[r];
    z_sample[(size_t)b * 16 + j] = zv + zoff;

    float zsq = zv * zv;
    #pragma unroll
    for (int off = 1; off < 16; off <<= 1) {
        tsum += __shfl_xor(tsum, off);
        zsq  += __shfl_xor(zsq, off);
    }
    if (j == 0) {
        d_out[2 * 512 + b] = 0.5f * zsq + 0.5f * tsum;
        d_out[3 * 512 + b] = ldsum;
        d_out[4 * 512 + b] = sg;
    }
}

__global__ void finalize_kernel(const float* __restrict__ rlsum, const float* __restrict__ sigma,
    const float* __restrict__ lsig, float* __restrict__ d_out)
{
    int b = blockIdx.x * 256 + threadIdx.x;
    if (b < BS_) {
        float sg = sigma[b];
        float rl = rlsum[b] / (2.0f * sg * sg);
        float le = d_out[2 * 512 + b];
        float ld = d_out[3 * 512 + b];
        d_out[b] = (rl + le + ld) / 3072.0f + lsig[b];
        d_out[512 + b] = rl;
    }
}

extern "C" void kernel_launch(void* const* d_in, const int* in_sizes, int n_in,
                              void* d_out, int out_size, void* d_ws, size_t ws_size,
                              hipStream_t stream)
{
    const float* x       = (const float*)d_in[0];
    const float* eps     = (const float*)d_in[1];
    const float* enc_W1  = (const float*)d_in[2];
    const float* enc_b1  = (const float*)d_in[3];
    const float* enc_Wmu = (const float*)d_in[4];
    const float* enc_bmu = (const float*)d_in[5];
    const float* enc_Wls = (const float*)d_in[6];
    const float* enc_bls = (const float*)d_in[7];
    const float* dec_W1  = (const float*)d_in[8];
    const float* dec_b1  = (const float*)d_in[9];
    const float* dec_W2  = (const float*)d_in[10];
    const float* dec_b2  = (const float*)d_in[11];
    float* out = (float*)d_out;

    char* wsb = (char*)d_ws;
    size_t off = 0;
    auto alloc = [&](size_t bytes) -> void* {
        off = (off + 255) & ~(size_t)255;
        void* p = wsb + off;
        off += bytes;
        return p;
    };

    float* t    = (float*)alloc((size_t)BS_ * H_ * 4);
    float* g    = (float*)alloc((size_t)BS_ * H_ * 4);
    float* z_st = (float*)alloc((size_t)BS_ * 16 * 4);
    float* lsig = (float*)alloc(BS_ * 4);
    float* sigm = (float*)alloc(BS_ * 4);
    float* z_sm = (float*)alloc((size_t)BS_ * 16 * 4);
    float* rls  = (float*)alloc(BS_ * 4);
    float* S    = (float*)alloc((size_t)BS_ * 256 * 4);
    float* Ch   = (float*)alloc((size_t)BS_ * H_ * 4);
    float* Cd   = (float*)alloc((size_t)BS_ * D_ * 4);
    bf16* x_bf  = (bf16*)alloc((size_t)BS_ * D_ * 2);
    bf16* eW1t  = (bf16*)alloc((size_t)H_ * D_ * 2);
    bf16* W2b   = (bf16*)alloc((size_t)H_ * D_ * 2);
    bf16* W2t   = (bf16*)alloc((size_t)D_ * H_ * 2);
    bf16* W1b   = (bf16*)alloc((size_t)N_ * H_ * 2);
    bf16* t_bf  = (bf16*)alloc((size_t)BS_ * H_ * 2);
    bf16* e_bf  = (bf16*)alloc((size_t)BS_ * D_ * 2);
    bf16* t2b   = (bf16*)alloc((size_t)BS_ * H_ * 2);

    int nb = 0;
    size_t base_off = off;
    const int cand[3] = {512, 128, 32};
    bf16* Vt = nullptr;
    for (int ci = 0; ci < 3; ++ci) {
        off = base_off;
        int n = cand[ci];
        bf16* vt = (bf16*)alloc((size_t)n * 16 * H_ * 2);
        if (off <= ws_size) { nb = n; Vt = vt; break; }
    }
    if (nb == 0) return;

    // casts
    cast_bf<<<dim3((BS_ * D_ / 8 + 255) / 256), 256, 0, stream>>>(x, x_bf, BS_ * D_ / 8);
    castT<<<dim3(D_ / 64, H_ / 64), 256, 0, stream>>>(enc_W1, eW1t, nullptr, D_, H_);
    castT<<<dim3(H_ / 64, D_ / 64), 256, 0, stream>>>(dec_W2, W2t, W2b, H_, D_);
    cast_bf<<<dim3((N_ * H_ / 8 + 255) / 256), 256, 0, stream>>>(dec_W1, W1b, N_ * H_ / 8);

    hipMemsetAsync(Ch, 0, (size_t)BS_ * H_ * 4, stream);
    hipMemsetAsync(Cd, 0, (size_t)BS_ * D_ * 4, stream);
    hipMemsetAsync(g,  0, (size_t)BS_ * H_ * 4, stream);
    hipMemsetAsync(S,  0, (size_t)BS_ * 256 * 4, stream);

    // h-accumulator = x @ enc_W1  [split-K 4]; tanh fused into zsig
    mfma_nt_sk<<<dim3(H_ / 128, BS_ / 128, 4), 256, 0, stream>>>(
        x_bf, eW1t, Ch, BS_, H_, D_, D_ / 4);
    zsig_kernel<<<dim3(BS_), 256, 0, stream>>>(Ch, enc_b1, enc_Wmu, enc_bmu, enc_Wls, enc_bls, z_st, lsig, sigm);
    // t = tanh(z_star @ dec_W1 + b1)
    build_t<<<dim3(BS_), 256, 0, stream>>>(z_st, dec_W1, dec_b1, t, t_bf);
    // e = x - (t @ W2 + b2)  [split-K 4]
    mfma_nt_sk<<<dim3(D_ / 128, BS_ / 128, 4), 256, 0, stream>>>(
        t_bf, W2t, Cd, BS_, D_, H_, H_ / 4);
    ep_ebf<<<dim3(BS_ * D_ / 8 / 256), 256, 0, stream>>>(Cd, dec_b2, x, e_bf, BS_ * D_, D_);
    // g = e @ W2^T  [split-K 4, direct accumulate]
    mfma_nt_sk<<<dim3(H_ / 128, BS_ / 128, 4), 256, 0, stream>>>(
        e_bf, W2b, g, BS_, H_, D_, D_ / 4);

    // S = J^T J (fused, BK=64 swizzled)
    for (int b0 = 0; b0 < BS_; b0 += nb) {
        build_vt<<<dim3(nb), 256, 0, stream>>>(t, dec_W1, Vt, b0);
        jtj_fused<<<dim3(D_ / 128, nb * 16 / 128), 256, 0, stream>>>(
            Vt, W2t, S, nb * 16 / 128, b0);
    }
    // S += hessian core
    hess_mfma<<<dim3(BS_ / 4), 256, 0, stream>>>(t, g, W1b, S);

    // eig-min / Cholesky / solves / scalars
    solve_kernel<<<dim3(BS_ / 4), 64, 0, stream>>>(S, sigm, z_st, eps, z_sm, out);
    // t2 = tanh(z_sample @ dec_W1 + b1)
    build_t<<<dim3(BS_), 256, 0, stream>>>(z_sm, dec_W1, dec_b1, nullptr, t2b);
    // recon GEMM [split-K 4] + row-sum epilogue
    hipMemsetAsync(Cd, 0, (size_t)BS_ * D_ * 4, stream);
    mfma_nt_sk<<<dim3(D_ / 128, BS_ / 128, 4), 256, 0, stream>>>(
        t2b, W2t, Cd, BS_, D_, H_, H_ / 4);
    ep_recon<<<dim3(BS_), 256, 0, stream>>>(Cd, dec_b2, x, rls);
    finalize_kernel<<<dim3(2), 256, 0, stream>>>(rls, sigm, lsig, out);
}

// Round 7
// 359.333 us; speedup vs baseline: 17.1660x; 1.0485x over previous
//
#include <hip/hip_runtime.h>
#include <hip/hip_bf16.h>
#include <math.h>

#define D_ 3072
#define H_ 2048
#define N_ 16
#define BS_ 512

typedef short s16x8 __attribute__((ext_vector_type(8)));
typedef float f32x4v __attribute__((ext_vector_type(4)));
typedef __hip_bfloat16 bf16;

__device__ __forceinline__ void gload_lds16(const void* g, void* l) {
    __builtin_amdgcn_global_load_lds((const __attribute__((address_space(1))) void*)g,
                                     (__attribute__((address_space(3))) void*)l, 16, 0, 0);
}

__device__ __forceinline__ float bf2f(unsigned short u) {
    unsigned v = (unsigned)u << 16; float f; __builtin_memcpy(&f, &v, 4); return f;
}

// ---------------- split-K NT GEMM: C(f32) += A(M,K)*Bt(N,K)^T over K-chunk ----------------
__global__ __launch_bounds__(256) void mfma_nt_sk(
    const bf16* __restrict__ A, const bf16* __restrict__ Bt,
    float* __restrict__ C, int M, int N, int K, int KC)
{
    __shared__ __align__(16) bf16 As[128 * 32];
    __shared__ __align__(16) bf16 Bs[128 * 32];
    const int tid = threadIdx.x;
    const int w = tid >> 6, l = tid & 63;
    const int wr = w >> 1, wc = w & 1;
    const int m0 = blockIdx.y * 128, n0 = blockIdx.x * 128;
    const int kbeg = blockIdx.z * KC;

    f32x4v acc[4][4];
    #pragma unroll
    for (int a = 0; a < 4; ++a)
        #pragma unroll
        for (int b = 0; b < 4; ++b) acc[a][b] = (f32x4v){0.f, 0.f, 0.f, 0.f};

    const int srow = l >> 2;
    const int scol = (l & 3) * 8;

    for (int k0 = kbeg; k0 < kbeg + KC; k0 += 32) {
        #pragma unroll
        for (int q = 0; q < 2; ++q) {
            int r0 = w * 32 + q * 16;
            gload_lds16(&A[(size_t)(m0 + r0 + srow) * K + k0 + scol], &As[r0 * 32]);
            gload_lds16(&Bt[(size_t)(n0 + r0 + srow) * K + k0 + scol], &Bs[r0 * 32]);
        }
        __syncthreads();
        s16x8 af[4], bfr[4];
        #pragma unroll
        for (int mf = 0; mf < 4; ++mf)
            af[mf] = *(const s16x8*)&As[(wr * 64 + mf * 16 + (l & 15)) * 32 + (l >> 4) * 8];
        #pragma unroll
        for (int nf = 0; nf < 4; ++nf)
            bfr[nf] = *(const s16x8*)&Bs[(wc * 64 + nf * 16 + (l & 15)) * 32 + (l >> 4) * 8];
        #pragma unroll
        for (int mf = 0; mf < 4; ++mf)
            #pragma unroll
            for (int nf = 0; nf < 4; ++nf)
                acc[mf][nf] = __builtin_amdgcn_mfma_f32_16x16x32_bf16(af[mf], bfr[nf], acc[mf][nf], 0, 0, 0);
        __syncthreads();
    }

    #pragma unroll
    for (int mf = 0; mf < 4; ++mf)
        #pragma unroll
        for (int nf = 0; nf < 4; ++nf) {
            int n = n0 + wc * 64 + nf * 16 + (l & 15);
            #pragma unroll
            for (int r = 0; r < 4; ++r) {
                int m = m0 + wr * 64 + mf * 16 + (l >> 4) * 4 + r;
                atomicAdd(&C[(size_t)m * N + n], acc[mf][nf][r]);
            }
        }
}

// ---------------- epilogues ----------------
__global__ __launch_bounds__(256) void ep_ebf(const float* __restrict__ C,
    const float* __restrict__ bias, const float* __restrict__ X,
    bf16* __restrict__ Eout, int MN, int N)
{
    int base = (blockIdx.x * 256 + threadIdx.x) * 8;
    if (base < MN) {
        float4 c0 = *(const float4*)&C[base];
        float4 c1 = *(const float4*)&C[base + 4];
        float4 x0 = *(const float4*)&X[base];
        float4 x1 = *(const float4*)&X[base + 4];
        int n = base % N;
        float4 b0 = *(const float4*)&bias[n];
        float4 b1 = *(const float4*)&bias[n + 4];
        union { s16x8 v; bf16 e[8]; } u;
        u.e[0] = __float2bfloat16(x0.x - (c0.x + b0.x));
        u.e[1] = __float2bfloat16(x0.y - (c0.y + b0.y));
        u.e[2] = __float2bfloat16(x0.z - (c0.z + b0.z));
        u.e[3] = __float2bfloat16(x0.w - (c0.w + b0.w));
        u.e[4] = __float2bfloat16(x1.x - (c1.x + b1.x));
        u.e[5] = __float2bfloat16(x1.y - (c1.y + b1.y));
        u.e[6] = __float2bfloat16(x1.z - (c1.z + b1.z));
        u.e[7] = __float2bfloat16(x1.w - (c1.w + b1.w));
        *(s16x8*)&Eout[base] = u.v;
    }
}

__global__ __launch_bounds__(256) void ep_recon(const float* __restrict__ C,
    const float* __restrict__ bias, const float* __restrict__ X, float* __restrict__ rls)
{
    int m = blockIdx.x;
    float s = 0.f;
    for (int n = threadIdx.x * 4; n < D_; n += 1024) {
        float4 c = *(const float4*)&C[(size_t)m * D_ + n];
        float4 bb = *(const float4*)&bias[n];
        float4 xx = *(const float4*)&X[(size_t)m * D_ + n];
        float v0 = c.x + bb.x - xx.x, v1 = c.y + bb.y - xx.y;
        float v2 = c.z + bb.z - xx.z, v3 = c.w + bb.w - xx.w;
        s += v0 * v0 + v1 * v1 + v2 * v2 + v3 * v3;
    }
    __shared__ float red[4];
    int wid = threadIdx.x >> 6, lane = threadIdx.x & 63;
    #pragma unroll
    for (int off = 32; off; off >>= 1) s += __shfl_xor(s, off);
    if (lane == 0) red[wid] = s;
    __syncthreads();
    if (threadIdx.x == 0) rls[m] = red[0] + red[1] + red[2] + red[3];
}

// ---------------- fused J-GEMM + J^T J (round-5 proven form: BK=32, linear LDS) ----------------
__global__ __launch_bounds__(256) void jtj_fused(
    const bf16* __restrict__ Vt, const bf16* __restrict__ W2t,
    float* __restrict__ S, int Mb, int b0)
{
    __shared__ union {
        struct { __align__(16) bf16 As[128 * 32]; __align__(16) bf16 Bs[128 * 32]; } s;
        __align__(16) bf16 J[128 * 136];
    } u;
    const int tid = threadIdx.x;
    const int w = tid >> 6, l = tid & 63;
    const int wr = w >> 1, wc = w & 1;

    int mb, nb;
    if ((Mb & 7) == 0) {
        int lin = blockIdx.y * 24 + blockIdx.x;
        int xcd = lin & 7, idx = lin >> 3;
        int mchunk = Mb >> 3;
        mb = xcd * mchunk + idx / 24;
        nb = idx % 24;
    } else { mb = blockIdx.y; nb = blockIdx.x; }
    const int m0 = mb * 128, n0 = nb * 128;

    f32x4v acc[4][4];
    #pragma unroll
    for (int a = 0; a < 4; ++a)
        #pragma unroll
        for (int b = 0; b < 4; ++b) acc[a][b] = (f32x4v){0.f, 0.f, 0.f, 0.f};

    const int srow = l >> 2;
    const int scol = (l & 3) * 8;

    for (int k0 = 0; k0 < H_; k0 += 32) {
        #pragma unroll
        for (int q = 0; q < 2; ++q) {
            int r0 = w * 32 + q * 16;
            gload_lds16(&Vt[(size_t)(m0 + r0 + srow) * H_ + k0 + scol], &u.s.As[r0 * 32]);
            gload_lds16(&W2t[(size_t)(n0 + r0 + srow) * H_ + k0 + scol], &u.s.Bs[r0 * 32]);
        }
        __syncthreads();
        s16x8 af[4], bfr[4];
        #pragma unroll
        for (int mf = 0; mf < 4; ++mf)
            af[mf] = *(const s16x8*)&u.s.As[(wr * 64 + mf * 16 + (l & 15)) * 32 + (l >> 4) * 8];
        #pragma unroll
        for (int nf = 0; nf < 4; ++nf)
            bfr[nf] = *(const s16x8*)&u.s.Bs[(wc * 64 + nf * 16 + (l & 15)) * 32 + (l >> 4) * 8];
        #pragma unroll
        for (int mf = 0; mf < 4; ++mf)
            #pragma unroll
            for (int nf = 0; nf < 4; ++nf)
                acc[mf][nf] = __builtin_amdgcn_mfma_f32_16x16x32_bf16(af[mf], bfr[nf], acc[mf][nf], 0, 0, 0);
        __syncthreads();
    }

    __syncthreads();
    #pragma unroll
    for (int mf = 0; mf < 4; ++mf) {
        int rbase = wr * 64 + mf * 16 + (l >> 4) * 4;
        #pragma unroll
        for (int nf = 0; nf < 4; ++nf) {
            int col = wc * 64 + nf * 16 + (l & 15);
            #pragma unroll
            for (int r = 0; r < 4; ++r)
                u.J[(rbase + r) * 136 + col] = __float2bfloat16(acc[mf][nf][r]);
        }
    }
    __syncthreads();

    #pragma unroll
    for (int t2 = 0; t2 < 2; ++t2) {
        int bl = w * 2 + t2;
        f32x4v sp = (f32x4v){0.f, 0.f, 0.f, 0.f};
        #pragma unroll
        for (int kq = 0; kq < 4; ++kq) {
            s16x8 fr = *(const s16x8*)&u.J[(bl * 16 + (l & 15)) * 136 + kq * 32 + (l >> 4) * 8];
            sp = __builtin_amdgcn_mfma_f32_16x16x32_bf16(fr, fr, sp, 0, 0, 0);
        }
        int bglob = b0 + mb * 8 + bl;
        #pragma unroll
        for (int r = 0; r < 4; ++r)
            atomicAdd(&S[(size_t)bglob * 256 + ((l >> 4) * 4 + r) * 16 + (l & 15)], sp[r]);
    }
}

// ---------------- hessian via MFMA ----------------
__global__ __launch_bounds__(256) void hess_mfma(const float* __restrict__ t,
    const float* __restrict__ g, const bf16* __restrict__ W1b, float* __restrict__ S)
{
    const int w = threadIdx.x >> 6, l = threadIdx.x & 63;
    const int b = blockIdx.x * 4 + w;
    const int row = l & 15, kq = (l >> 4) * 8;

    f32x4v sp = (f32x4v){0.f, 0.f, 0.f, 0.f};
    for (int k0 = 0; k0 < H_; k0 += 32) {
        int kk = k0 + kq;
        s16x8 wf = *(const s16x8*)&W1b[(size_t)row * H_ + kk];
        float4 t0 = *(const float4*)&t[(size_t)b * H_ + kk];
        float4 t1 = *(const float4*)&t[(size_t)b * H_ + kk + 4];
        float4 g0 = *(const float4*)&g[(size_t)b * H_ + kk];
        float4 g1 = *(const float4*)&g[(size_t)b * H_ + kk + 4];
        float wv[8];
        wv[0] = 2.f * g0.x * t0.x * (1.f - t0.x * t0.x);
        wv[1] = 2.f * g0.y * t0.y * (1.f - t0.y * t0.y);
        wv[2] = 2.f * g0.z * t0.z * (1.f - t0.z * t0.z);
        wv[3] = 2.f * g0.w * t0.w * (1.f - t0.w * t0.w);
        wv[4] = 2.f * g1.x * t1.x * (1.f - t1.x * t1.x);
        wv[5] = 2.f * g1.y * t1.y * (1.f - t1.y * t1.y);
        wv[6] = 2.f * g1.z * t1.z * (1.f - t1.z * t1.z);
        wv[7] = 2.f * g1.w * t1.w * (1.f - t1.w * t1.w);
        union { s16x8 v; bf16 e[8]; } af;
        #pragma unroll
        for (int e = 0; e < 8; ++e)
            af.e[e] = __float2bfloat16(wv[e] * bf2f((unsigned short)wf[e]));
        sp = __builtin_amdgcn_mfma_f32_16x16x32_bf16(af.v, wf, sp, 0, 0, 0);
    }
    #pragma unroll
    for (int r = 0; r < 4; ++r)
        S[(size_t)b * 256 + ((l >> 4) * 4 + r) * 16 + (l & 15)] += sp[r];
}

// ---------------- fused prep: all casts in one launch ----------------
// seg0: x -> x_bf (768 blocks); seg1: enc_W1 (D x H) -> eW1t (1536);
// seg2: dec_W2 (H x D) -> W2t + W2b (1536); seg3: dec_W1 -> W1b (16)
__global__ __launch_bounds__(256) void prep_all(
    const float* __restrict__ x, const float* __restrict__ enc_W1,
    const float* __restrict__ dec_W2, const float* __restrict__ dec_W1,
    bf16* __restrict__ x_bf, bf16* __restrict__ eW1t,
    bf16* __restrict__ W2t, bf16* __restrict__ W2b, bf16* __restrict__ W1b)
{
    __shared__ float tile[64][65];
    const int blk = blockIdx.x;
    const int tid = threadIdx.x;
    if (blk < 768) {                                  // x cast: 196608 x8 elems
        int i = blk * 256 + tid;
        const float4* p = (const float4*)x + (size_t)i * 2;
        float4 a = p[0], b = p[1];
        union { s16x8 v; bf16 e[8]; } u;
        u.e[0] = __float2bfloat16(a.x); u.e[1] = __float2bfloat16(a.y);
        u.e[2] = __float2bfloat16(a.z); u.e[3] = __float2bfloat16(a.w);
        u.e[4] = __float2bfloat16(b.x); u.e[5] = __float2bfloat16(b.y);
        u.e[6] = __float2bfloat16(b.z); u.e[7] = __float2bfloat16(b.w);
        *(s16x8*)&x_bf[(size_t)i * 8] = u.v;
    } else if (blk < 768 + 1536) {                    // enc_W1 transpose (R=D, C=H)
        int bid = blk - 768;
        int r0 = (bid % 48) * 64, c0 = (bid / 48) * 64;
        int tx = tid & 63, ty = tid >> 6;
        #pragma unroll
        for (int k = 0; k < 16; ++k) {
            int rr = ty * 16 + k;
            tile[rr][tx] = enc_W1[(size_t)(r0 + rr) * H_ + c0 + tx];
        }
        __syncthreads();
        #pragma unroll
        for (int k = 0; k < 16; ++k) {
            int cc = ty * 16 + k;
            eW1t[(size_t)(c0 + cc) * D_ + r0 + tx] = __float2bfloat16(tile[tx][cc]);
        }
    } else if (blk < 768 + 3072) {                    // dec_W2 transpose+copy (R=H, C=D)
        int bid = blk - 768 - 1536;
        int r0 = (bid % 32) * 64, c0 = (bid / 32) * 64;
        int tx = tid & 63, ty = tid >> 6;
        #pragma unroll
        for (int k = 0; k < 16; ++k) {
            int rr = ty * 16 + k;
            float v = dec_W2[(size_t)(r0 + rr) * D_ + c0 + tx];
            tile[rr][tx] = v;
            W2b[(size_t)(r0 + rr) * D_ + c0 + tx] = __float2bfloat16(v);
        }
        __syncthreads();
        #pragma unroll
        for (int k = 0; k < 16; ++k) {
            int cc = ty * 16 + k;
            W2t[(size_t)(c0 + cc) * H_ + r0 + tx] = __float2bfloat16(tile[tx][cc]);
        }
    } else {                                          // dec_W1 cast: 4096 x8 elems
        int i = (blk - 768 - 3072) * 256 + tid;
        if (i < N_ * H_ / 8) {
            const float4* p = (const float4*)dec_W1 + (size_t)i * 2;
            float4 a = p[0], b = p[1];
            union { s16x8 v; bf16 e[8]; } u;
            u.e[0] = __float2bfloat16(a.x); u.e[1] = __float2bfloat16(a.y);
            u.e[2] = __float2bfloat16(a.z); u.e[3] = __float2bfloat16(a.w);
            u.e[4] = __float2bfloat16(b.x); u.e[5] = __float2bfloat16(b.y);
            u.e[6] = __float2bfloat16(b.z); u.e[7] = __float2bfloat16(b.w);
            *(s16x8*)&W1b[(size_t)i * 8] = u.v;
        }
    }
}

// ---------------- zsig + build_t fused: z_star/sigma, then t = tanh(z@W1+b1) ----------------
__global__ __launch_bounds__(256) void zsig_t_kernel(const float* __restrict__ Ch,
    const float* __restrict__ enc_b1, const float* __restrict__ Wmu, const float* __restrict__ bmu,
    const float* __restrict__ Wls, const float* __restrict__ bls,
    const float* __restrict__ dW1, const float* __restrict__ db1,
    float* __restrict__ z_star, float* __restrict__ lsig, float* __restrict__ sigma,
    float* __restrict__ t, bf16* __restrict__ tb)
{
    const int b = blockIdx.x, tid = threadIdx.x;
    float acc[17];
    #pragma unroll
    for (int i = 0; i < 17; ++i) acc[i] = 0.f;
    for (int hh = tid; hh < H_; hh += 256) {
        float hv = tanhf(Ch[(size_t)b * H_ + hh] + enc_b1[hh]);
        const float* wr = &Wmu[(size_t)hh * 16];
        #pragma unroll
        for (int i = 0; i < 16; ++i) acc[i] += hv * wr[i];
        acc[16] += hv * Wls[hh];
    }
    __shared__ float red[17][4];
    __shared__ float zs[16];
    const int wid = tid >> 6, lane = tid & 63;
    #pragma unroll
    for (int i = 0; i < 17; ++i) {
        float v = acc[i];
        #pragma unroll
        for (int off = 32; off; off >>= 1) v += __shfl_xor(v, off);
        if (lane == 0) red[i][wid] = v;
    }
    __syncthreads();
    if (tid < 17) {
        float v = red[tid][0] + red[tid][1] + red[tid][2] + red[tid][3];
        if (tid < 16) { float z = v + bmu[tid]; zs[tid] = z; z_star[(size_t)b * 16 + tid] = z; }
        else { float ls = v + bls[0]; lsig[b] = ls; sigma[b] = expf(ls); }
    }
    __syncthreads();
    for (int hh = tid; hh < H_; hh += 256) {
        float a = db1[hh];
        #pragma unroll
        for (int i = 0; i < 16; ++i) a += zs[i] * dW1[(size_t)i * H_ + hh];
        float tv = tanhf(a);
        t[(size_t)b * H_ + hh] = tv;
        tb[(size_t)b * H_ + hh] = __float2bfloat16(tv);
    }
}

// t = tanh(z @ W1 + b1), bf16 out only
__global__ __launch_bounds__(256) void build_t(const float* __restrict__ z,
    const float* __restrict__ W1, const float* __restrict__ b1, bf16* __restrict__ tb)
{
    __shared__ float zs[16];
    int b = blockIdx.x, tid = threadIdx.x;
    if (tid < 16) zs[tid] = z[(size_t)b * 16 + tid];
    __syncthreads();
    for (int hh = tid; hh < H_; hh += 256) {
        float a = b1[hh];
        #pragma unroll
        for (int i = 0; i < 16; ++i) a += zs[i] * W1[(size_t)i * H_ + hh];
        tb[(size_t)b * H_ + hh] = __float2bfloat16(tanhf(a));
    }
}

// Vt[(b_local*16+i), h] = (1-t^2) * W1[i,h]  (bf16)
__global__ __launch_bounds__(256) void build_vt(const float* __restrict__ t,
    const float* __restrict__ W1, bf16* __restrict__ Vt, int b0)
{
    int bl = blockIdx.x, b = b0 + bl, tid = threadIdx.x;
    __shared__ float u[H_];
    for (int hh = tid; hh < H_; hh += 256) {
        float tv = t[(size_t)b * H_ + hh];
        u[hh] = 1.f - tv * tv;
    }
    __syncthreads();
    size_t base = (size_t)bl * 16 * H_;
    int hh = tid * 8;
    for (int i = 0; i < 16; ++i) {
        union { s16x8 v; bf16 e[8]; } pk;
        #pragma unroll
        for (int k = 0; k < 8; ++k)
            pk.e[k] = __float2bfloat16(u[hh + k] * W1[(size_t)i * H_ + hh + k]);
        *(s16x8*)&Vt[base + (size_t)i * H_ + hh] = pk.v;
    }
}

// ---------------- per-batch 16x16: barrier-free register solve ----------------
__global__ __launch_bounds__(64) void solve_kernel(const float* __restrict__ S,
    const float* __restrict__ sigma, const float* __restrict__ z_star,
    const float* __restrict__ eps, float* __restrict__ z_sample, float* __restrict__ d_out)
{
    const int lane = threadIdx.x;
    const int q = lane >> 4;
    const int j = lane & 15;
    const int b = blockIdx.x * 4 + q;

    const float sg = sigma[b];
    const float inv_s2 = 1.0f / (sg * sg);

    float a0[16], a[16];
    #pragma unroll
    for (int r = 0; r < 16; ++r) {
        a0[r] = S[(size_t)b * 256 + r * 16 + j] * inv_s2 + ((r == j) ? 1.0f : 0.0f);
        a[r] = a0[r];
    }

    #pragma unroll
    for (int k = 0; k < 14; ++k) {
        float x[16];
        #pragma unroll
        for (int r = 0; r < 16; ++r) x[r] = __shfl(a[k], r, 16);
        float sig2 = 0.f;
        #pragma unroll
        for (int r = 0; r < 16; ++r) if (r > k + 1) sig2 += x[r] * x[r];
        float x0 = x[k + 1];
        float normx = sqrtf(sig2 + x0 * x0);
        float alpha = (x0 >= 0.f) ? -normx : normx;
        float v[16];
        #pragma unroll
        for (int r = 0; r < 16; ++r)
            v[r] = (r <= k) ? 0.f : ((r == k + 1) ? x0 - alpha : x[r]);
        float vtv = 0.f;
        #pragma unroll
        for (int r = 0; r < 16; ++r) vtv += v[r] * v[r];
        float beta = (vtv > 1e-28f) ? 2.0f / vtv : 0.f;
        float sj = 0.f;
        #pragma unroll
        for (int r = 0; r < 16; ++r) sj += a[r] * v[r];
        float av[16];
        #pragma unroll
        for (int r = 0; r < 16; ++r) av[r] = __shfl(sj, r, 16);
        float vtav = 0.f;
        #pragma unroll
        for (int r = 0; r < 16; ++r) vtav += v[r] * av[r];
        float c = 0.5f * beta * vtav;
        float wv[16];
        #pragma unroll
        for (int r = 0; r < 16; ++r) wv[r] = beta * (av[r] - c * v[r]);
        float vj = (j <= k) ? 0.f : ((j == k + 1) ? a[k] - alpha : a[k]);
        float wj = beta * (sj - c * vj);
        #pragma unroll
        for (int r = 0; r < 16; ++r) a[r] -= v[r] * wj + wv[r] * vj;
    }

    float dg[16], eo[15];
    #pragma unroll
    for (int r = 0; r < 16; ++r) dg[r] = __shfl(a[r], r, 16);
    #pragma unroll
    for (int r = 0; r < 15; ++r) eo[r] = __shfl(a[r + 1], r, 16);

    float lo = 1e30f, hi = 1e30f;
    #pragma unroll
    for (int r = 0; r < 16; ++r) {
        float rad = ((r > 0) ? fabsf(eo[r - 1]) : 0.f) + ((r < 15) ? fabsf(eo[r]) : 0.f);
        lo = fminf(lo, dg[r] - rad);
        hi = fminf(hi, dg[r]);
    }
    lo -= 1e-4f; hi += 1e-4f;

    #pragma unroll
    for (int pass = 0; pass < 5; ++pass) {
        float step = (hi - lo) * (1.0f / 17.0f);
        float s = lo + step * (float)(j + 1);
        float qq = dg[0] - s;
        int cnt = (qq < 0.f) ? 1 : 0;
        #pragma unroll
        for (int i = 1; i < 16; ++i) {
            float denom = (fabsf(qq) < 1e-30f) ? -1e-30f : qq;
            qq = dg[i] - s - eo[i - 1] * eo[i - 1] / denom;
            cnt += (qq < 0.f) ? 1 : 0;
        }
        unsigned long long bal = __ballot(cnt >= 1);
        unsigned grp = (unsigned)((bal >> (q * 16)) & 0xffffull);
        int f = grp ? (__ffs(grp) - 1) : 16;
        float nlo = lo + step * (float)f;
        float nhi = (f < 16) ? (lo + step * (float)(f + 1)) : hi;
        lo = nlo; hi = nhi;
    }
    const float lam_min = 0.5f * (lo + hi);
    const float delta = 10.0f - lam_min;

    float bm[16];
    #pragma unroll
    for (int r = 0; r < 16; ++r) bm[r] = a0[r] + ((r == j) ? delta : 0.f);

    float ldsum = 0.f;
    #pragma unroll
    for (int kk = 0; kk < 16; ++kk) {
        float ck[16];
        #pragma unroll
        for (int r = 0; r < 16; ++r) ck[r] = __shfl(bm[kk], r, 16);
        float dkk = sqrtf(fmaxf(ck[kk], 1e-30f));
        float inv = 1.0f / dkk;
        ldsum += logf(dkk);
        float lfull[16];
        #pragma unroll
        for (int r = 0; r < 16; ++r) lfull[r] = ck[r] * inv;
        float lj = bm[kk] * inv;
        if (j == kk) {
            #pragma unroll
            for (int r = 0; r < 16; ++r) bm[r] = (r >= kk) ? lfull[r] : 0.f;
        } else if (j > kk) {
            #pragma unroll
            for (int r = 0; r < 16; ++r)
                if (r > kk) bm[r] -= lfull[r] * lj;
        }
    }

    float w[16];
    #pragma unroll
    for (int r = 0; r < 16; ++r) w[r] = 0.f;
    #pragma unroll
    for (int i = 0; i < 16; ++i) {
        float row[16];
        #pragma unroll
        for (int kx = 0; kx < 16; ++kx) row[kx] = __shfl(bm[i], kx, 16);
        float sacc = 0.f;
        #pragma unroll
        for (int kx = 0; kx < 16; ++kx) if (kx < i) sacc += row[kx] * w[kx];
        float invd = 1.0f / row[i];
        float val = (i == j) ? invd : (-sacc * invd);
        w[i] = (i >= j) ? val : 0.f;
    }

    float tsum = 0.f;
    #pragma unroll
    for (int r = 0; r < 16; ++r) tsum += w[r] * w[r];
    float zv = z_star[(size_t)b * 16 + j];
    float ep = eps[(size_t)b * 16 + j];
    float epsv[16];
    #pragma unroll
    for (int r = 0; r < 16; ++r) epsv[r] = __shfl(ep, r, 16);
    float zoff = 0.f;
    #pragma unroll
    for (int r = 0; r < 16; ++r) zoff += w[r] * epsv[r];
    z_sample[(size_t)b * 16 + j] = zv + zoff;

    float zsq = zv * zv;
    #pragma unroll
    for (int off = 1; off < 16; off <<= 1) {
        tsum += __shfl_xor(tsum, off);
        zsq  += __shfl_xor(zsq, off);
    }
    if (j == 0) {
        d_out[2 * 512 + b] = 0.5f * zsq + 0.5f * tsum;
        d_out[3 * 512 + b] = ldsum;
        d_out[4 * 512 + b] = sg;
    }
}

__global__ void finalize_kernel(const float* __restrict__ rlsum, const float* __restrict__ sigma,
    const float* __restrict__ lsig, float* __restrict__ d_out)
{
    int b = blockIdx.x * 256 + threadIdx.x;
    if (b < BS_) {
        float sg = sigma[b];
        float rl = rlsum[b] / (2.0f * sg * sg);
        float le = d_out[2 * 512 + b];
        float ld = d_out[3 * 512 + b];
        d_out[b] = (rl + le + ld) / 3072.0f + lsig[b];
        d_out[512 + b] = rl;
    }
}

extern "C" void kernel_launch(void* const* d_in, const int* in_sizes, int n_in,
                              void* d_out, int out_size, void* d_ws, size_t ws_size,
                              hipStream_t stream)
{
    const float* x       = (const float*)d_in[0];
    const float* eps     = (const float*)d_in[1];
    const float* enc_W1  = (const float*)d_in[2];
    const float* enc_b1  = (const float*)d_in[3];
    const float* enc_Wmu = (const float*)d_in[4];
    const float* enc_bmu = (const float*)d_in[5];
    const float* enc_Wls = (const float*)d_in[6];
    const float* enc_bls = (const float*)d_in[7];
    const float* dec_W1  = (const float*)d_in[8];
    const float* dec_b1  = (const float*)d_in[9];
    const float* dec_W2  = (const float*)d_in[10];
    const float* dec_b2  = (const float*)d_in[11];
    float* out = (float*)d_out;

    char* wsb = (char*)d_ws;
    size_t off = 0;
    auto alloc = [&](size_t bytes) -> void* {
        off = (off + 255) & ~(size_t)255;
        void* p = wsb + off;
        off += bytes;
        return p;
    };

    // contiguous zero region: Ch, Cd, g, S (sizes are 256-multiples -> no gaps)
    float* Ch   = (float*)alloc((size_t)BS_ * H_ * 4);
    float* Cd   = (float*)alloc((size_t)BS_ * D_ * 4);
    float* g    = (float*)alloc((size_t)BS_ * H_ * 4);
    float* S    = (float*)alloc((size_t)BS_ * 256 * 4);
    size_t zero_span = (size_t)((char*)(S + BS_ * 256) - (char*)Ch);

    float* t    = (float*)alloc((size_t)BS_ * H_ * 4);
    float* z_st = (float*)alloc((size_t)BS_ * 16 * 4);
    float* lsig = (float*)alloc(BS_ * 4);
    float* sigm = (float*)alloc(BS_ * 4);
    float* z_sm = (float*)alloc((size_t)BS_ * 16 * 4);
    float* rls  = (float*)alloc(BS_ * 4);
    bf16* x_bf  = (bf16*)alloc((size_t)BS_ * D_ * 2);
    bf16* eW1t  = (bf16*)alloc((size_t)H_ * D_ * 2);
    bf16* W2b   = (bf16*)alloc((size_t)H_ * D_ * 2);
    bf16* W2t   = (bf16*)alloc((size_t)D_ * H_ * 2);
    bf16* W1b   = (bf16*)alloc((size_t)N_ * H_ * 2);
    bf16* t_bf  = (bf16*)alloc((size_t)BS_ * H_ * 2);
    bf16* e_bf  = (bf16*)alloc((size_t)BS_ * D_ * 2);
    bf16* t2b   = (bf16*)alloc((size_t)BS_ * H_ * 2);

    int nb = 0;
    size_t base_off = off;
    const int cand[3] = {512, 128, 32};
    bf16* Vt = nullptr;
    for (int ci = 0; ci < 3; ++ci) {
        off = base_off;
        int n = cand[ci];
        bf16* vt = (bf16*)alloc((size_t)n * 16 * H_ * 2);
        if (off <= ws_size) { nb = n; Vt = vt; break; }
    }
    if (nb == 0) return;

    // one fused prep launch + one memset
    prep_all<<<dim3(768 + 3072 + 16), 256, 0, stream>>>(
        x, enc_W1, dec_W2, dec_W1, x_bf, eW1t, W2t, W2b, W1b);
    hipMemsetAsync(Ch, 0, zero_span, stream);

    // h-accumulator = x @ enc_W1  [split-K 4]; tanh+z/sigma+t fused into zsig_t
    mfma_nt_sk<<<dim3(H_ / 128, BS_ / 128, 4), 256, 0, stream>>>(
        x_bf, eW1t, Ch, BS_, H_, D_, D_ / 4);
    zsig_t_kernel<<<dim3(BS_), 256, 0, stream>>>(Ch, enc_b1, enc_Wmu, enc_bmu, enc_Wls, enc_bls,
        dec_W1, dec_b1, z_st, lsig, sigm, t, t_bf);
    // e = x - (t @ W2 + b2)  [split-K 4]
    mfma_nt_sk<<<dim3(D_ / 128, BS_ / 128, 4), 256, 0, stream>>>(
        t_bf, W2t, Cd, BS_, D_, H_, H_ / 4);
    ep_ebf<<<dim3(BS_ * D_ / 8 / 256), 256, 0, stream>>>(Cd, dec_b2, x, e_bf, BS_ * D_, D_);
    // g = e @ W2^T  [split-K 4, direct accumulate]
    mfma_nt_sk<<<dim3(H_ / 128, BS_ / 128, 4), 256, 0, stream>>>(
        e_bf, W2b, g, BS_, H_, D_, D_ / 4);

    // S = J^T J (fused)
    for (int b0 = 0; b0 < BS_; b0 += nb) {
        build_vt<<<dim3(nb), 256, 0, stream>>>(t, dec_W1, Vt, b0);
        jtj_fused<<<dim3(D_ / 128, nb * 16 / 128), 256, 0, stream>>>(
            Vt, W2t, S, nb * 16 / 128, b0);
    }
    // S += hessian core
    hess_mfma<<<dim3(BS_ / 4), 256, 0, stream>>>(t, g, W1b, S);

    // eig-min / Cholesky / solves / scalars
    solve_kernel<<<dim3(BS_ / 4), 64, 0, stream>>>(S, sigm, z_st, eps, z_sm, out);
    // t2 = tanh(z_sample @ dec_W1 + b1)
    build_t<<<dim3(BS_), 256, 0, stream>>>(z_sm, dec_W1, dec_b1, t2b);
    // recon GEMM [split-K 4] + row-sum epilogue
    hipMemsetAsync(Cd, 0, (size_t)BS_ * D_ * 4, stream);
    mfma_nt_sk<<<dim3(D_ / 128, BS_ / 128, 4), 256, 0, stream>>>(
        t2b, W2t, Cd, BS_, D_, H_, H_ / 4);
    ep_recon<<<dim3(BS_), 256, 0, stream>>>(Cd, dec_b2, x, rls);
    finalize_kernel<<<dim3(2), 256, 0, stream>>>(rls, sigm, lsig, out);
}